// Round 2
// baseline (2246.090 us; speedup 1.0000x reference)
//
#include <hip/hip_runtime.h>
#include <hip/hip_bf16.h>
#include <math.h>

typedef __hip_bfloat16 bf16;
typedef short short8 __attribute__((ext_vector_type(8)));
typedef float f32x4 __attribute__((ext_vector_type(4)));

#define Bq 2
#define Sq 2048
#define Dq 2048
#define Hq 16
#define DHq 128
#define FFq 8192
#define Mq 4096  // Bq*Sq

__device__ __forceinline__ float b2f(bf16 x) { return __bfloat162float(x); }
__device__ __forceinline__ bf16 f2b(float x) { return __float2bfloat16(x); }

// Runtime dtype probe: wq ~ N(0,0.02). If the buffer is true f32, |v|<1.
// If it's bf16 misread as f32, the exponent field comes from a bf16's low
// exponent bits -> |v| ~ 2^100 (or NaN, which also fails the < test).
__device__ __forceinline__ bool is_f32(const void* probe) {
  const float* p = (const float*)probe;
  return (fabsf(p[0]) < 1.0f) || (fabsf(p[1]) < 1.0f);
}

// async global->LDS, 16B/lane. LDS dest is the wave-uniform BASE; HW adds lane*16.
__device__ __forceinline__ void gload16(const bf16* g, bf16* lds_base) {
  __builtin_amdgcn_global_load_lds(
      (const __attribute__((address_space(1))) void*)g,
      (__attribute__((address_space(3))) void*)lds_base,
      16, 0, 0);
}

// XOR swizzle: permutes 8-element (16B) blocks within a 64-elem span, keyed on row.
__device__ __forceinline__ int swz8(int row) { return (((row >> 3) ^ row) & 7) << 3; }

// ---------------------------------------------------------------------------
// GEMM: C[M,N] = A[M,K] * Bt[N,K]^T. A is always internal bf16 (lda=K).
// Bt/R/C dtypes resolved at runtime via probe (uniform branch).
// EPI 0: C(bf16) = acc
// EPI 1: C(dual) = R(dual) + acc      (residual)
// EPI 2: C(bf16) = silu(R(bf16)) * acc  (SwiGLU)
// 128x128 tile, BK=64, 4 waves (2x2), wave = 4x4 MFMA 16x16x32 tiles.
// ---------------------------------------------------------------------------
template <int EPI>
__global__ __launch_bounds__(256)
void gemm_bt(const bf16* __restrict__ A, const void* __restrict__ Bt,
             const void* __restrict__ R, void* __restrict__ C,
             const void* __restrict__ probe,
             int M, int N, int K, int ldb, long long boff) {
  __shared__ __align__(16) bf16 As[128][64];
  __shared__ __align__(16) bf16 Bs[128][64];
  const bool f32in = is_f32(probe);
  const int tid = threadIdx.x;
  const int w = tid >> 6;
  const int l = tid & 63;
  const int bm = blockIdx.y * 128;
  const int bn = blockIdx.x * 128;
  const int wr = (w >> 1) * 64;
  const int wc = (w & 1) * 64;
  const int srow = w * 8 + (l >> 3);
  const int scol = (l & 7) * 8;
  f32x4 acc[4][4] = {};

  const bf16* Ab = A + (size_t)bm * K;
  const size_t Bbase = (size_t)bn * ldb + (size_t)boff;

  for (int kt = 0; kt < K; kt += 64) {
    __syncthreads();  // prev tile's LDS reads done
#pragma unroll
    for (int i = 0; i < 4; ++i) {
      // A: async direct-to-LDS. Uniform base; lane l lands at base + l*16
      // == As[i*32+w*8 + l/8][(l%8)*8], matching the per-lane src below.
      gload16(Ab + (size_t)(i * 32 + w * 8 + (l >> 3)) * K + kt + (l & 7) * 8,
              &As[i * 32 + w * 8][0]);
      // B: reg-staged (handles dtype conversion)
      const int r = i * 32 + srow;
      const size_t e = Bbase + (size_t)r * ldb + kt + scol;
      short8 bv;
      if (f32in) {
        const float* bp = (const float*)Bt + e;
        f32x4 f0 = *(const f32x4*)bp;
        f32x4 f1 = *(const f32x4*)(bp + 4);
        union { short8 s; bf16 h[8]; } u;
#pragma unroll
        for (int j = 0; j < 4; ++j) { u.h[j] = f2b(f0[j]); u.h[j + 4] = f2b(f1[j]); }
        bv = u.s;
      } else {
        bv = *(const short8*)((const bf16*)Bt + e);
      }
      *(short8*)&Bs[r][scol] = bv;
    }
    __syncthreads();  // vmcnt+lgkmcnt drained before barrier
#pragma unroll
    for (int kk = 0; kk < 2; ++kk) {
      short8 af[4], bfv[4];
#pragma unroll
      for (int m = 0; m < 4; ++m)
        af[m] = *(const short8*)&As[wr + m * 16 + (l & 15)][kk * 32 + (l >> 4) * 8];
#pragma unroll
      for (int n = 0; n < 4; ++n)
        bfv[n] = *(const short8*)&Bs[wc + n * 16 + (l & 15)][kk * 32 + (l >> 4) * 8];
#pragma unroll
      for (int m = 0; m < 4; ++m)
#pragma unroll
        for (int n = 0; n < 4; ++n)
          acc[m][n] = __builtin_amdgcn_mfma_f32_16x16x32_bf16(af[m], bfv[n], acc[m][n], 0, 0, 0);
    }
  }

  // epilogue: C/D layout col = lane&15, row = (lane>>4)*4 + reg
  const int rbase = bm + wr + (l >> 4) * 4;
  const int cbase = bn + wc + (l & 15);
#pragma unroll
  for (int m = 0; m < 4; ++m)
#pragma unroll
    for (int r = 0; r < 4; ++r) {
      const int row = rbase + m * 16 + r;
#pragma unroll
      for (int n = 0; n < 4; ++n) {
        const size_t idx = (size_t)row * N + (cbase + n * 16);
        float vacc = acc[m][n][r];
        if (EPI == 1) {
          vacc += f32in ? ((const float*)R)[idx] : b2f(((const bf16*)R)[idx]);
          if (f32in) ((float*)C)[idx] = vacc;
          else       ((bf16*)C)[idx] = f2b(vacc);
        } else if (EPI == 2) {
          const float u = b2f(((const bf16*)R)[idx]);
          vacc = (u / (1.f + expf(-u))) * vacc;
          ((bf16*)C)[idx] = f2b(vacc);
        } else {
          ((bf16*)C)[idx] = f2b(vacc);
        }
      }
    }
}

// ---------------------------------------------------------------------------
// RMSNorm: one block per row of 2048. Input/g dual-dtype; output bf16.
// ---------------------------------------------------------------------------
__global__ __launch_bounds__(256)
void rmsnorm_k(const void* __restrict__ xin, const void* __restrict__ g,
               bf16* __restrict__ out, const void* __restrict__ probe) {
  const bool f32in = is_f32(probe);
  const int row = blockIdx.x;
  const int tid = threadIdx.x;
  float xf[8];
  if (f32in) {
    const float* xp = (const float*)xin + (size_t)row * Dq + tid * 8;
    f32x4 a = *(const f32x4*)xp, b = *(const f32x4*)(xp + 4);
#pragma unroll
    for (int j = 0; j < 4; ++j) { xf[j] = a[j]; xf[j + 4] = b[j]; }
  } else {
    union { short8 s; bf16 h[8]; } u;
    u.s = *(const short8*)((const bf16*)xin + (size_t)row * Dq + tid * 8);
#pragma unroll
    for (int j = 0; j < 8; ++j) xf[j] = b2f(u.h[j]);
  }
  float ss = 0.f;
#pragma unroll
  for (int j = 0; j < 8; ++j) ss += xf[j] * xf[j];
#pragma unroll
  for (int off = 32; off > 0; off >>= 1) ss += __shfl_down(ss, off);
  __shared__ float red[4];
  if ((tid & 63) == 0) red[tid >> 6] = ss;
  __syncthreads();
  const float rms = rsqrtf((red[0] + red[1] + red[2] + red[3]) * (1.f / (float)Dq) + 1e-6f);
  float gf[8];
  if (f32in) {
    const float* gp = (const float*)g + tid * 8;
    f32x4 a = *(const f32x4*)gp, b = *(const f32x4*)(gp + 4);
#pragma unroll
    for (int j = 0; j < 4; ++j) { gf[j] = a[j]; gf[j + 4] = b[j]; }
  } else {
    union { short8 s; bf16 h[8]; } u;
    u.s = *(const short8*)((const bf16*)g + tid * 8);
#pragma unroll
    for (int j = 0; j < 8; ++j) gf[j] = b2f(u.h[j]);
  }
  union { short8 s; bf16 h[8]; } uo;
#pragma unroll
  for (int j = 0; j < 8; ++j) {
    if (f32in) uo.h[j] = f2b(xf[j] * rms * gf[j]);
    else       uo.h[j] = f2b(b2f(f2b(xf[j] * rms)) * gf[j]);  // ref's astype-then-mul
  }
  *(short8*)(out + (size_t)row * Dq + tid * 8) = uo.s;
}

// ---------------------------------------------------------------------------
// RoPE in-place on q and k (internal bf16). One thread per (b,s,h,i<64).
// ---------------------------------------------------------------------------
__global__ __launch_bounds__(256)
void rope_k(bf16* __restrict__ q, bf16* __restrict__ k) {
  const size_t idx = (size_t)blockIdx.x * 256 + threadIdx.x;
  const int i = (int)(idx & 63);
  const int h = (int)((idx >> 6) & 15);
  const int s = (int)((idx >> 10) & 2047);
  const int b = (int)(idx >> 21);
  const float f = (float)s * powf(10000.f, -(float)i * (1.f / 64.f));
  float sn, cs;
  sincosf(f, &sn, &cs);
  const size_t base = ((size_t)(b * Sq + s)) * Dq + h * DHq + i;
  const float qa = b2f(q[base]), qb_ = b2f(q[base + 64]);
  q[base] = f2b(qa * cs - qb_ * sn);
  q[base + 64] = f2b(qb_ * cs + qa * sn);
  const float ka = b2f(k[base]), kb_ = b2f(k[base + 64]);
  k[base] = f2b(ka * cs - kb_ * sn);
  k[base + 64] = f2b(kb_ * cs + ka * sn);
}

// ---------------------------------------------------------------------------
// Causal flash attention. Grid (S/64, H, B), 4 waves; wave w owns 16 q-rows.
// All operands internal bf16.
// ---------------------------------------------------------------------------
__global__ __launch_bounds__(256)
void attn_k(const bf16* __restrict__ q, const bf16* __restrict__ k,
            const bf16* __restrict__ v, bf16* __restrict__ o) {
  __shared__ __align__(16) bf16 Ks[64][128];   // [kv][d], swizzled by swz8(kv)
  __shared__ __align__(16) bf16 Vt[128][64];   // [d][kv], swizzled by swz8(d)
  __shared__ __align__(16) bf16 Ps[4][16][64]; // [wave][q][kv], swizzled by swz8(q)
  const int tid = threadIdx.x;
  const int w = tid >> 6, l = tid & 63;
  const int q0 = blockIdx.x * 64;
  const int h = blockIdx.y;
  const int b = blockIdx.z;
  const size_t hoff = (size_t)h * DHq;
  const float SCALE = 0.08838834764831845f;  // 1/sqrt(128)

  short8 aq[4];
  {
    const bf16* qp = q + ((size_t)(b * Sq + q0 + w * 16 + (l & 15))) * Dq + hoff + (l >> 4) * 8;
#pragma unroll
    for (int kk = 0; kk < 4; ++kk) aq[kk] = *(const short8*)(qp + kk * 32);
  }

  float m_run[4], l_run[4];
  f32x4 o_acc[8] = {};
#pragma unroll
  for (int r = 0; r < 4; ++r) { m_run[r] = -3.0e38f; l_run[r] = 0.f; }

  const int ntiles = (q0 >> 6) + 1;
  for (int t = 0; t < ntiles; ++t) {
    const int kv0 = t * 64;
    __syncthreads();
#pragma unroll
    for (int rr = 0; rr < 4; ++rr) {
      const int e = (rr * 256 + tid) * 8;
      const int kr = e >> 7, c = e & 127;
      *(short8*)&Ks[kr][c ^ swz8(kr)] =
          *(const short8*)(k + ((size_t)(b * Sq + kv0 + kr)) * Dq + hoff + c);
      union { short8 s; bf16 hh[8]; } uv;
      uv.s = *(const short8*)(v + ((size_t)(b * Sq + kv0 + kr)) * Dq + hoff + c);
#pragma unroll
      for (int j = 0; j < 8; ++j) Vt[c + j][kr ^ swz8(c + j)] = uv.hh[j];
    }
    __syncthreads();

    const bool active = (kv0 <= q0 + w * 16 + 15);
    if (active) {
      f32x4 sc[4] = {};
#pragma unroll
      for (int n = 0; n < 4; ++n) {
        const int krow = n * 16 + (l & 15);
        const int sw = swz8(krow);
#pragma unroll
        for (int kk = 0; kk < 4; ++kk) {
          short8 bk = *(const short8*)&Ks[krow][(kk * 32 + (l >> 4) * 8) ^ sw];
          sc[n] = __builtin_amdgcn_mfma_f32_16x16x32_bf16(aq[kk], bk, sc[n], 0, 0, 0);
        }
      }
      const int qg = q0 + w * 16 + (l >> 4) * 4;
      const int kvg = kv0 + (l & 15);
      float p[4][4], tmax[4];
#pragma unroll
      for (int r = 0; r < 4; ++r) tmax[r] = -3.0e38f;
#pragma unroll
      for (int n = 0; n < 4; ++n)
#pragma unroll
        for (int r = 0; r < 4; ++r) {
          float val = sc[n][r] * SCALE;
          if (kvg + n * 16 > qg + r) val = -3.0e38f;
          p[n][r] = val;
          tmax[r] = fmaxf(tmax[r], val);
        }
#pragma unroll
      for (int r = 0; r < 4; ++r) {
#pragma unroll
        for (int mm = 1; mm < 16; mm <<= 1)
          tmax[r] = fmaxf(tmax[r], __shfl_xor(tmax[r], mm));
        const float m_new = fmaxf(m_run[r], tmax[r]);
        const float corr = expf(m_run[r] - m_new);
        float tsum = 0.f;
#pragma unroll
        for (int n = 0; n < 4; ++n) {
          const float pv = expf(p[n][r] - m_new);
          p[n][r] = pv;
          tsum += pv;
        }
#pragma unroll
        for (int mm = 1; mm < 16; mm <<= 1) tsum += __shfl_xor(tsum, mm);
        l_run[r] = l_run[r] * corr + tsum;
        m_run[r] = m_new;
#pragma unroll
        for (int dt = 0; dt < 8; ++dt) o_acc[dt][r] *= corr;
      }
#pragma unroll
      for (int n = 0; n < 4; ++n)
#pragma unroll
        for (int r = 0; r < 4; ++r) {
          const int prow = (l >> 4) * 4 + r;
          Ps[w][prow][(n * 16 + (l & 15)) ^ swz8(prow)] = f2b(p[n][r]);
        }
    }
    __syncthreads();
    if (active) {
      short8 ap[2];
      const int psw = swz8(l & 15);
#pragma unroll
      for (int kk = 0; kk < 2; ++kk)
        ap[kk] = *(const short8*)&Ps[w][l & 15][(kk * 32 + (l >> 4) * 8) ^ psw];
#pragma unroll
      for (int dt = 0; dt < 8; ++dt) {
        const int vrow = dt * 16 + (l & 15);
        const int vsw = swz8(vrow);
#pragma unroll
        for (int kk = 0; kk < 2; ++kk) {
          short8 bv = *(const short8*)&Vt[vrow][(kk * 32 + (l >> 4) * 8) ^ vsw];
          o_acc[dt] = __builtin_amdgcn_mfma_f32_16x16x32_bf16(ap[kk], bv, o_acc[dt], 0, 0, 0);
        }
      }
    }
  }
  const size_t orow = (size_t)(b * Sq + q0 + w * 16 + (l >> 4) * 4);
#pragma unroll
  for (int dt = 0; dt < 8; ++dt)
#pragma unroll
    for (int r = 0; r < 4; ++r)
      o[(orow + r) * Dq + hoff + dt * 16 + (l & 15)] = f2b(o_acc[dt][r] / l_run[r]);
}

// ---------------------------------------------------------------------------
// Workspace (64 MiB total):
//   h  = [0,  16M)  rmsnorm1 out -> attn out (ob)
//   kb = [16M, 32M)
//   vb = [32M, 48M)
//   qb = [48M, 64M)  -> reused as h2
//   ub_half = [0, 32M)   (M x FF/2, overlaps dead h/kb during FFN)
// FFN runs in two FF/2 halves; down-proj accumulates into out twice.
// ---------------------------------------------------------------------------
extern "C" void kernel_launch(void* const* d_in, const int* in_sizes, int n_in,
                              void* d_out, int out_size, void* d_ws, size_t ws_size,
                              hipStream_t stream) {
  (void)in_sizes; (void)n_in; (void)out_size; (void)ws_size;
  const void* x  = d_in[0];
  // d_in[1] = mask (causality implemented directly)
  const void* wq = d_in[2];
  const void* wk = d_in[3];
  const void* wv = d_in[4];
  const void* wo = d_in[5];
  const void* w1 = d_in[6];
  const void* w2 = d_in[7];
  const void* w3 = d_in[8];
  const void* ga = d_in[9];
  const void* gf = d_in[10];
  void* out = d_out;
  const void* probe = wq;

  char* ws = (char*)d_ws;
  const size_t MS = (size_t)Mq * Dq * sizeof(bf16);  // 16 MiB
  bf16* h  = (bf16*)(ws);
  bf16* kb = (bf16*)(ws + MS);
  bf16* vb = (bf16*)(ws + 2 * MS);
  bf16* qb = (bf16*)(ws + 3 * MS);
  bf16* ub = (bf16*)(ws);            // M x FF/2, overlaps h+kb (dead by FFN)
  bf16* ob = h;
  bf16* h2 = qb;

  dim3 blk(256);
  dim3 gD(Dq / 128, Mq / 128);       // N=2048 outputs
  dim3 gU(32, Mq / 128);             // N=4096 (FF/2) outputs
  dim3 gA(Sq / 64, Hq, Bq);

  rmsnorm_k<<<Mq, blk, 0, stream>>>(x, ga, h, probe);
  gemm_bt<0><<<gD, blk, 0, stream>>>(h, wq, nullptr, qb, probe, Mq, Dq, Dq, Dq, 0);
  gemm_bt<0><<<gD, blk, 0, stream>>>(h, wk, nullptr, kb, probe, Mq, Dq, Dq, Dq, 0);
  gemm_bt<0><<<gD, blk, 0, stream>>>(h, wv, nullptr, vb, probe, Mq, Dq, Dq, Dq, 0);
  rope_k<<<(Bq * Sq * Hq * 64) / 256, blk, 0, stream>>>(qb, kb);
  attn_k<<<gA, blk, 0, stream>>>(qb, kb, vb, ob);
  gemm_bt<1><<<gD, blk, 0, stream>>>(ob, wo, x, out, probe, Mq, Dq, Dq, Dq, 0);
  rmsnorm_k<<<Mq, blk, 0, stream>>>(out, gf, h2, probe);
  for (int hh = 0; hh < 2; ++hh) {
    const long long bo13 = (long long)hh * 4096 * 2048;  // row offset into w1/w3
    gemm_bt<0><<<gU, blk, 0, stream>>>(h2, w1, nullptr, ub, probe, Mq, 4096, Dq, Dq, bo13);
    gemm_bt<2><<<gU, blk, 0, stream>>>(h2, w3, ub, ub, probe, Mq, 4096, Dq, Dq, bo13);
    gemm_bt<1><<<gD, blk, 0, stream>>>(ub, w2, out, out, probe, Mq, Dq, 4096, FFq,
                                       (long long)hh * 4096);
  }
}

// Round 3
// 1267.006 us; speedup vs baseline: 1.7728x; 1.7728x over previous
//
#include <hip/hip_runtime.h>
#include <hip/hip_bf16.h>
#include <math.h>

typedef __hip_bfloat16 bf16;
typedef short short8 __attribute__((ext_vector_type(8)));
typedef float f32x4 __attribute__((ext_vector_type(4)));

#define Bq 2
#define Sq 2048
#define Dq 2048
#define Hq 16
#define DHq 128
#define FFq 8192
#define Mq 4096  // Bq*Sq

// Inputs/outputs are f32 (round-2 evidence: down-proj WRITE_SIZE = 33.5 MB =
// M*D*4B). Internal activations are bf16; weights are read as f32 directly.

__device__ __forceinline__ float b2f(bf16 x) { return __bfloat162float(x); }
__device__ __forceinline__ bf16 f2b(float x) { return __float2bfloat16(x); }

// async global->LDS, 16B/lane. LDS dest arg is the wave-uniform BASE; HW places
// lane l at base + l*16.
__device__ __forceinline__ void gload16(const void* g, void* lds_base) {
  __builtin_amdgcn_global_load_lds(
      (const __attribute__((address_space(1))) void*)g,
      (__attribute__((address_space(3))) void*)lds_base,
      16, 0, 0);
}

// ---------------------------------------------------------------------------
// GEMM: C[M,N] = A[M,K](bf16) * Bt[N,K](f32)^T
// EPI 0: C(bf16) = acc
// EPI 1: C(f32)  = R(f32) + acc       (residual)
// EPI 2: C(bf16) = silu(R(bf16)) * acc  (SwiGLU)
// 128x128 tile, BK=64, 4 waves (2x2), wave = 4x4 MFMA 16x16x32 tiles.
// Both operands staged via global_load_lds with XOR-8 block swizzle:
// physical 16B-block = logical ^ (row&7), applied on the GLOBAL source (DMA
// dest is linear) and again on the LDS read (rule #21: both-sides).
// ---------------------------------------------------------------------------
template <int EPI>
__global__ __launch_bounds__(256)
void gemm2(const bf16* __restrict__ A, const float* __restrict__ Bt,
           const void* __restrict__ R, void* __restrict__ C,
           int M, int N, int K, int ldb, long long boff) {
  __shared__ __align__(16) bf16 As[128][64];    // 16 KiB, row = 8 blocks of 16B
  __shared__ __align__(16) float Bsf[128][64];  // 32 KiB, row = 16 blocks of 16B
  const int tid = threadIdx.x;
  const int w = tid >> 6;
  const int l = tid & 63;

  // bijective XCD swizzle (T1, m204): contiguous chunk of blocks per XCD
  const int nwg = gridDim.x * gridDim.y;
  const int orig = blockIdx.x + blockIdx.y * gridDim.x;
  const int qq = nwg >> 3, rr8 = nwg & 7;
  const int xcd = orig & 7, idx8 = orig >> 3;
  const int wg = (xcd < rr8 ? xcd * (qq + 1) : rr8 * (qq + 1) + (xcd - rr8) * qq) + idx8;
  const int bm = (wg / gridDim.x) * 128;
  const int bn = (wg % gridDim.x) * 128;

  const int wr = (w >> 1) * 64;
  const int wc = (w & 1) * 64;
  f32x4 acc[4][4] = {};

  const bf16* Ab = A + (size_t)bm * K;
  const float* Bb = Bt + (size_t)bn * ldb + (size_t)boff;

  // per-lane staging source columns (pre-swizzled so linear DMA dest lands
  // each 16B block at physical = logical ^ (row&7))
  const int aSrcCol = (((l & 7) ^ (l >> 3)) << 3);            // bf16 elems
  const int bKey = (w * 4 + (l >> 4)) & 7;
  const int bSrcCol = (((l & 15) ^ bKey) << 2);               // f32 elems

  for (int kt = 0; kt < K; kt += 64) {
    __syncthreads();  // prev tile's LDS reads done
#pragma unroll
    for (int i = 0; i < 4; ++i)
      gload16(Ab + (size_t)(i * 32 + w * 8 + (l >> 3)) * K + kt + aSrcCol,
              &As[i * 32 + w * 8][0]);
#pragma unroll
    for (int i = 0; i < 8; ++i)
      gload16(Bb + (size_t)(i * 16 + w * 4 + (l >> 4)) * ldb + kt + bSrcCol,
              &Bsf[i * 16 + w * 4][0]);
    __syncthreads();  // compiler drains vmcnt(0) before s_barrier

#pragma unroll
    for (int kk = 0; kk < 2; ++kk) {
      short8 af[4], bfv[4];
#pragma unroll
      for (int m = 0; m < 4; ++m) {
        const int ra = wr + m * 16 + (l & 15);
        const int pb = (kk * 4 + (l >> 4)) ^ (ra & 7);
        af[m] = *(const short8*)&As[ra][pb * 8];
      }
#pragma unroll
      for (int n = 0; n < 4; ++n) {
        const int rb = wc + n * 16 + (l & 15);
        const int b0 = kk * 8 + (l >> 4) * 2;
        const f32x4 x0 = *(const f32x4*)&Bsf[rb][(b0 ^ (rb & 7)) * 4];
        const f32x4 x1 = *(const f32x4*)&Bsf[rb][((b0 + 1) ^ (rb & 7)) * 4];
        union { short8 s; bf16 h[8]; } u;
#pragma unroll
        for (int j = 0; j < 4; ++j) { u.h[j] = f2b(x0[j]); u.h[j + 4] = f2b(x1[j]); }
        bfv[n] = u.s;
      }
#pragma unroll
      for (int m = 0; m < 4; ++m)
#pragma unroll
        for (int n = 0; n < 4; ++n)
          acc[m][n] = __builtin_amdgcn_mfma_f32_16x16x32_bf16(af[m], bfv[n], acc[m][n], 0, 0, 0);
    }
  }

  // epilogue: C/D layout col = lane&15, row = (lane>>4)*4 + reg
  const int rbase = bm + wr + (l >> 4) * 4;
  const int cbase = bn + wc + (l & 15);
#pragma unroll
  for (int m = 0; m < 4; ++m)
#pragma unroll
    for (int r = 0; r < 4; ++r) {
      const int row = rbase + m * 16 + r;
#pragma unroll
      for (int n = 0; n < 4; ++n) {
        const size_t idx = (size_t)row * N + (cbase + n * 16);
        float vacc = acc[m][n][r];
        if (EPI == 1) {
          ((float*)C)[idx] = vacc + ((const float*)R)[idx];
        } else if (EPI == 2) {
          const float u = b2f(((const bf16*)R)[idx]);
          ((bf16*)C)[idx] = f2b((u / (1.f + expf(-u))) * vacc);
        } else {
          ((bf16*)C)[idx] = f2b(vacc);
        }
      }
    }
}

// ---------------------------------------------------------------------------
// RMSNorm: one block per row of 2048. f32 in, f32 g, bf16 out.
// ---------------------------------------------------------------------------
__global__ __launch_bounds__(256)
void rmsnorm_k(const float* __restrict__ xin, const float* __restrict__ g,
               bf16* __restrict__ out) {
  const int row = blockIdx.x;
  const int tid = threadIdx.x;
  const float* xp = xin + (size_t)row * Dq + tid * 8;
  f32x4 a = *(const f32x4*)xp, b = *(const f32x4*)(xp + 4);
  float xf[8];
#pragma unroll
  for (int j = 0; j < 4; ++j) { xf[j] = a[j]; xf[j + 4] = b[j]; }
  float ss = 0.f;
#pragma unroll
  for (int j = 0; j < 8; ++j) ss += xf[j] * xf[j];
#pragma unroll
  for (int off = 32; off > 0; off >>= 1) ss += __shfl_down(ss, off);
  __shared__ float red[4];
  if ((tid & 63) == 0) red[tid >> 6] = ss;
  __syncthreads();
  const float rms = rsqrtf((red[0] + red[1] + red[2] + red[3]) * (1.f / (float)Dq) + 1e-6f);
  const float* gp = g + tid * 8;
  f32x4 ga = *(const f32x4*)gp, gb = *(const f32x4*)(gp + 4);
  union { short8 s; bf16 h[8]; } uo;
#pragma unroll
  for (int j = 0; j < 4; ++j) {
    uo.h[j] = f2b(xf[j] * rms * ga[j]);
    uo.h[j + 4] = f2b(xf[j + 4] * rms * gb[j]);
  }
  *(short8*)(out + (size_t)row * Dq + tid * 8) = uo.s;
}

// ---------------------------------------------------------------------------
// RoPE in-place on q and k (bf16). One thread per (b,s,h,i<64).
// ---------------------------------------------------------------------------
__global__ __launch_bounds__(256)
void rope_k(bf16* __restrict__ q, bf16* __restrict__ k) {
  const size_t idx = (size_t)blockIdx.x * 256 + threadIdx.x;
  const int i = (int)(idx & 63);
  const int h = (int)((idx >> 6) & 15);
  const int s = (int)((idx >> 10) & 2047);
  const int b = (int)(idx >> 21);
  const float f = (float)s * powf(10000.f, -(float)i * (1.f / 64.f));
  float sn, cs;
  sincosf(f, &sn, &cs);
  const size_t base = ((size_t)(b * Sq + s)) * Dq + h * DHq + i;
  const float qa = b2f(q[base]), qb_ = b2f(q[base + 64]);
  q[base] = f2b(qa * cs - qb_ * sn);
  q[base + 64] = f2b(qb_ * cs + qa * sn);
  const float ka = b2f(k[base]), kb_ = b2f(k[base + 64]);
  k[base] = f2b(ka * cs - kb_ * sn);
  k[base + 64] = f2b(kb_ * cs + ka * sn);
}

// ---------------------------------------------------------------------------
// Causal flash attention. Grid (S/64, H, B), 4 waves; wave w owns 16 q-rows.
// ---------------------------------------------------------------------------
__device__ __forceinline__ int swz8(int row) { return (((row >> 3) ^ row) & 7) << 3; }

__global__ __launch_bounds__(256)
void attn_k(const bf16* __restrict__ q, const bf16* __restrict__ k,
            const bf16* __restrict__ v, bf16* __restrict__ o) {
  __shared__ __align__(16) bf16 Ks[64][128];   // [kv][d], swizzled by swz8(kv)
  __shared__ __align__(16) bf16 Vt[128][64];   // [d][kv], swizzled by swz8(d)
  __shared__ __align__(16) bf16 Ps[4][16][64]; // [wave][q][kv], swizzled by swz8(q)
  const int tid = threadIdx.x;
  const int w = tid >> 6, l = tid & 63;
  const int q0 = blockIdx.x * 64;
  const int h = blockIdx.y;
  const int b = blockIdx.z;
  const size_t hoff = (size_t)h * DHq;
  const float SCALE = 0.08838834764831845f;  // 1/sqrt(128)

  short8 aq[4];
  {
    const bf16* qp = q + ((size_t)(b * Sq + q0 + w * 16 + (l & 15))) * Dq + hoff + (l >> 4) * 8;
#pragma unroll
    for (int kk = 0; kk < 4; ++kk) aq[kk] = *(const short8*)(qp + kk * 32);
  }

  float m_run[4], l_run[4];
  f32x4 o_acc[8] = {};
#pragma unroll
  for (int r = 0; r < 4; ++r) { m_run[r] = -3.0e38f; l_run[r] = 0.f; }

  const int ntiles = (q0 >> 6) + 1;
  for (int t = 0; t < ntiles; ++t) {
    const int kv0 = t * 64;
    __syncthreads();
#pragma unroll
    for (int rr = 0; rr < 4; ++rr) {
      const int e = (rr * 256 + tid) * 8;
      const int kr = e >> 7, c = e & 127;
      *(short8*)&Ks[kr][c ^ swz8(kr)] =
          *(const short8*)(k + ((size_t)(b * Sq + kv0 + kr)) * Dq + hoff + c);
      union { short8 s; bf16 hh[8]; } uv;
      uv.s = *(const short8*)(v + ((size_t)(b * Sq + kv0 + kr)) * Dq + hoff + c);
#pragma unroll
      for (int j = 0; j < 8; ++j) Vt[c + j][kr ^ swz8(c + j)] = uv.hh[j];
    }
    __syncthreads();

    const bool active = (kv0 <= q0 + w * 16 + 15);
    if (active) {
      f32x4 sc[4] = {};
#pragma unroll
      for (int n = 0; n < 4; ++n) {
        const int krow = n * 16 + (l & 15);
        const int sw = swz8(krow);
#pragma unroll
        for (int kk = 0; kk < 4; ++kk) {
          short8 bk = *(const short8*)&Ks[krow][(kk * 32 + (l >> 4) * 8) ^ sw];
          sc[n] = __builtin_amdgcn_mfma_f32_16x16x32_bf16(aq[kk], bk, sc[n], 0, 0, 0);
        }
      }
      const int qg = q0 + w * 16 + (l >> 4) * 4;
      const int kvg = kv0 + (l & 15);
      float p[4][4], tmax[4];
#pragma unroll
      for (int r = 0; r < 4; ++r) tmax[r] = -3.0e38f;
#pragma unroll
      for (int n = 0; n < 4; ++n)
#pragma unroll
        for (int r = 0; r < 4; ++r) {
          float val = sc[n][r] * SCALE;
          if (kvg + n * 16 > qg + r) val = -3.0e38f;
          p[n][r] = val;
          tmax[r] = fmaxf(tmax[r], val);
        }
#pragma unroll
      for (int r = 0; r < 4; ++r) {
#pragma unroll
        for (int mm = 1; mm < 16; mm <<= 1)
          tmax[r] = fmaxf(tmax[r], __shfl_xor(tmax[r], mm));
        const float m_new = fmaxf(m_run[r], tmax[r]);
        const float corr = expf(m_run[r] - m_new);
        float tsum = 0.f;
#pragma unroll
        for (int n = 0; n < 4; ++n) {
          const float pv = expf(p[n][r] - m_new);
          p[n][r] = pv;
          tsum += pv;
        }
#pragma unroll
        for (int mm = 1; mm < 16; mm <<= 1) tsum += __shfl_xor(tsum, mm);
        l_run[r] = l_run[r] * corr + tsum;
        m_run[r] = m_new;
#pragma unroll
        for (int dt = 0; dt < 8; ++dt) o_acc[dt][r] *= corr;
      }
#pragma unroll
      for (int n = 0; n < 4; ++n)
#pragma unroll
        for (int r = 0; r < 4; ++r) {
          const int prow = (l >> 4) * 4 + r;
          Ps[w][prow][(n * 16 + (l & 15)) ^ swz8(prow)] = f2b(p[n][r]);
        }
    }
    __syncthreads();
    if (active) {
      short8 ap[2];
      const int psw = swz8(l & 15);
#pragma unroll
      for (int kk = 0; kk < 2; ++kk)
        ap[kk] = *(const short8*)&Ps[w][l & 15][(kk * 32 + (l >> 4) * 8) ^ psw];
#pragma unroll
      for (int dt = 0; dt < 8; ++dt) {
        const int vrow = dt * 16 + (l & 15);
        const int vsw = swz8(vrow);
#pragma unroll
        for (int kk = 0; kk < 2; ++kk) {
          short8 bv = *(const short8*)&Vt[vrow][(kk * 32 + (l >> 4) * 8) ^ vsw];
          o_acc[dt] = __builtin_amdgcn_mfma_f32_16x16x32_bf16(ap[kk], bv, o_acc[dt], 0, 0, 0);
        }
      }
    }
  }
  const size_t orow = (size_t)(b * Sq + q0 + w * 16 + (l >> 4) * 4);
#pragma unroll
  for (int dt = 0; dt < 8; ++dt)
#pragma unroll
    for (int r = 0; r < 4; ++r)
      o[(orow + r) * Dq + hoff + dt * 16 + (l & 15)] = f2b(o_acc[dt][r] / l_run[r]);
}

// ---------------------------------------------------------------------------
// Workspace (64 MiB):
//   h  = [0,  16M)  rmsnorm1 out -> attn out (ob)
//   kb = [16M, 32M)
//   vb = [32M, 48M)
//   qb = [48M, 64M)  -> reused as h2
//   ub = [0, 32M)    M x FF/2 bf16, overlaps dead h/kb during FFN
// ---------------------------------------------------------------------------
extern "C" void kernel_launch(void* const* d_in, const int* in_sizes, int n_in,
                              void* d_out, int out_size, void* d_ws, size_t ws_size,
                              hipStream_t stream) {
  (void)in_sizes; (void)n_in; (void)out_size; (void)ws_size;
  const float* x  = (const float*)d_in[0];
  // d_in[1] = mask (causality implemented directly)
  const float* wq = (const float*)d_in[2];
  const float* wk = (const float*)d_in[3];
  const float* wv = (const float*)d_in[4];
  const float* wo = (const float*)d_in[5];
  const float* w1 = (const float*)d_in[6];
  const float* w2 = (const float*)d_in[7];
  const float* w3 = (const float*)d_in[8];
  const float* ga = (const float*)d_in[9];
  const float* gf = (const float*)d_in[10];
  float* out = (float*)d_out;

  char* ws = (char*)d_ws;
  const size_t MS = (size_t)Mq * Dq * sizeof(bf16);  // 16 MiB
  bf16* h  = (bf16*)(ws);
  bf16* kb = (bf16*)(ws + MS);
  bf16* vb = (bf16*)(ws + 2 * MS);
  bf16* qb = (bf16*)(ws + 3 * MS);
  bf16* ub = (bf16*)(ws);            // M x FF/2, overlaps h+kb (dead by FFN)
  bf16* ob = h;
  bf16* h2 = qb;

  dim3 blk(256);
  dim3 gD(Dq / 128, Mq / 128);       // 512 blocks
  dim3 gU(32, Mq / 128);             // 1024 blocks (N=4096)
  dim3 gA(Sq / 64, Hq, Bq);

  rmsnorm_k<<<Mq, blk, 0, stream>>>(x, ga, h);
  gemm2<0><<<gD, blk, 0, stream>>>(h, wq, nullptr, qb, Mq, Dq, Dq, Dq, 0);
  gemm2<0><<<gD, blk, 0, stream>>>(h, wk, nullptr, kb, Mq, Dq, Dq, Dq, 0);
  gemm2<0><<<gD, blk, 0, stream>>>(h, wv, nullptr, vb, Mq, Dq, Dq, Dq, 0);
  rope_k<<<(Bq * Sq * Hq * 64) / 256, blk, 0, stream>>>(qb, kb);
  attn_k<<<gA, blk, 0, stream>>>(qb, kb, vb, ob);
  gemm2<1><<<gD, blk, 0, stream>>>(ob, wo, x, out, Mq, Dq, Dq, Dq, 0);
  rmsnorm_k<<<Mq, blk, 0, stream>>>(out, gf, h2);
  for (int hh = 0; hh < 2; ++hh) {
    const long long bo13 = (long long)hh * 4096 * 2048;  // row offset into w1/w3
    gemm2<0><<<gU, blk, 0, stream>>>(h2, w1, nullptr, ub, Mq, 4096, Dq, Dq, bo13);
    gemm2<2><<<gU, blk, 0, stream>>>(h2, w3, ub, ub, Mq, 4096, Dq, Dq, bo13);
    gemm2<1><<<gD, blk, 0, stream>>>(ub, w2, out, out, Mq, Dq, 4096, FFq,
                                     (long long)hh * 4096);
  }
}

// Round 4
// 1090.527 us; speedup vs baseline: 2.0596x; 1.1618x over previous
//
#include <hip/hip_runtime.h>
#include <hip/hip_bf16.h>
#include <math.h>

typedef __hip_bfloat16 bf16;
typedef short short8 __attribute__((ext_vector_type(8)));
typedef float f32x4 __attribute__((ext_vector_type(4)));

#define Bq 2
#define Sq 2048
#define Dq 2048
#define Hq 16
#define DHq 128
#define FFq 8192
#define Mq 4096  // Bq*Sq

// Inputs/outputs are f32 (round-2 evidence: down-proj WRITE_SIZE = M*D*4B).
// Internal activations bf16. Weights pre-converted to bf16 when ws_size
// allows (path A); otherwise f32-staged directly (path B = round-3 code).

__device__ __forceinline__ float b2f(bf16 x) { return __bfloat162float(x); }
__device__ __forceinline__ bf16 f2b(float x) { return __float2bfloat16(x); }

// async global->LDS, 16B/lane. LDS dest arg is the wave-uniform BASE; HW places
// lane l at base + l*16.
__device__ __forceinline__ void gload16(const void* g, void* lds_base) {
  __builtin_amdgcn_global_load_lds(
      (const __attribute__((address_space(1))) void*)g,
      (__attribute__((address_space(3))) void*)lds_base,
      16, 0, 0);
}

// ---------------------------------------------------------------------------
// f32 -> bf16 conversion (grid-stride, 8 elems/thread)
// ---------------------------------------------------------------------------
__global__ __launch_bounds__(256)
void conv_k(const float* __restrict__ src, bf16* __restrict__ dst, long n) {
  const long stride = (long)gridDim.x * 256 * 8;
  for (long i = ((long)blockIdx.x * 256 + threadIdx.x) * 8; i < n; i += stride) {
    f32x4 a = *(const f32x4*)(src + i);
    f32x4 b = *(const f32x4*)(src + i + 4);
    union { short8 s; bf16 h[8]; } u;
#pragma unroll
    for (int j = 0; j < 4; ++j) { u.h[j] = f2b(a[j]); u.h[j + 4] = f2b(b[j]); }
    *(short8*)(dst + i) = u.s;
  }
}

// ---------------------------------------------------------------------------
// PATH A GEMM: C[M,N] = A[M,K](bf16) * Bt[N,K](bf16)^T
// EPI 0: C(bf16) = acc
// EPI 1: C(f32)  = R(f32) + acc        (residual)
// EPI 2: C(bf16) = silu(R(bf16)) * acc (SwiGLU)
// 128x128 tile, BK=64, 4 waves (2x2). Both operands via global_load_lds with
// the XOR-8 block swizzle applied on source AND read (rule #21).
// ---------------------------------------------------------------------------
template <int EPI>
__global__ __launch_bounds__(256)
void gemm3(const bf16* __restrict__ A, const bf16* __restrict__ Bt,
           const void* __restrict__ R, void* __restrict__ C,
           int N, int K, int ldb, long long boff) {
  __shared__ __align__(16) bf16 As[128][64];
  __shared__ __align__(16) bf16 Bs[128][64];
  const int tid = threadIdx.x;
  const int w = tid >> 6;
  const int l = tid & 63;

  // bijective XCD swizzle (T1, m204)
  const int nwg = gridDim.x * gridDim.y;
  const int orig = blockIdx.x + blockIdx.y * gridDim.x;
  const int qq = nwg >> 3, rr8 = nwg & 7;
  const int xcd = orig & 7, idx8 = orig >> 3;
  const int wg = (xcd < rr8 ? xcd * (qq + 1) : rr8 * (qq + 1) + (xcd - rr8) * qq) + idx8;
  const int bm = (wg / gridDim.x) * 128;
  const int bn = (wg % gridDim.x) * 128;

  const int wr = (w >> 1) * 64;
  const int wc = (w & 1) * 64;
  f32x4 acc[4][4] = {};

  const bf16* Ab = A + (size_t)bm * K;
  const bf16* Bb = Bt + (size_t)bn * ldb + (size_t)boff;

  // staging: lane l covers row (l>>3) within each 8-row group, 16B block (l&7).
  // pre-swizzled source so linear DMA dest => physical block = logical ^ (row&7)
  const int sRow = w * 8 + (l >> 3);                 // + i*32
  const int sCol = (((l & 7) ^ (l >> 3)) << 3);      // bf16 elems

  for (int kt = 0; kt < K; kt += 64) {
    __syncthreads();  // prev tile's LDS reads done
#pragma unroll
    for (int i = 0; i < 4; ++i) {
      gload16(Ab + (size_t)(i * 32 + sRow) * K + kt + sCol, &As[i * 32 + w * 8][0]);
      gload16(Bb + (size_t)(i * 32 + sRow) * ldb + kt + sCol, &Bs[i * 32 + w * 8][0]);
    }
    __syncthreads();  // vmcnt(0) drained before barrier

#pragma unroll
    for (int kk = 0; kk < 2; ++kk) {
      short8 af[4], bfv[4];
#pragma unroll
      for (int m = 0; m < 4; ++m) {
        const int ra = wr + m * 16 + (l & 15);
        af[m] = *(const short8*)&As[ra][(((kk * 4 + (l >> 4)) ^ (ra & 7)) << 3)];
      }
#pragma unroll
      for (int n = 0; n < 4; ++n) {
        const int rb = wc + n * 16 + (l & 15);
        bfv[n] = *(const short8*)&Bs[rb][(((kk * 4 + (l >> 4)) ^ (rb & 7)) << 3)];
      }
#pragma unroll
      for (int m = 0; m < 4; ++m)
#pragma unroll
        for (int n = 0; n < 4; ++n)
          acc[m][n] = __builtin_amdgcn_mfma_f32_16x16x32_bf16(af[m], bfv[n], acc[m][n], 0, 0, 0);
    }
  }

  // epilogue: C/D layout col = lane&15, row = (lane>>4)*4 + reg
  const int rbase = bm + wr + (l >> 4) * 4;
  const int cbase = bn + wc + (l & 15);
#pragma unroll
  for (int m = 0; m < 4; ++m)
#pragma unroll
    for (int r = 0; r < 4; ++r) {
      const int row = rbase + m * 16 + r;
#pragma unroll
      for (int n = 0; n < 4; ++n) {
        const size_t idx = (size_t)row * N + (cbase + n * 16);
        float vacc = acc[m][n][r];
        if (EPI == 1) {
          ((float*)C)[idx] = vacc + ((const float*)R)[idx];
        } else if (EPI == 2) {
          const float u = b2f(((const bf16*)R)[idx]);
          ((bf16*)C)[idx] = f2b((u / (1.f + expf(-u))) * vacc);
        } else {
          ((bf16*)C)[idx] = f2b(vacc);
        }
      }
    }
}

// ---------------------------------------------------------------------------
// PATH B GEMM (round-3 verified): B operand f32, staged via gload_lds.
// ---------------------------------------------------------------------------
template <int EPI>
__global__ __launch_bounds__(256)
void gemm2(const bf16* __restrict__ A, const float* __restrict__ Bt,
           const void* __restrict__ R, void* __restrict__ C,
           int N, int K, int ldb, long long boff) {
  __shared__ __align__(16) bf16 As[128][64];
  __shared__ __align__(16) float Bsf[128][64];
  const int tid = threadIdx.x;
  const int w = tid >> 6;
  const int l = tid & 63;

  const int nwg = gridDim.x * gridDim.y;
  const int orig = blockIdx.x + blockIdx.y * gridDim.x;
  const int qq = nwg >> 3, rr8 = nwg & 7;
  const int xcd = orig & 7, idx8 = orig >> 3;
  const int wg = (xcd < rr8 ? xcd * (qq + 1) : rr8 * (qq + 1) + (xcd - rr8) * qq) + idx8;
  const int bm = (wg / gridDim.x) * 128;
  const int bn = (wg % gridDim.x) * 128;

  const int wr = (w >> 1) * 64;
  const int wc = (w & 1) * 64;
  f32x4 acc[4][4] = {};

  const bf16* Ab = A + (size_t)bm * K;
  const float* Bb = Bt + (size_t)bn * ldb + (size_t)boff;

  const int aSrcCol = (((l & 7) ^ (l >> 3)) << 3);
  const int bKey = (w * 4 + (l >> 4)) & 7;
  const int bSrcCol = (((l & 15) ^ bKey) << 2);

  for (int kt = 0; kt < K; kt += 64) {
    __syncthreads();
#pragma unroll
    for (int i = 0; i < 4; ++i)
      gload16(Ab + (size_t)(i * 32 + w * 8 + (l >> 3)) * K + kt + aSrcCol,
              &As[i * 32 + w * 8][0]);
#pragma unroll
    for (int i = 0; i < 8; ++i)
      gload16(Bb + (size_t)(i * 16 + w * 4 + (l >> 4)) * ldb + kt + bSrcCol,
              &Bsf[i * 16 + w * 4][0]);
    __syncthreads();

#pragma unroll
    for (int kk = 0; kk < 2; ++kk) {
      short8 af[4], bfv[4];
#pragma unroll
      for (int m = 0; m < 4; ++m) {
        const int ra = wr + m * 16 + (l & 15);
        const int pb = (kk * 4 + (l >> 4)) ^ (ra & 7);
        af[m] = *(const short8*)&As[ra][pb * 8];
      }
#pragma unroll
      for (int n = 0; n < 4; ++n) {
        const int rb = wc + n * 16 + (l & 15);
        const int b0 = kk * 8 + (l >> 4) * 2;
        const f32x4 x0 = *(const f32x4*)&Bsf[rb][(b0 ^ (rb & 7)) * 4];
        const f32x4 x1 = *(const f32x4*)&Bsf[rb][((b0 + 1) ^ (rb & 7)) * 4];
        union { short8 s; bf16 h[8]; } u;
#pragma unroll
        for (int j = 0; j < 4; ++j) { u.h[j] = f2b(x0[j]); u.h[j + 4] = f2b(x1[j]); }
        bfv[n] = u.s;
      }
#pragma unroll
      for (int m = 0; m < 4; ++m)
#pragma unroll
        for (int n = 0; n < 4; ++n)
          acc[m][n] = __builtin_amdgcn_mfma_f32_16x16x32_bf16(af[m], bfv[n], acc[m][n], 0, 0, 0);
    }
  }

  const int rbase = bm + wr + (l >> 4) * 4;
  const int cbase = bn + wc + (l & 15);
#pragma unroll
  for (int m = 0; m < 4; ++m)
#pragma unroll
    for (int r = 0; r < 4; ++r) {
      const int row = rbase + m * 16 + r;
#pragma unroll
      for (int n = 0; n < 4; ++n) {
        const size_t idx = (size_t)row * N + (cbase + n * 16);
        float vacc = acc[m][n][r];
        if (EPI == 1) {
          ((float*)C)[idx] = vacc + ((const float*)R)[idx];
        } else if (EPI == 2) {
          const float u = b2f(((const bf16*)R)[idx]);
          ((bf16*)C)[idx] = f2b((u / (1.f + expf(-u))) * vacc);
        } else {
          ((bf16*)C)[idx] = f2b(vacc);
        }
      }
    }
}

// ---------------------------------------------------------------------------
// RMSNorm: one block per row of 2048. f32 in, f32 g, bf16 out.
// ---------------------------------------------------------------------------
__global__ __launch_bounds__(256)
void rmsnorm_k(const float* __restrict__ xin, const float* __restrict__ g,
               bf16* __restrict__ out) {
  const int row = blockIdx.x;
  const int tid = threadIdx.x;
  const float* xp = xin + (size_t)row * Dq + tid * 8;
  f32x4 a = *(const f32x4*)xp, b = *(const f32x4*)(xp + 4);
  float xf[8];
#pragma unroll
  for (int j = 0; j < 4; ++j) { xf[j] = a[j]; xf[j + 4] = b[j]; }
  float ss = 0.f;
#pragma unroll
  for (int j = 0; j < 8; ++j) ss += xf[j] * xf[j];
#pragma unroll
  for (int off = 32; off > 0; off >>= 1) ss += __shfl_down(ss, off);
  __shared__ float red[4];
  if ((tid & 63) == 0) red[tid >> 6] = ss;
  __syncthreads();
  const float rms = rsqrtf((red[0] + red[1] + red[2] + red[3]) * (1.f / (float)Dq) + 1e-6f);
  const float* gp = g + tid * 8;
  f32x4 ga = *(const f32x4*)gp, gb = *(const f32x4*)(gp + 4);
  union { short8 s; bf16 h[8]; } uo;
#pragma unroll
  for (int j = 0; j < 4; ++j) {
    uo.h[j] = f2b(xf[j] * rms * ga[j]);
    uo.h[j + 4] = f2b(xf[j + 4] * rms * gb[j]);
  }
  *(short8*)(out + (size_t)row * Dq + tid * 8) = uo.s;
}

// ---------------------------------------------------------------------------
// RoPE in-place on q and k (bf16, row stride ld). One thread per (b,s,h,i<64).
// ---------------------------------------------------------------------------
__global__ __launch_bounds__(256)
void rope_k(bf16* __restrict__ q, bf16* __restrict__ k, int ld) {
  const size_t idx = (size_t)blockIdx.x * 256 + threadIdx.x;
  const int i = (int)(idx & 63);
  const int h = (int)((idx >> 6) & 15);
  const int s = (int)((idx >> 10) & 2047);
  const int b = (int)(idx >> 21);
  const float f = (float)s * powf(10000.f, -(float)i * (1.f / 64.f));
  float sn, cs;
  sincosf(f, &sn, &cs);
  const size_t base = ((size_t)(b * Sq + s)) * ld + h * DHq + i;
  const float qa = b2f(q[base]), qb_ = b2f(q[base + 64]);
  q[base] = f2b(qa * cs - qb_ * sn);
  q[base + 64] = f2b(qb_ * cs + qa * sn);
  const float ka = b2f(k[base]), kb_ = b2f(k[base + 64]);
  k[base] = f2b(ka * cs - kb_ * sn);
  k[base + 64] = f2b(kb_ * cs + ka * sn);
}

// ---------------------------------------------------------------------------
// Causal flash attention. Grid (S/64, H, B), 4 waves; wave w owns 16 q-rows.
// q,k,v have row stride ld; o has stride Dq.
// ---------------------------------------------------------------------------
__device__ __forceinline__ int swz8(int row) { return (((row >> 3) ^ row) & 7) << 3; }

__global__ __launch_bounds__(256)
void attn_k(const bf16* __restrict__ q, const bf16* __restrict__ k,
            const bf16* __restrict__ v, bf16* __restrict__ o, int ld) {
  __shared__ __align__(16) bf16 Ks[64][128];
  __shared__ __align__(16) bf16 Vt[128][64];
  __shared__ __align__(16) bf16 Ps[4][16][64];
  const int tid = threadIdx.x;
  const int w = tid >> 6, l = tid & 63;
  const int q0 = blockIdx.x * 64;
  const int h = blockIdx.y;
  const int b = blockIdx.z;
  const size_t hoff = (size_t)h * DHq;
  const float SCALE = 0.08838834764831845f;

  short8 aq[4];
  {
    const bf16* qp = q + ((size_t)(b * Sq + q0 + w * 16 + (l & 15))) * ld + hoff + (l >> 4) * 8;
#pragma unroll
    for (int kk = 0; kk < 4; ++kk) aq[kk] = *(const short8*)(qp + kk * 32);
  }

  float m_run[4], l_run[4];
  f32x4 o_acc[8] = {};
#pragma unroll
  for (int r = 0; r < 4; ++r) { m_run[r] = -3.0e38f; l_run[r] = 0.f; }

  const int ntiles = (q0 >> 6) + 1;
  for (int t = 0; t < ntiles; ++t) {
    const int kv0 = t * 64;
    __syncthreads();
#pragma unroll
    for (int rr = 0; rr < 4; ++rr) {
      const int e = (rr * 256 + tid) * 8;
      const int kr = e >> 7, c = e & 127;
      *(short8*)&Ks[kr][c ^ swz8(kr)] =
          *(const short8*)(k + ((size_t)(b * Sq + kv0 + kr)) * ld + hoff + c);
      union { short8 s; bf16 hh[8]; } uv;
      uv.s = *(const short8*)(v + ((size_t)(b * Sq + kv0 + kr)) * ld + hoff + c);
#pragma unroll
      for (int j = 0; j < 8; ++j) Vt[c + j][kr ^ swz8(c + j)] = uv.hh[j];
    }
    __syncthreads();

    const bool active = (kv0 <= q0 + w * 16 + 15);
    if (active) {
      f32x4 sc[4] = {};
#pragma unroll
      for (int n = 0; n < 4; ++n) {
        const int krow = n * 16 + (l & 15);
        const int sw = swz8(krow);
#pragma unroll
        for (int kk = 0; kk < 4; ++kk) {
          short8 bk = *(const short8*)&Ks[krow][(kk * 32 + (l >> 4) * 8) ^ sw];
          sc[n] = __builtin_amdgcn_mfma_f32_16x16x32_bf16(aq[kk], bk, sc[n], 0, 0, 0);
        }
      }
      const int qg = q0 + w * 16 + (l >> 4) * 4;
      const int kvg = kv0 + (l & 15);
      float p[4][4], tmax[4];
#pragma unroll
      for (int r = 0; r < 4; ++r) tmax[r] = -3.0e38f;
#pragma unroll
      for (int n = 0; n < 4; ++n)
#pragma unroll
        for (int r = 0; r < 4; ++r) {
          float val = sc[n][r] * SCALE;
          if (kvg + n * 16 > qg + r) val = -3.0e38f;
          p[n][r] = val;
          tmax[r] = fmaxf(tmax[r], val);
        }
#pragma unroll
      for (int r = 0; r < 4; ++r) {
#pragma unroll
        for (int mm = 1; mm < 16; mm <<= 1)
          tmax[r] = fmaxf(tmax[r], __shfl_xor(tmax[r], mm));
        const float m_new = fmaxf(m_run[r], tmax[r]);
        const float corr = expf(m_run[r] - m_new);
        float tsum = 0.f;
#pragma unroll
        for (int n = 0; n < 4; ++n) {
          const float pv = expf(p[n][r] - m_new);
          p[n][r] = pv;
          tsum += pv;
        }
#pragma unroll
        for (int mm = 1; mm < 16; mm <<= 1) tsum += __shfl_xor(tsum, mm);
        l_run[r] = l_run[r] * corr + tsum;
        m_run[r] = m_new;
#pragma unroll
        for (int dt = 0; dt < 8; ++dt) o_acc[dt][r] *= corr;
      }
#pragma unroll
      for (int n = 0; n < 4; ++n)
#pragma unroll
        for (int r = 0; r < 4; ++r) {
          const int prow = (l >> 4) * 4 + r;
          Ps[w][prow][(n * 16 + (l & 15)) ^ swz8(prow)] = f2b(p[n][r]);
        }
    }
    __syncthreads();
    if (active) {
      short8 ap[2];
      const int psw = swz8(l & 15);
#pragma unroll
      for (int kk = 0; kk < 2; ++kk)
        ap[kk] = *(const short8*)&Ps[w][l & 15][(kk * 32 + (l >> 4) * 8) ^ psw];
#pragma unroll
      for (int dt = 0; dt < 8; ++dt) {
        const int vrow = dt * 16 + (l & 15);
        const int vsw = swz8(vrow);
#pragma unroll
        for (int kk = 0; kk < 2; ++kk) {
          short8 bv = *(const short8*)&Vt[vrow][(kk * 32 + (l >> 4) * 8) ^ vsw];
          o_acc[dt] = __builtin_amdgcn_mfma_f32_16x16x32_bf16(ap[kk], bv, o_acc[dt], 0, 0, 0);
        }
      }
    }
  }
  const size_t orow = (size_t)(b * Sq + q0 + w * 16 + (l >> 4) * 4);
#pragma unroll
  for (int dt = 0; dt < 8; ++dt)
#pragma unroll
    for (int r = 0; r < 4; ++r)
      o[(orow + r) * Dq + hoff + dt * 16 + (l & 15)] = f2b(o_acc[dt][r] / l_run[r]);
}

// ---------------------------------------------------------------------------
extern "C" void kernel_launch(void* const* d_in, const int* in_sizes, int n_in,
                              void* d_out, int out_size, void* d_ws, size_t ws_size,
                              hipStream_t stream) {
  (void)in_sizes; (void)n_in; (void)out_size;
  const float* x  = (const float*)d_in[0];
  const float* wq = (const float*)d_in[2];
  const float* wk = (const float*)d_in[3];
  const float* wv = (const float*)d_in[4];
  const float* wo = (const float*)d_in[5];
  const float* w1 = (const float*)d_in[6];
  const float* w2 = (const float*)d_in[7];
  const float* w3 = (const float*)d_in[8];
  const float* ga = (const float*)d_in[9];
  const float* gf = (const float*)d_in[10];
  float* out = (float*)d_out;

  char* ws = (char*)d_ws;
  dim3 blk(256);
  dim3 gA(Sq / 64, Hq, Bq);

  // Path A sizes (bytes)
  const size_t SZ_H   = (size_t)Mq * Dq * 2;        // 16.78 MB
  const size_t SZ_QKV = (size_t)Mq * 3 * Dq * 2;    // 50.33 MB
  const size_t SZ_W4  = (size_t)Dq * Dq * 2;        // 8.39 MB (2048x2048)
  const size_t SZ_W13 = (size_t)FFq * Dq * 2;       // 33.55 MB
  const size_t ACT    = SZ_H + SZ_QKV;              // 67.11 MB
  const size_t WTS    = 3 * SZ_W4 + SZ_W4 + 3 * SZ_W13;  // wqkv(3)+wo+w1+w3+w2
  const size_t NEED   = ACT + WTS;                  // ~201.6 MB

  if (ws_size >= NEED) {
    // ---- PATH A: bf16 weights ----
    bf16* h    = (bf16*)(ws);
    bf16* qkv  = (bf16*)(ws + SZ_H);                // [4096][6144]
    bf16* ob   = h;                                  // h dead after QKV gemm
    bf16* h2   = qkv;                                // qkv dead after attn
    bf16* ub   = (bf16*)(ws + SZ_H + SZ_H);          // M x 4096
    char* wb   = ws + ACT;
    bf16* wqkv_b = (bf16*)(wb);                      // [6144][2048]
    bf16* wo_b   = (bf16*)(wb + 3 * SZ_W4);
    bf16* w1_b   = (bf16*)(wb + 4 * SZ_W4);
    bf16* w3_b   = (bf16*)(wb + 4 * SZ_W4 + SZ_W13);
    bf16* w2_b   = (bf16*)(wb + 4 * SZ_W4 + 2 * SZ_W13);

    const long nW4 = (long)Dq * Dq, nW13 = (long)FFq * Dq;
    conv_k<<<1024, blk, 0, stream>>>(wq, wqkv_b, nW4);
    conv_k<<<1024, blk, 0, stream>>>(wk, wqkv_b + nW4, nW4);
    conv_k<<<1024, blk, 0, stream>>>(wv, wqkv_b + 2 * nW4, nW4);
    conv_k<<<1024, blk, 0, stream>>>(wo, wo_b, nW4);
    conv_k<<<2048, blk, 0, stream>>>(w1, w1_b, nW13);
    conv_k<<<2048, blk, 0, stream>>>(w3, w3_b, nW13);
    conv_k<<<2048, blk, 0, stream>>>(w2, w2_b, nW13);

    rmsnorm_k<<<Mq, blk, 0, stream>>>(x, ga, h);
    gemm3<0><<<dim3(48, 32), blk, 0, stream>>>(h, wqkv_b, nullptr, qkv, 6144, Dq, Dq, 0);
    rope_k<<<(Bq * Sq * Hq * 64) / 256, blk, 0, stream>>>(qkv, qkv + Dq, 3 * Dq);
    attn_k<<<gA, blk, 0, stream>>>(qkv, qkv + Dq, qkv + 2 * Dq, ob, 3 * Dq);
    gemm3<1><<<dim3(16, 32), blk, 0, stream>>>(ob, wo_b, x, out, Dq, Dq, Dq, 0);
    rmsnorm_k<<<Mq, blk, 0, stream>>>(out, gf, h2);
    for (int hh = 0; hh < 2; ++hh) {
      bf16* w1h = w1_b + (size_t)hh * 4096 * Dq;
      bf16* w3h = w3_b + (size_t)hh * 4096 * Dq;
      gemm3<0><<<dim3(32, 32), blk, 0, stream>>>(h2, w1h, nullptr, ub, 4096, Dq, Dq, 0);
      gemm3<2><<<dim3(32, 32), blk, 0, stream>>>(h2, w3h, ub, ub, 4096, Dq, Dq, 0);
      gemm3<1><<<dim3(16, 32), blk, 0, stream>>>(ub, w2_b, out, out, Dq, 4096, FFq,
                                                 (long long)hh * 4096);
    }
  } else {
    // ---- PATH B: round-3 verified f32-weight path (64 MiB ws) ----
    const size_t MS = (size_t)Mq * Dq * 2;
    bf16* h  = (bf16*)(ws);
    bf16* kb = (bf16*)(ws + MS);
    bf16* vb = (bf16*)(ws + 2 * MS);
    bf16* qb = (bf16*)(ws + 3 * MS);
    bf16* ub = (bf16*)(ws);
    bf16* ob = h;
    bf16* h2 = qb;

    dim3 gD(Dq / 128, Mq / 128);
    dim3 gU(32, Mq / 128);

    rmsnorm_k<<<Mq, blk, 0, stream>>>(x, ga, h);
    gemm2<0><<<gD, blk, 0, stream>>>(h, wq, nullptr, qb, Dq, Dq, Dq, 0);
    gemm2<0><<<gD, blk, 0, stream>>>(h, wk, nullptr, kb, Dq, Dq, Dq, 0);
    gemm2<0><<<gD, blk, 0, stream>>>(h, wv, nullptr, vb, Dq, Dq, Dq, 0);
    rope_k<<<(Bq * Sq * Hq * 64) / 256, blk, 0, stream>>>(qb, kb, Dq);
    attn_k<<<gA, blk, 0, stream>>>(qb, kb, vb, ob, Dq);
    gemm2<1><<<gD, blk, 0, stream>>>(ob, wo, x, out, Dq, Dq, Dq, 0);
    rmsnorm_k<<<Mq, blk, 0, stream>>>(out, gf, h2);
    for (int hh = 0; hh < 2; ++hh) {
      const long long bo13 = (long long)hh * 4096 * 2048;
      gemm2<0><<<gU, blk, 0, stream>>>(h2, w1, nullptr, ub, 4096, Dq, Dq, bo13);
      gemm2<2><<<gU, blk, 0, stream>>>(h2, w3, ub, ub, 4096, Dq, Dq, bo13);
      gemm2<1><<<gD, blk, 0, stream>>>(ub, w2, out, out, Dq, 4096, FFq,
                                       (long long)hh * 4096);
    }
  }
}

// Round 5
// 1090.279 us; speedup vs baseline: 2.0601x; 1.0002x over previous
//
#include <hip/hip_runtime.h>
#include <hip/hip_bf16.h>
#include <math.h>

typedef __hip_bfloat16 bf16;
typedef short short8 __attribute__((ext_vector_type(8)));
typedef float f32x4 __attribute__((ext_vector_type(4)));

#define Bq 2
#define Sq 2048
#define Dq 2048
#define Hq 16
#define DHq 128
#define FFq 8192
#define Mq 4096  // Bq*Sq

// Inputs/outputs are f32. Internal activations bf16. Weights pre-converted to
// bf16 when ws_size allows (path A); otherwise f32-staged directly (path B).

__device__ __forceinline__ float b2f(bf16 x) { return __bfloat162float(x); }
__device__ __forceinline__ bf16 f2b(float x) { return __float2bfloat16(x); }

// async global->LDS, 16B/lane. LDS dest arg is the wave-uniform BASE; HW places
// lane l at base + l*16.
__device__ __forceinline__ void gload16(const void* g, void* lds_base) {
  __builtin_amdgcn_global_load_lds(
      (const __attribute__((address_space(1))) void*)g,
      (__attribute__((address_space(3))) void*)lds_base,
      16, 0, 0);
}

// ---------------------------------------------------------------------------
// f32 -> bf16 conversion (grid-stride, 8 elems/thread)
// ---------------------------------------------------------------------------
__global__ __launch_bounds__(256)
void conv_k(const float* __restrict__ src, bf16* __restrict__ dst, long n) {
  const long stride = (long)gridDim.x * 256 * 8;
  for (long i = ((long)blockIdx.x * 256 + threadIdx.x) * 8; i < n; i += stride) {
    f32x4 a = *(const f32x4*)(src + i);
    f32x4 b = *(const f32x4*)(src + i + 4);
    union { short8 s; bf16 h[8]; } u;
#pragma unroll
    for (int j = 0; j < 4; ++j) { u.h[j] = f2b(a[j]); u.h[j + 4] = f2b(b[j]); }
    *(short8*)(dst + i) = u.s;
  }
}

// ---------------------------------------------------------------------------
// PATH A GEMM: C[M,N] = A[M,K](bf16) * Bt[N,K](bf16)^T
// EPI 0: C(bf16) = acc
// EPI 1: C(f32)  = R(f32) + acc        (residual)
// EPI 2: C(bf16) = silu(R(bf16)) * acc (SwiGLU)
// 128x128 tile, BK=64, 4 waves (2x2). Both operands via global_load_lds with
// the XOR-8 block swizzle applied on source AND read (rule #21).
// ---------------------------------------------------------------------------
template <int EPI>
__global__ __launch_bounds__(256)
void gemm3(const bf16* __restrict__ A, const bf16* __restrict__ Bt,
           const void* __restrict__ R, void* __restrict__ C,
           int N, int K, int ldb, long long boff) {
  __shared__ __align__(16) bf16 As[128][64];
  __shared__ __align__(16) bf16 Bs[128][64];
  const int tid = threadIdx.x;
  const int w = tid >> 6;
  const int l = tid & 63;

  // bijective XCD swizzle (T1, m204)
  const int nwg = gridDim.x * gridDim.y;
  const int orig = blockIdx.x + blockIdx.y * gridDim.x;
  const int qq = nwg >> 3, rr8 = nwg & 7;
  const int xcd = orig & 7, idx8 = orig >> 3;
  const int wg = (xcd < rr8 ? xcd * (qq + 1) : rr8 * (qq + 1) + (xcd - rr8) * qq) + idx8;
  const int bm = (wg / gridDim.x) * 128;
  const int bn = (wg % gridDim.x) * 128;

  const int wr = (w >> 1) * 64;
  const int wc = (w & 1) * 64;
  f32x4 acc[4][4] = {};

  const bf16* Ab = A + (size_t)bm * K;
  const bf16* Bb = Bt + (size_t)bn * ldb + (size_t)boff;

  // staging: lane l covers row (l>>3) within each 8-row group, 16B block (l&7).
  // pre-swizzled source so linear DMA dest => physical block = logical ^ (row&7)
  const int sRow = w * 8 + (l >> 3);                 // + i*32
  const int sCol = (((l & 7) ^ (l >> 3)) << 3);      // bf16 elems

  for (int kt = 0; kt < K; kt += 64) {
    __syncthreads();  // prev tile's LDS reads done
#pragma unroll
    for (int i = 0; i < 4; ++i) {
      gload16(Ab + (size_t)(i * 32 + sRow) * K + kt + sCol, &As[i * 32 + w * 8][0]);
      gload16(Bb + (size_t)(i * 32 + sRow) * ldb + kt + sCol, &Bs[i * 32 + w * 8][0]);
    }
    __syncthreads();  // vmcnt(0) drained before barrier

#pragma unroll
    for (int kk = 0; kk < 2; ++kk) {
      short8 af[4], bfv[4];
#pragma unroll
      for (int m = 0; m < 4; ++m) {
        const int ra = wr + m * 16 + (l & 15);
        af[m] = *(const short8*)&As[ra][(((kk * 4 + (l >> 4)) ^ (ra & 7)) << 3)];
      }
#pragma unroll
      for (int n = 0; n < 4; ++n) {
        const int rb = wc + n * 16 + (l & 15);
        bfv[n] = *(const short8*)&Bs[rb][(((kk * 4 + (l >> 4)) ^ (rb & 7)) << 3)];
      }
#pragma unroll
      for (int m = 0; m < 4; ++m)
#pragma unroll
        for (int n = 0; n < 4; ++n)
          acc[m][n] = __builtin_amdgcn_mfma_f32_16x16x32_bf16(af[m], bfv[n], acc[m][n], 0, 0, 0);
    }
  }

  // epilogue: C/D layout col = lane&15, row = (lane>>4)*4 + reg
  const int rbase = bm + wr + (l >> 4) * 4;
  const int cbase = bn + wc + (l & 15);
#pragma unroll
  for (int m = 0; m < 4; ++m)
#pragma unroll
    for (int r = 0; r < 4; ++r) {
      const int row = rbase + m * 16 + r;
#pragma unroll
      for (int n = 0; n < 4; ++n) {
        const size_t idx = (size_t)row * N + (cbase + n * 16);
        float vacc = acc[m][n][r];
        if (EPI == 1) {
          ((float*)C)[idx] = vacc + ((const float*)R)[idx];
        } else if (EPI == 2) {
          const float u = b2f(((const bf16*)R)[idx]);
          ((bf16*)C)[idx] = f2b((u / (1.f + expf(-u))) * vacc);
        } else {
          ((bf16*)C)[idx] = f2b(vacc);
        }
      }
    }
}

// ---------------------------------------------------------------------------
// PATH B GEMM (round-3 verified): B operand f32, staged via gload_lds.
// ---------------------------------------------------------------------------
template <int EPI>
__global__ __launch_bounds__(256)
void gemm2(const bf16* __restrict__ A, const float* __restrict__ Bt,
           const void* __restrict__ R, void* __restrict__ C,
           int N, int K, int ldb, long long boff) {
  __shared__ __align__(16) bf16 As[128][64];
  __shared__ __align__(16) float Bsf[128][64];
  const int tid = threadIdx.x;
  const int w = tid >> 6;
  const int l = tid & 63;

  const int nwg = gridDim.x * gridDim.y;
  const int orig = blockIdx.x + blockIdx.y * gridDim.x;
  const int qq = nwg >> 3, rr8 = nwg & 7;
  const int xcd = orig & 7, idx8 = orig >> 3;
  const int wg = (xcd < rr8 ? xcd * (qq + 1) : rr8 * (qq + 1) + (xcd - rr8) * qq) + idx8;
  const int bm = (wg / gridDim.x) * 128;
  const int bn = (wg % gridDim.x) * 128;

  const int wr = (w >> 1) * 64;
  const int wc = (w & 1) * 64;
  f32x4 acc[4][4] = {};

  const bf16* Ab = A + (size_t)bm * K;
  const float* Bb = Bt + (size_t)bn * ldb + (size_t)boff;

  const int aSrcCol = (((l & 7) ^ (l >> 3)) << 3);
  const int bKey = (w * 4 + (l >> 4)) & 7;
  const int bSrcCol = (((l & 15) ^ bKey) << 2);

  for (int kt = 0; kt < K; kt += 64) {
    __syncthreads();
#pragma unroll
    for (int i = 0; i < 4; ++i)
      gload16(Ab + (size_t)(i * 32 + w * 8 + (l >> 3)) * K + kt + aSrcCol,
              &As[i * 32 + w * 8][0]);
#pragma unroll
    for (int i = 0; i < 8; ++i)
      gload16(Bb + (size_t)(i * 16 + w * 4 + (l >> 4)) * ldb + kt + bSrcCol,
              &Bsf[i * 16 + w * 4][0]);
    __syncthreads();

#pragma unroll
    for (int kk = 0; kk < 2; ++kk) {
      short8 af[4], bfv[4];
#pragma unroll
      for (int m = 0; m < 4; ++m) {
        const int ra = wr + m * 16 + (l & 15);
        const int pb = (kk * 4 + (l >> 4)) ^ (ra & 7);
        af[m] = *(const short8*)&As[ra][pb * 8];
      }
#pragma unroll
      for (int n = 0; n < 4; ++n) {
        const int rb = wc + n * 16 + (l & 15);
        const int b0 = kk * 8 + (l >> 4) * 2;
        const f32x4 x0 = *(const f32x4*)&Bsf[rb][(b0 ^ (rb & 7)) * 4];
        const f32x4 x1 = *(const f32x4*)&Bsf[rb][((b0 + 1) ^ (rb & 7)) * 4];
        union { short8 s; bf16 h[8]; } u;
#pragma unroll
        for (int j = 0; j < 4; ++j) { u.h[j] = f2b(x0[j]); u.h[j + 4] = f2b(x1[j]); }
        bfv[n] = u.s;
      }
#pragma unroll
      for (int m = 0; m < 4; ++m)
#pragma unroll
        for (int n = 0; n < 4; ++n)
          acc[m][n] = __builtin_amdgcn_mfma_f32_16x16x32_bf16(af[m], bfv[n], acc[m][n], 0, 0, 0);
    }
  }

  const int rbase = bm + wr + (l >> 4) * 4;
  const int cbase = bn + wc + (l & 15);
#pragma unroll
  for (int m = 0; m < 4; ++m)
#pragma unroll
    for (int r = 0; r < 4; ++r) {
      const int row = rbase + m * 16 + r;
#pragma unroll
      for (int n = 0; n < 4; ++n) {
        const size_t idx = (size_t)row * N + (cbase + n * 16);
        float vacc = acc[m][n][r];
        if (EPI == 1) {
          ((float*)C)[idx] = vacc + ((const float*)R)[idx];
        } else if (EPI == 2) {
          const float u = b2f(((const bf16*)R)[idx]);
          ((bf16*)C)[idx] = f2b((u / (1.f + expf(-u))) * vacc);
        } else {
          ((bf16*)C)[idx] = f2b(vacc);
        }
      }
    }
}

// ---------------------------------------------------------------------------
// RMSNorm: one block per row of 2048. f32 in, f32 g, bf16 out.
// ---------------------------------------------------------------------------
__global__ __launch_bounds__(256)
void rmsnorm_k(const float* __restrict__ xin, const float* __restrict__ g,
               bf16* __restrict__ out) {
  const int row = blockIdx.x;
  const int tid = threadIdx.x;
  const float* xp = xin + (size_t)row * Dq + tid * 8;
  f32x4 a = *(const f32x4*)xp, b = *(const f32x4*)(xp + 4);
  float xf[8];
#pragma unroll
  for (int j = 0; j < 4; ++j) { xf[j] = a[j]; xf[j + 4] = b[j]; }
  float ss = 0.f;
#pragma unroll
  for (int j = 0; j < 8; ++j) ss += xf[j] * xf[j];
#pragma unroll
  for (int off = 32; off > 0; off >>= 1) ss += __shfl_down(ss, off);
  __shared__ float red[4];
  if ((tid & 63) == 0) red[tid >> 6] = ss;
  __syncthreads();
  const float rms = rsqrtf((red[0] + red[1] + red[2] + red[3]) * (1.f / (float)Dq) + 1e-6f);
  const float* gp = g + tid * 8;
  f32x4 ga = *(const f32x4*)gp, gb = *(const f32x4*)(gp + 4);
  union { short8 s; bf16 h[8]; } uo;
#pragma unroll
  for (int j = 0; j < 4; ++j) {
    uo.h[j] = f2b(xf[j] * rms * ga[j]);
    uo.h[j + 4] = f2b(xf[j + 4] * rms * gb[j]);
  }
  *(short8*)(out + (size_t)row * Dq + tid * 8) = uo.s;
}

// ---------------------------------------------------------------------------
// RoPE in-place on q and k (bf16, row stride ld). One thread per (b,s,h,i<64).
// ---------------------------------------------------------------------------
__global__ __launch_bounds__(256)
void rope_k(bf16* __restrict__ q, bf16* __restrict__ k, int ld) {
  const size_t idx = (size_t)blockIdx.x * 256 + threadIdx.x;
  const int i = (int)(idx & 63);
  const int h = (int)((idx >> 6) & 15);
  const int s = (int)((idx >> 10) & 2047);
  const int b = (int)(idx >> 21);
  const float f = (float)s * powf(10000.f, -(float)i * (1.f / 64.f));
  float sn, cs;
  sincosf(f, &sn, &cs);
  const size_t base = ((size_t)(b * Sq + s)) * ld + h * DHq + i;
  const float qa = b2f(q[base]), qb_ = b2f(q[base + 64]);
  q[base] = f2b(qa * cs - qb_ * sn);
  q[base + 64] = f2b(qb_ * cs + qa * sn);
  const float ka = b2f(k[base]), kb_ = b2f(k[base + 64]);
  k[base] = f2b(ka * cs - kb_ * sn);
  k[base + 64] = f2b(kb_ * cs + ka * sn);
}

// ---------------------------------------------------------------------------
// Causal flash attention. Grid (S/64, H, B), 4 waves; wave w owns 16 q-rows.
// q,k,v have row stride ld; o has stride Dq.
// q-tile index REVERSED vs blockIdx.x: heavy (diagonal-distant) blocks
// dispatch first -> LPT packing, fixes the 11%-occupancy tail.
// ---------------------------------------------------------------------------
__device__ __forceinline__ int swz8(int row) { return (((row >> 3) ^ row) & 7) << 3; }

__global__ __launch_bounds__(256)
void attn_k(const bf16* __restrict__ q, const bf16* __restrict__ k,
            const bf16* __restrict__ v, bf16* __restrict__ o, int ld) {
  __shared__ __align__(16) bf16 Ks[64][128];
  __shared__ __align__(16) bf16 Vt[128][64];
  __shared__ __align__(16) bf16 Ps[4][16][64];
  const int tid = threadIdx.x;
  const int w = tid >> 6, l = tid & 63;
  const int q0 = (gridDim.x - 1 - blockIdx.x) * 64;  // heavy blocks first
  const int h = blockIdx.y;
  const int b = blockIdx.z;
  const size_t hoff = (size_t)h * DHq;
  const float SCALE = 0.08838834764831845f;

  short8 aq[4];
  {
    const bf16* qp = q + ((size_t)(b * Sq + q0 + w * 16 + (l & 15))) * ld + hoff + (l >> 4) * 8;
#pragma unroll
    for (int kk = 0; kk < 4; ++kk) aq[kk] = *(const short8*)(qp + kk * 32);
  }

  float m_run[4], l_run[4];
  f32x4 o_acc[8] = {};
#pragma unroll
  for (int r = 0; r < 4; ++r) { m_run[r] = -3.0e38f; l_run[r] = 0.f; }

  const int ntiles = (q0 >> 6) + 1;
  for (int t = 0; t < ntiles; ++t) {
    const int kv0 = t * 64;
    __syncthreads();
#pragma unroll
    for (int rr = 0; rr < 4; ++rr) {
      const int e = (rr * 256 + tid) * 8;
      const int kr = e >> 7, c = e & 127;
      *(short8*)&Ks[kr][c ^ swz8(kr)] =
          *(const short8*)(k + ((size_t)(b * Sq + kv0 + kr)) * ld + hoff + c);
      union { short8 s; bf16 hh[8]; } uv;
      uv.s = *(const short8*)(v + ((size_t)(b * Sq + kv0 + kr)) * ld + hoff + c);
#pragma unroll
      for (int j = 0; j < 8; ++j) Vt[c + j][kr ^ swz8(c + j)] = uv.hh[j];
    }
    __syncthreads();

    const bool active = (kv0 <= q0 + w * 16 + 15);
    if (active) {
      f32x4 sc[4] = {};
      __builtin_amdgcn_s_setprio(1);  // T5: favor MFMA wave (m191: +4-7% attn)
#pragma unroll
      for (int n = 0; n < 4; ++n) {
        const int krow = n * 16 + (l & 15);
        const int sw = swz8(krow);
#pragma unroll
        for (int kk = 0; kk < 4; ++kk) {
          short8 bk = *(const short8*)&Ks[krow][(kk * 32 + (l >> 4) * 8) ^ sw];
          sc[n] = __builtin_amdgcn_mfma_f32_16x16x32_bf16(aq[kk], bk, sc[n], 0, 0, 0);
        }
      }
      __builtin_amdgcn_s_setprio(0);
      const int qg = q0 + w * 16 + (l >> 4) * 4;
      const int kvg = kv0 + (l & 15);
      float p[4][4], tmax[4];
#pragma unroll
      for (int r = 0; r < 4; ++r) tmax[r] = -3.0e38f;
#pragma unroll
      for (int n = 0; n < 4; ++n)
#pragma unroll
        for (int r = 0; r < 4; ++r) {
          float val = sc[n][r] * SCALE;
          if (kvg + n * 16 > qg + r) val = -3.0e38f;
          p[n][r] = val;
          tmax[r] = fmaxf(tmax[r], val);
        }
#pragma unroll
      for (int r = 0; r < 4; ++r) {
#pragma unroll
        for (int mm = 1; mm < 16; mm <<= 1)
          tmax[r] = fmaxf(tmax[r], __shfl_xor(tmax[r], mm));
        const float m_new = fmaxf(m_run[r], tmax[r]);
        const float corr = expf(m_run[r] - m_new);
        float tsum = 0.f;
#pragma unroll
        for (int n = 0; n < 4; ++n) {
          const float pv = expf(p[n][r] - m_new);
          p[n][r] = pv;
          tsum += pv;
        }
#pragma unroll
        for (int mm = 1; mm < 16; mm <<= 1) tsum += __shfl_xor(tsum, mm);
        l_run[r] = l_run[r] * corr + tsum;
        m_run[r] = m_new;
#pragma unroll
        for (int dt = 0; dt < 8; ++dt) o_acc[dt][r] *= corr;
      }
#pragma unroll
      for (int n = 0; n < 4; ++n)
#pragma unroll
        for (int r = 0; r < 4; ++r) {
          const int prow = (l >> 4) * 4 + r;
          Ps[w][prow][(n * 16 + (l & 15)) ^ swz8(prow)] = f2b(p[n][r]);
        }
    }
    __syncthreads();
    if (active) {
      short8 ap[2];
      const int psw = swz8(l & 15);
#pragma unroll
      for (int kk = 0; kk < 2; ++kk)
        ap[kk] = *(const short8*)&Ps[w][l & 15][(kk * 32 + (l >> 4) * 8) ^ psw];
      __builtin_amdgcn_s_setprio(1);
#pragma unroll
      for (int dt = 0; dt < 8; ++dt) {
        const int vrow = dt * 16 + (l & 15);
        const int vsw = swz8(vrow);
#pragma unroll
        for (int kk = 0; kk < 2; ++kk) {
          short8 bv = *(const short8*)&Vt[vrow][(kk * 32 + (l >> 4) * 8) ^ vsw];
          o_acc[dt] = __builtin_amdgcn_mfma_f32_16x16x32_bf16(ap[kk], bv, o_acc[dt], 0, 0, 0);
        }
      }
      __builtin_amdgcn_s_setprio(0);
    }
  }
  const size_t orow = (size_t)(b * Sq + q0 + w * 16 + (l >> 4) * 4);
#pragma unroll
  for (int dt = 0; dt < 8; ++dt)
#pragma unroll
    for (int r = 0; r < 4; ++r)
      o[(orow + r) * Dq + hoff + dt * 16 + (l & 15)] = f2b(o_acc[dt][r] / l_run[r]);
}

// ---------------------------------------------------------------------------
extern "C" void kernel_launch(void* const* d_in, const int* in_sizes, int n_in,
                              void* d_out, int out_size, void* d_ws, size_t ws_size,
                              hipStream_t stream) {
  (void)in_sizes; (void)n_in; (void)out_size;
  const float* x  = (const float*)d_in[0];
  const float* wq = (const float*)d_in[2];
  const float* wk = (const float*)d_in[3];
  const float* wv = (const float*)d_in[4];
  const float* wo = (const float*)d_in[5];
  const float* w1 = (const float*)d_in[6];
  const float* w2 = (const float*)d_in[7];
  const float* w3 = (const float*)d_in[8];
  const float* ga = (const float*)d_in[9];
  const float* gf = (const float*)d_in[10];
  float* out = (float*)d_out;

  char* ws = (char*)d_ws;
  dim3 blk(256);
  dim3 gA(Sq / 64, Hq, Bq);

  // Path A sizes (bytes)
  const size_t SZ_H   = (size_t)Mq * Dq * 2;        // 16.78 MB
  const size_t SZ_QKV = (size_t)Mq * 3 * Dq * 2;    // 50.33 MB
  const size_t SZ_W4  = (size_t)Dq * Dq * 2;        // 8.39 MB
  const size_t SZ_W13 = (size_t)FFq * Dq * 2;       // 33.55 MB
  const size_t ACT    = SZ_H + SZ_QKV;              // 67.11 MB
  const size_t WTS    = 3 * SZ_W4 + SZ_W4 + 3 * SZ_W13;
  const size_t NEED   = ACT + WTS;                  // ~201.6 MB

  if (ws_size >= NEED) {
    // ---- PATH A: bf16 weights ----
    bf16* h    = (bf16*)(ws);
    bf16* qkv  = (bf16*)(ws + SZ_H);                // [4096][6144]
    bf16* ob   = h;
    bf16* h2   = qkv;
    bf16* ub   = (bf16*)(ws + SZ_H + SZ_H);         // M x 4096
    char* wb   = ws + ACT;
    bf16* wqkv_b = (bf16*)(wb);                     // [6144][2048]
    bf16* wo_b   = (bf16*)(wb + 3 * SZ_W4);
    bf16* w1_b   = (bf16*)(wb + 4 * SZ_W4);
    bf16* w3_b   = (bf16*)(wb + 4 * SZ_W4 + SZ_W13);
    bf16* w2_b   = (bf16*)(wb + 4 * SZ_W4 + 2 * SZ_W13);

    const long nW4 = (long)Dq * Dq, nW13 = (long)FFq * Dq;
    conv_k<<<1024, blk, 0, stream>>>(wq, wqkv_b, nW4);
    conv_k<<<1024, blk, 0, stream>>>(wk, wqkv_b + nW4, nW4);
    conv_k<<<1024, blk, 0, stream>>>(wv, wqkv_b + 2 * nW4, nW4);
    conv_k<<<1024, blk, 0, stream>>>(wo, wo_b, nW4);
    conv_k<<<2048, blk, 0, stream>>>(w1, w1_b, nW13);
    conv_k<<<2048, blk, 0, stream>>>(w3, w3_b, nW13);
    conv_k<<<2048, blk, 0, stream>>>(w2, w2_b, nW13);

    rmsnorm_k<<<Mq, blk, 0, stream>>>(x, ga, h);
    gemm3<0><<<dim3(48, 32), blk, 0, stream>>>(h, wqkv_b, nullptr, qkv, 6144, Dq, Dq, 0);
    rope_k<<<(Bq * Sq * Hq * 64) / 256, blk, 0, stream>>>(qkv, qkv + Dq, 3 * Dq);
    attn_k<<<gA, blk, 0, stream>>>(qkv, qkv + Dq, qkv + 2 * Dq, ob, 3 * Dq);
    gemm3<1><<<dim3(16, 32), blk, 0, stream>>>(ob, wo_b, x, out, Dq, Dq, Dq, 0);
    rmsnorm_k<<<Mq, blk, 0, stream>>>(out, gf, h2);
    for (int hh = 0; hh < 2; ++hh) {
      bf16* w1h = w1_b + (size_t)hh * 4096 * Dq;
      bf16* w3h = w3_b + (size_t)hh * 4096 * Dq;
      gemm3<0><<<dim3(32, 32), blk, 0, stream>>>(h2, w1h, nullptr, ub, 4096, Dq, Dq, 0);
      gemm3<2><<<dim3(32, 32), blk, 0, stream>>>(h2, w3h, ub, ub, 4096, Dq, Dq, 0);
      gemm3<1><<<dim3(16, 32), blk, 0, stream>>>(ub, w2_b, out, out, Dq, 4096, FFq,
                                                 (long long)hh * 4096);
    }
  } else {
    // ---- PATH B: round-3 verified f32-weight path (64 MiB ws) ----
    const size_t MS = (size_t)Mq * Dq * 2;
    bf16* h  = (bf16*)(ws);
    bf16* kb = (bf16*)(ws + MS);
    bf16* vb = (bf16*)(ws + 2 * MS);
    bf16* qb = (bf16*)(ws + 3 * MS);
    bf16* ub = (bf16*)(ws);
    bf16* ob = h;
    bf16* h2 = qb;

    dim3 gD(Dq / 128, Mq / 128);
    dim3 gU(32, Mq / 128);

    rmsnorm_k<<<Mq, blk, 0, stream>>>(x, ga, h);
    gemm2<0><<<gD, blk, 0, stream>>>(h, wq, nullptr, qb, Dq, Dq, Dq, 0);
    gemm2<0><<<gD, blk, 0, stream>>>(h, wk, nullptr, kb, Dq, Dq, Dq, 0);
    gemm2<0><<<gD, blk, 0, stream>>>(h, wv, nullptr, vb, Dq, Dq, Dq, 0);
    rope_k<<<(Bq * Sq * Hq * 64) / 256, blk, 0, stream>>>(qb, kb, Dq);
    attn_k<<<gA, blk, 0, stream>>>(qb, kb, vb, ob, Dq);
    gemm2<1><<<gD, blk, 0, stream>>>(ob, wo, x, out, Dq, Dq, Dq, 0);
    rmsnorm_k<<<Mq, blk, 0, stream>>>(out, gf, h2);
    for (int hh = 0; hh < 2; ++hh) {
      const long long bo13 = (long long)hh * 4096 * 2048;
      gemm2<0><<<gU, blk, 0, stream>>>(h2, w1, nullptr, ub, 4096, Dq, Dq, bo13);
      gemm2<2><<<gU, blk, 0, stream>>>(h2, w3, ub, ub, 4096, Dq, Dq, bo13);
      gemm2<1><<<gD, blk, 0, stream>>>(ub, w2, out, out, Dq, 4096, FFq,
                                       (long long)hh * 4096);
    }
  }
}

// Round 6
// 1040.930 us; speedup vs baseline: 2.1578x; 1.0474x over previous
//
#include <hip/hip_runtime.h>
#include <hip/hip_bf16.h>
#include <math.h>

typedef __hip_bfloat16 bf16;
typedef short short8 __attribute__((ext_vector_type(8)));
typedef float f32x4 __attribute__((ext_vector_type(4)));

#define Bq 2
#define Sq 2048
#define Dq 2048
#define Hq 16
#define DHq 128
#define FFq 8192
#define Mq 4096  // Bq*Sq

// Inputs/outputs are f32. Internal activations bf16. Weights pre-converted to
// bf16 when ws_size allows (path A); otherwise f32-staged directly (path B).

__device__ __forceinline__ float b2f(bf16 x) { return __bfloat162float(x); }
__device__ __forceinline__ bf16 f2b(float x) { return __float2bfloat16(x); }

// async global->LDS, 16B/lane. LDS dest arg is the wave-uniform BASE; HW places
// lane l at base + l*16.
__device__ __forceinline__ void gload16(const void* g, void* lds_base) {
  __builtin_amdgcn_global_load_lds(
      (const __attribute__((address_space(1))) void*)g,
      (__attribute__((address_space(3))) void*)lds_base,
      16, 0, 0);
}

// ---------------------------------------------------------------------------
// f32 -> bf16 conversion (grid-stride, 8 elems/thread)
// ---------------------------------------------------------------------------
__global__ __launch_bounds__(256)
void conv_k(const float* __restrict__ src, bf16* __restrict__ dst, long n) {
  const long stride = (long)gridDim.x * 256 * 8;
  for (long i = ((long)blockIdx.x * 256 + threadIdx.x) * 8; i < n; i += stride) {
    f32x4 a = *(const f32x4*)(src + i);
    f32x4 b = *(const f32x4*)(src + i + 4);
    union { short8 s; bf16 h[8]; } u;
#pragma unroll
    for (int j = 0; j < 4; ++j) { u.h[j] = f2b(a[j]); u.h[j + 4] = f2b(b[j]); }
    *(short8*)(dst + i) = u.s;
  }
}

// ---------------------------------------------------------------------------
// PATH A GEMM: C[M,N] = A[M,K](bf16) * Bt[N,K](bf16)^T
// EPI 0: C(bf16) = acc ; EPI 1: C(f32) = R(f32)+acc ; EPI 2: C(bf16)=silu(R)*acc
// 128x128 tile, BK=64, 4 waves (2x2). Both operands via global_load_lds with
// the XOR-8 block swizzle applied on source AND read (rule #21).
// ---------------------------------------------------------------------------
template <int EPI>
__global__ __launch_bounds__(256)
void gemm3(const bf16* __restrict__ A, const bf16* __restrict__ Bt,
           const void* __restrict__ R, void* __restrict__ C,
           int N, int K, int ldb, long long boff) {
  __shared__ __align__(16) bf16 As[128][64];
  __shared__ __align__(16) bf16 Bs[128][64];
  const int tid = threadIdx.x;
  const int w = tid >> 6;
  const int l = tid & 63;

  // bijective XCD swizzle (T1, m204)
  const int nwg = gridDim.x * gridDim.y;
  const int orig = blockIdx.x + blockIdx.y * gridDim.x;
  const int qq = nwg >> 3, rr8 = nwg & 7;
  const int xcd = orig & 7, idx8 = orig >> 3;
  const int wg = (xcd < rr8 ? xcd * (qq + 1) : rr8 * (qq + 1) + (xcd - rr8) * qq) + idx8;
  const int bm = (wg / gridDim.x) * 128;
  const int bn = (wg % gridDim.x) * 128;

  const int wr = (w >> 1) * 64;
  const int wc = (w & 1) * 64;
  f32x4 acc[4][4] = {};

  const bf16* Ab = A + (size_t)bm * K;
  const bf16* Bb = Bt + (size_t)bn * ldb + (size_t)boff;

  const int sRow = w * 8 + (l >> 3);
  const int sCol = (((l & 7) ^ (l >> 3)) << 3);

  for (int kt = 0; kt < K; kt += 64) {
    __syncthreads();
#pragma unroll
    for (int i = 0; i < 4; ++i) {
      gload16(Ab + (size_t)(i * 32 + sRow) * K + kt + sCol, &As[i * 32 + w * 8][0]);
      gload16(Bb + (size_t)(i * 32 + sRow) * ldb + kt + sCol, &Bs[i * 32 + w * 8][0]);
    }
    __syncthreads();

#pragma unroll
    for (int kk = 0; kk < 2; ++kk) {
      short8 af[4], bfv[4];
#pragma unroll
      for (int m = 0; m < 4; ++m) {
        const int ra = wr + m * 16 + (l & 15);
        af[m] = *(const short8*)&As[ra][(((kk * 4 + (l >> 4)) ^ (ra & 7)) << 3)];
      }
#pragma unroll
      for (int n = 0; n < 4; ++n) {
        const int rb = wc + n * 16 + (l & 15);
        bfv[n] = *(const short8*)&Bs[rb][(((kk * 4 + (l >> 4)) ^ (rb & 7)) << 3)];
      }
#pragma unroll
      for (int m = 0; m < 4; ++m)
#pragma unroll
        for (int n = 0; n < 4; ++n)
          acc[m][n] = __builtin_amdgcn_mfma_f32_16x16x32_bf16(af[m], bfv[n], acc[m][n], 0, 0, 0);
    }
  }

  const int rbase = bm + wr + (l >> 4) * 4;
  const int cbase = bn + wc + (l & 15);
#pragma unroll
  for (int m = 0; m < 4; ++m)
#pragma unroll
    for (int r = 0; r < 4; ++r) {
      const int row = rbase + m * 16 + r;
#pragma unroll
      for (int n = 0; n < 4; ++n) {
        const size_t idx = (size_t)row * N + (cbase + n * 16);
        float vacc = acc[m][n][r];
        if (EPI == 1) {
          ((float*)C)[idx] = vacc + ((const float*)R)[idx];
        } else if (EPI == 2) {
          const float u = b2f(((const bf16*)R)[idx]);
          ((bf16*)C)[idx] = f2b((u / (1.f + expf(-u))) * vacc);
        } else {
          ((bf16*)C)[idx] = f2b(vacc);
        }
      }
    }
}

// ---------------------------------------------------------------------------
// PATH B GEMM (round-3 verified): B operand f32, staged via gload_lds.
// ---------------------------------------------------------------------------
template <int EPI>
__global__ __launch_bounds__(256)
void gemm2(const bf16* __restrict__ A, const float* __restrict__ Bt,
           const void* __restrict__ R, void* __restrict__ C,
           int N, int K, int ldb, long long boff) {
  __shared__ __align__(16) bf16 As[128][64];
  __shared__ __align__(16) float Bsf[128][64];
  const int tid = threadIdx.x;
  const int w = tid >> 6;
  const int l = tid & 63;

  const int nwg = gridDim.x * gridDim.y;
  const int orig = blockIdx.x + blockIdx.y * gridDim.x;
  const int qq = nwg >> 3, rr8 = nwg & 7;
  const int xcd = orig & 7, idx8 = orig >> 3;
  const int wg = (xcd < rr8 ? xcd * (qq + 1) : rr8 * (qq + 1) + (xcd - rr8) * qq) + idx8;
  const int bm = (wg / gridDim.x) * 128;
  const int bn = (wg % gridDim.x) * 128;

  const int wr = (w >> 1) * 64;
  const int wc = (w & 1) * 64;
  f32x4 acc[4][4] = {};

  const bf16* Ab = A + (size_t)bm * K;
  const float* Bb = Bt + (size_t)bn * ldb + (size_t)boff;

  const int aSrcCol = (((l & 7) ^ (l >> 3)) << 3);
  const int bKey = (w * 4 + (l >> 4)) & 7;
  const int bSrcCol = (((l & 15) ^ bKey) << 2);

  for (int kt = 0; kt < K; kt += 64) {
    __syncthreads();
#pragma unroll
    for (int i = 0; i < 4; ++i)
      gload16(Ab + (size_t)(i * 32 + w * 8 + (l >> 3)) * K + kt + aSrcCol,
              &As[i * 32 + w * 8][0]);
#pragma unroll
    for (int i = 0; i < 8; ++i)
      gload16(Bb + (size_t)(i * 16 + w * 4 + (l >> 4)) * ldb + kt + bSrcCol,
              &Bsf[i * 16 + w * 4][0]);
    __syncthreads();

#pragma unroll
    for (int kk = 0; kk < 2; ++kk) {
      short8 af[4], bfv[4];
#pragma unroll
      for (int m = 0; m < 4; ++m) {
        const int ra = wr + m * 16 + (l & 15);
        const int pb = (kk * 4 + (l >> 4)) ^ (ra & 7);
        af[m] = *(const short8*)&As[ra][pb * 8];
      }
#pragma unroll
      for (int n = 0; n < 4; ++n) {
        const int rb = wc + n * 16 + (l & 15);
        const int b0 = kk * 8 + (l >> 4) * 2;
        const f32x4 x0 = *(const f32x4*)&Bsf[rb][(b0 ^ (rb & 7)) * 4];
        const f32x4 x1 = *(const f32x4*)&Bsf[rb][((b0 + 1) ^ (rb & 7)) * 4];
        union { short8 s; bf16 h[8]; } u;
#pragma unroll
        for (int j = 0; j < 4; ++j) { u.h[j] = f2b(x0[j]); u.h[j + 4] = f2b(x1[j]); }
        bfv[n] = u.s;
      }
#pragma unroll
      for (int m = 0; m < 4; ++m)
#pragma unroll
        for (int n = 0; n < 4; ++n)
          acc[m][n] = __builtin_amdgcn_mfma_f32_16x16x32_bf16(af[m], bfv[n], acc[m][n], 0, 0, 0);
    }
  }

  const int rbase = bm + wr + (l >> 4) * 4;
  const int cbase = bn + wc + (l & 15);
#pragma unroll
  for (int m = 0; m < 4; ++m)
#pragma unroll
    for (int r = 0; r < 4; ++r) {
      const int row = rbase + m * 16 + r;
#pragma unroll
      for (int n = 0; n < 4; ++n) {
        const size_t idx = (size_t)row * N + (cbase + n * 16);
        float vacc = acc[m][n][r];
        if (EPI == 1) {
          ((float*)C)[idx] = vacc + ((const float*)R)[idx];
        } else if (EPI == 2) {
          const float u = b2f(((const bf16*)R)[idx]);
          ((bf16*)C)[idx] = f2b((u / (1.f + expf(-u))) * vacc);
        } else {
          ((bf16*)C)[idx] = f2b(vacc);
        }
      }
    }
}

// ---------------------------------------------------------------------------
// RMSNorm: one block per row of 2048. f32 in, f32 g, bf16 out.
// ---------------------------------------------------------------------------
__global__ __launch_bounds__(256)
void rmsnorm_k(const float* __restrict__ xin, const float* __restrict__ g,
               bf16* __restrict__ out) {
  const int row = blockIdx.x;
  const int tid = threadIdx.x;
  const float* xp = xin + (size_t)row * Dq + tid * 8;
  f32x4 a = *(const f32x4*)xp, b = *(const f32x4*)(xp + 4);
  float xf[8];
#pragma unroll
  for (int j = 0; j < 4; ++j) { xf[j] = a[j]; xf[j + 4] = b[j]; }
  float ss = 0.f;
#pragma unroll
  for (int j = 0; j < 8; ++j) ss += xf[j] * xf[j];
#pragma unroll
  for (int off = 32; off > 0; off >>= 1) ss += __shfl_down(ss, off);
  __shared__ float red[4];
  if ((tid & 63) == 0) red[tid >> 6] = ss;
  __syncthreads();
  const float rms = rsqrtf((red[0] + red[1] + red[2] + red[3]) * (1.f / (float)Dq) + 1e-6f);
  const float* gp = g + tid * 8;
  f32x4 ga = *(const f32x4*)gp, gb = *(const f32x4*)(gp + 4);
  union { short8 s; bf16 h[8]; } uo;
#pragma unroll
  for (int j = 0; j < 4; ++j) {
    uo.h[j] = f2b(xf[j] * rms * ga[j]);
    uo.h[j + 4] = f2b(xf[j + 4] * rms * gb[j]);
  }
  *(short8*)(out + (size_t)row * Dq + tid * 8) = uo.s;
}

// ---------------------------------------------------------------------------
// RoPE in-place on q and k (bf16, row stride ld). One thread per (b,s,h,i<64).
// ---------------------------------------------------------------------------
__global__ __launch_bounds__(256)
void rope_k(bf16* __restrict__ q, bf16* __restrict__ k, int ld) {
  const size_t idx = (size_t)blockIdx.x * 256 + threadIdx.x;
  const int i = (int)(idx & 63);
  const int h = (int)((idx >> 6) & 15);
  const int s = (int)((idx >> 10) & 2047);
  const int b = (int)(idx >> 21);
  const float f = (float)s * powf(10000.f, -(float)i * (1.f / 64.f));
  float sn, cs;
  sincosf(f, &sn, &cs);
  const size_t base = ((size_t)(b * Sq + s)) * ld + h * DHq + i;
  const float qa = b2f(q[base]), qb_ = b2f(q[base + 64]);
  q[base] = f2b(qa * cs - qb_ * sn);
  q[base + 64] = f2b(qb_ * cs + qa * sn);
  const float ka = b2f(k[base]), kb_ = b2f(k[base + 64]);
  k[base] = f2b(ka * cs - kb_ * sn);
  k[base + 64] = f2b(kb_ * cs + ka * sn);
}

// ---------------------------------------------------------------------------
// Causal flash attention v2: 8 waves (512 thr), QBLK=128, KVBLK=64.
// Swapped QK^T (mfma(K,Q)) -> P^T in registers: lane owns ONE q-row
// (q = l&15), kv = n*16 + (l>>4)*4 + r. Softmax: in-lane + 2 shfl_xor;
// scalar m/l/corr. PV as O^T = mfma(Vt-frag, P-frag); P round-trips through
// per-wave LDS (packed b64 writes, NO block barrier - wave-local dep only).
// Grid (S/128, H, B), q-tile reversed (heavy first).
// ---------------------------------------------------------------------------
__device__ __forceinline__ int swz8(int row) { return (((row >> 3) ^ row) & 7) << 3; }

__global__ __launch_bounds__(512)
void attn_k(const bf16* __restrict__ q, const bf16* __restrict__ k,
            const bf16* __restrict__ v, bf16* __restrict__ o, int ld) {
  __shared__ __align__(16) bf16 Ks[64][128];   // [kv][d], phys blk8 = log ^ key(kv)
  __shared__ __align__(16) bf16 Vt[128][64];   // [d][kv], elem ^ swz8(d)
  __shared__ __align__(16) bf16 Ps[8][16][64]; // [wave][q][kv], blk8 ^ key(q)
  const int tid = threadIdx.x;
  const int w = tid >> 6, l = tid & 63;
  const int g = l >> 4, c = l & 15;
  const int q0 = ((int)gridDim.x - 1 - (int)blockIdx.x) * 128;  // heavy first
  const int h = blockIdx.y;
  const int b = blockIdx.z;
  const size_t hoff = (size_t)h * DHq;
  const float SCALE = 0.08838834764831845f;  // 1/sqrt(128)

  const int qrow = q0 + w * 16 + c;  // this lane's q row (for waveW)

  // Q fragments (B-operand of swapped QK): lane holds Q[qrow][kslots g*8..]
  short8 aq[4];
  {
    const bf16* qp = q + (size_t)(b * Sq + qrow) * ld + hoff + g * 8;
#pragma unroll
    for (int kk = 0; kk < 4; ++kk) aq[kk] = *(const short8*)(qp + kk * 32);
  }

  float m_run = -3.0e38f, l_run = 0.f;
  f32x4 o_acc[8] = {};

  // staging geometry (512 threads)
  const int stRow = tid >> 4;           // 0..31 (+ i*32)
  const int stBlk = tid & 15;           // 16B block within 128-elem row
  const int ntiles = (q0 >> 6) + 2;

  for (int t = 0; t < ntiles; ++t) {
    const int kv0 = t * 64;
    __syncthreads();  // prev tile's LDS reads done
    // K: global_load_lds, pre-swizzled source (phys blk8 = logical ^ key(row))
#pragma unroll
    for (int i = 0; i < 2; ++i) {
      const int kr = i * 32 + w * 4 + (l >> 4);      // dest row for this lane
      const int key = (kr ^ (kr >> 3)) & 7;
      gload16(k + (size_t)(b * Sq + kv0 + kr) * ld + hoff + ((c ^ key) << 3),
              &Ks[i * 32 + w * 4][0]);
    }
    // V^T: reg-staged scatter (8 scalar writes x 2 iters)
#pragma unroll
    for (int i = 0; i < 2; ++i) {
      const int vr = i * 32 + stRow;
      const int c0 = stBlk * 8;
      union { short8 s; bf16 hh[8]; } uv;
      uv.s = *(const short8*)(v + (size_t)(b * Sq + kv0 + vr) * ld + hoff + c0);
#pragma unroll
      for (int j = 0; j < 8; ++j) Vt[c0 + j][vr ^ swz8(c0 + j)] = uv.hh[j];
    }
    __syncthreads();  // staging visible (vmcnt+lgkmcnt drained at barrier)

    const bool active = (kv0 <= q0 + w * 16 + 15);
    if (active) {
      // S^T = K Q^T : sc[n] rows = kv (n*16 + g*4 + r), col = q (= c)
      f32x4 sc[4] = {};
      __builtin_amdgcn_s_setprio(1);
#pragma unroll
      for (int n = 0; n < 4; ++n) {
        const int krow = n * 16 + c;
        const int sw = swz8(krow);
#pragma unroll
        for (int kk = 0; kk < 4; ++kk) {
          short8 ak = *(const short8*)&Ks[krow][(kk * 32 + g * 8) ^ sw];
          sc[n] = __builtin_amdgcn_mfma_f32_16x16x32_bf16(ak, aq[kk], sc[n], 0, 0, 0);
        }
      }
      __builtin_amdgcn_s_setprio(0);

      // mask + in-lane max over the 16 kv values this lane holds (one q row)
      float p[4][4];
      float tmax = -3.0e38f;
#pragma unroll
      for (int n = 0; n < 4; ++n)
#pragma unroll
        for (int r = 0; r < 4; ++r) {
          const int kvg = kv0 + n * 16 + g * 4 + r;
          float val = sc[n][r] * SCALE;
          if (kvg > qrow) val = -3.0e38f;
          p[n][r] = val;
          tmax = fmaxf(tmax, val);
        }
      // cross-group reduce (same q row lives in lanes l, l^16, l^32, l^48)
      tmax = fmaxf(tmax, __shfl_xor(tmax, 16));
      tmax = fmaxf(tmax, __shfl_xor(tmax, 32));
      const float m_new = fmaxf(m_run, tmax);
      const float corr = expf(m_run - m_new);
      float tsum = 0.f;
#pragma unroll
      for (int n = 0; n < 4; ++n)
#pragma unroll
        for (int r = 0; r < 4; ++r) {
          const float pv = expf(p[n][r] - m_new);
          p[n][r] = pv;
          tsum += pv;
        }
      tsum += __shfl_xor(tsum, 16);
      tsum += __shfl_xor(tsum, 32);
      l_run = l_run * corr + tsum;
      m_run = m_new;
#pragma unroll
      for (int dt = 0; dt < 8; ++dt) o_acc[dt] *= corr;

      // P^T -> Ps (per-wave, packed b64, swizzled blk8 ^ key(q)); wave-local dep
      const int keyc = (c ^ (c >> 3)) & 7;
#pragma unroll
      for (int n = 0; n < 4; ++n) {
        union { unsigned long long u; bf16 hh[4]; } pk;
#pragma unroll
        for (int r = 0; r < 4; ++r) pk.hh[r] = f2b(p[n][r]);
        const int blk = (2 * n + (g >> 1)) ^ keyc;
        *(unsigned long long*)&Ps[w][c][blk * 8 + (g & 1) * 4] = pk.u;
      }
      // read P rows as B-frag: lane c reads q-row c, kv-slots kk*32 + g*8
      short8 ap[2];
#pragma unroll
      for (int kk = 0; kk < 2; ++kk)
        ap[kk] = *(const short8*)&Ps[w][c][(kk * 32 + g * 8) ^ (keyc << 3)];

      // O^T += V^T-frag x P-frag : rows d, col q
      __builtin_amdgcn_s_setprio(1);
#pragma unroll
      for (int dt = 0; dt < 8; ++dt) {
        const int vrow = dt * 16 + c;
        const int vsw = swz8(vrow);
#pragma unroll
        for (int kk = 0; kk < 2; ++kk) {
          short8 av = *(const short8*)&Vt[vrow][(kk * 32 + g * 8) ^ vsw];
          o_acc[dt] = __builtin_amdgcn_mfma_f32_16x16x32_bf16(av, ap[kk], o_acc[dt], 0, 0, 0);
        }
      }
      __builtin_amdgcn_s_setprio(0);
    }
  }

  // epilogue: lane owns q-row `qrow`; o_acc[dt][r] = O[qrow][dt*16 + g*4 + r]
  const float inv = 1.f / l_run;
  bf16* op = o + (size_t)(b * Sq + qrow) * Dq + hoff + g * 4;
#pragma unroll
  for (int dt = 0; dt < 8; ++dt) {
    union { unsigned long long u; bf16 hh[4]; } pk;
#pragma unroll
    for (int r = 0; r < 4; ++r) pk.hh[r] = f2b(o_acc[dt][r] * inv);
    *(unsigned long long*)(op + dt * 16) = pk.u;
  }
}

// ---------------------------------------------------------------------------
extern "C" void kernel_launch(void* const* d_in, const int* in_sizes, int n_in,
                              void* d_out, int out_size, void* d_ws, size_t ws_size,
                              hipStream_t stream) {
  (void)in_sizes; (void)n_in; (void)out_size;
  const float* x  = (const float*)d_in[0];
  const float* wq = (const float*)d_in[2];
  const float* wk = (const float*)d_in[3];
  const float* wv = (const float*)d_in[4];
  const float* wo = (const float*)d_in[5];
  const float* w1 = (const float*)d_in[6];
  const float* w2 = (const float*)d_in[7];
  const float* w3 = (const float*)d_in[8];
  const float* ga = (const float*)d_in[9];
  const float* gf = (const float*)d_in[10];
  float* out = (float*)d_out;

  char* ws = (char*)d_ws;
  dim3 blk(256);
  dim3 gA(Sq / 128, Hq, Bq);
  dim3 blkA(512);

  const size_t SZ_H   = (size_t)Mq * Dq * 2;        // 16.78 MB
  const size_t SZ_QKV = (size_t)Mq * 3 * Dq * 2;    // 50.33 MB
  const size_t SZ_W4  = (size_t)Dq * Dq * 2;        // 8.39 MB
  const size_t SZ_W13 = (size_t)FFq * Dq * 2;       // 33.55 MB
  const size_t ACT    = SZ_H + SZ_QKV;              // 67.11 MB
  const size_t WTS    = 3 * SZ_W4 + SZ_W4 + 3 * SZ_W13;
  const size_t NEED   = ACT + WTS;                  // ~201.6 MB

  if (ws_size >= NEED) {
    // ---- PATH A: bf16 weights ----
    bf16* h    = (bf16*)(ws);
    bf16* qkv  = (bf16*)(ws + SZ_H);                // [4096][6144]
    bf16* ob   = h;
    bf16* h2   = qkv;
    bf16* ub   = (bf16*)(ws + SZ_H + SZ_H);         // M x 4096
    char* wb   = ws + ACT;
    bf16* wqkv_b = (bf16*)(wb);                     // [6144][2048]
    bf16* wo_b   = (bf16*)(wb + 3 * SZ_W4);
    bf16* w1_b   = (bf16*)(wb + 4 * SZ_W4);
    bf16* w3_b   = (bf16*)(wb + 4 * SZ_W4 + SZ_W13);
    bf16* w2_b   = (bf16*)(wb + 4 * SZ_W4 + 2 * SZ_W13);

    const long nW4 = (long)Dq * Dq, nW13 = (long)FFq * Dq;
    conv_k<<<1024, blk, 0, stream>>>(wq, wqkv_b, nW4);
    conv_k<<<1024, blk, 0, stream>>>(wk, wqkv_b + nW4, nW4);
    conv_k<<<1024, blk, 0, stream>>>(wv, wqkv_b + 2 * nW4, nW4);
    conv_k<<<1024, blk, 0, stream>>>(wo, wo_b, nW4);
    conv_k<<<2048, blk, 0, stream>>>(w1, w1_b, nW13);
    conv_k<<<2048, blk, 0, stream>>>(w3, w3_b, nW13);
    conv_k<<<2048, blk, 0, stream>>>(w2, w2_b, nW13);

    rmsnorm_k<<<Mq, blk, 0, stream>>>(x, ga, h);
    gemm3<0><<<dim3(48, 32), blk, 0, stream>>>(h, wqkv_b, nullptr, qkv, 6144, Dq, Dq, 0);
    rope_k<<<(Bq * Sq * Hq * 64) / 256, blk, 0, stream>>>(qkv, qkv + Dq, 3 * Dq);
    attn_k<<<gA, blkA, 0, stream>>>(qkv, qkv + Dq, qkv + 2 * Dq, ob, 3 * Dq);
    gemm3<1><<<dim3(16, 32), blk, 0, stream>>>(ob, wo_b, x, out, Dq, Dq, Dq, 0);
    rmsnorm_k<<<Mq, blk, 0, stream>>>(out, gf, h2);
    for (int hh = 0; hh < 2; ++hh) {
      bf16* w1h = w1_b + (size_t)hh * 4096 * Dq;
      bf16* w3h = w3_b + (size_t)hh * 4096 * Dq;
      gemm3<0><<<dim3(32, 32), blk, 0, stream>>>(h2, w1h, nullptr, ub, 4096, Dq, Dq, 0);
      gemm3<2><<<dim3(32, 32), blk, 0, stream>>>(h2, w3h, ub, ub, 4096, Dq, Dq, 0);
      gemm3<1><<<dim3(16, 32), blk, 0, stream>>>(ub, w2_b, out, out, Dq, 4096, FFq,
                                                 (long long)hh * 4096);
    }
  } else {
    // ---- PATH B: f32-weight fallback (64 MiB ws) ----
    const size_t MS = (size_t)Mq * Dq * 2;
    bf16* h  = (bf16*)(ws);
    bf16* kb = (bf16*)(ws + MS);
    bf16* vb = (bf16*)(ws + 2 * MS);
    bf16* qb = (bf16*)(ws + 3 * MS);
    bf16* ub = (bf16*)(ws);
    bf16* ob = h;
    bf16* h2 = qb;

    dim3 gD(Dq / 128, Mq / 128);
    dim3 gU(32, Mq / 128);

    rmsnorm_k<<<Mq, blk, 0, stream>>>(x, ga, h);
    gemm2<0><<<gD, blk, 0, stream>>>(h, wq, nullptr, qb, Dq, Dq, Dq, 0);
    gemm2<0><<<gD, blk, 0, stream>>>(h, wk, nullptr, kb, Dq, Dq, Dq, 0);
    gemm2<0><<<gD, blk, 0, stream>>>(h, wv, nullptr, vb, Dq, Dq, Dq, 0);
    rope_k<<<(Bq * Sq * Hq * 64) / 256, blk, 0, stream>>>(qb, kb, Dq);
    attn_k<<<gA, blkA, 0, stream>>>(qb, kb, vb, ob, Dq);
    gemm2<1><<<gD, blk, 0, stream>>>(ob, wo, x, out, Dq, Dq, Dq, 0);
    rmsnorm_k<<<Mq, blk, 0, stream>>>(out, gf, h2);
    for (int hh = 0; hh < 2; ++hh) {
      const long long bo13 = (long long)hh * 4096 * 2048;
      gemm2<0><<<gU, blk, 0, stream>>>(h2, w1, nullptr, ub, 4096, Dq, Dq, bo13);
      gemm2<2><<<gU, blk, 0, stream>>>(h2, w3, ub, ub, 4096, Dq, Dq, bo13);
      gemm2<1><<<gD, blk, 0, stream>>>(ub, w2, out, out, Dq, 4096, FFq,
                                       (long long)hh * 4096);
    }
  }
}

// Round 7
// 953.340 us; speedup vs baseline: 2.3560x; 1.0919x over previous
//
#include <hip/hip_runtime.h>
#include <hip/hip_bf16.h>
#include <math.h>

typedef __hip_bfloat16 bf16;
typedef short short8 __attribute__((ext_vector_type(8)));
typedef float f32x4 __attribute__((ext_vector_type(4)));

#define Bq 2
#define Sq 2048
#define Dq 2048
#define Hq 16
#define DHq 128
#define FFq 8192
#define Mq 4096  // Bq*Sq

// Inputs/outputs are f32. Internal activations bf16. Weights pre-converted to
// bf16 when ws_size allows (path A); otherwise f32-staged directly (path B).

__device__ __forceinline__ float b2f(bf16 x) { return __bfloat162float(x); }
__device__ __forceinline__ bf16 f2b(float x) { return __float2bfloat16(x); }

// async global->LDS, 16B/lane. LDS dest arg is the wave-uniform BASE; HW places
// lane l at base + l*16.
__device__ __forceinline__ void gload16(const void* g, void* lds_base) {
  __builtin_amdgcn_global_load_lds(
      (const __attribute__((address_space(1))) void*)g,
      (__attribute__((address_space(3))) void*)lds_base,
      16, 0, 0);
}

// ---------------------------------------------------------------------------
// f32 -> bf16 conversion (grid-stride, 8 elems/thread)
// ---------------------------------------------------------------------------
__global__ __launch_bounds__(256)
void conv_k(const float* __restrict__ src, bf16* __restrict__ dst, long n) {
  const long stride = (long)gridDim.x * 256 * 8;
  for (long i = ((long)blockIdx.x * 256 + threadIdx.x) * 8; i < n; i += stride) {
    f32x4 a = *(const f32x4*)(src + i);
    f32x4 b = *(const f32x4*)(src + i + 4);
    union { short8 s; bf16 h[8]; } u;
#pragma unroll
    for (int j = 0; j < 4; ++j) { u.h[j] = f2b(a[j]); u.h[j + 4] = f2b(b[j]); }
    *(short8*)(dst + i) = u.s;
  }
}

// ---------------------------------------------------------------------------
// PATH A GEMM: C[M,N] = A[M,K](bf16) * Bt[N,K](bf16)^T
// EPI 0: C(bf16) = acc ; EPI 1: C(f32) = R(f32)+acc ; EPI 2: C(bf16)=silu(R)*acc
// 128x128 tile, BK=64, 4 waves (2x2). Both operands via global_load_lds with
// the XOR-8 block swizzle applied on source AND read (rule #21).
// ---------------------------------------------------------------------------
template <int EPI>
__global__ __launch_bounds__(256)
void gemm3(const bf16* __restrict__ A, const bf16* __restrict__ Bt,
           const void* __restrict__ R, void* __restrict__ C,
           int N, int K, int ldb, long long boff) {
  __shared__ __align__(16) bf16 As[128][64];
  __shared__ __align__(16) bf16 Bs[128][64];
  const int tid = threadIdx.x;
  const int w = tid >> 6;
  const int l = tid & 63;

  // bijective XCD swizzle (T1, m204)
  const int nwg = gridDim.x * gridDim.y;
  const int orig = blockIdx.x + blockIdx.y * gridDim.x;
  const int qq = nwg >> 3, rr8 = nwg & 7;
  const int xcd = orig & 7, idx8 = orig >> 3;
  const int wg = (xcd < rr8 ? xcd * (qq + 1) : rr8 * (qq + 1) + (xcd - rr8) * qq) + idx8;
  const int bm = (wg / gridDim.x) * 128;
  const int bn = (wg % gridDim.x) * 128;

  const int wr = (w >> 1) * 64;
  const int wc = (w & 1) * 64;
  f32x4 acc[4][4] = {};

  const bf16* Ab = A + (size_t)bm * K;
  const bf16* Bb = Bt + (size_t)bn * ldb + (size_t)boff;

  const int sRow = w * 8 + (l >> 3);
  const int sCol = (((l & 7) ^ (l >> 3)) << 3);

  for (int kt = 0; kt < K; kt += 64) {
    __syncthreads();
#pragma unroll
    for (int i = 0; i < 4; ++i) {
      gload16(Ab + (size_t)(i * 32 + sRow) * K + kt + sCol, &As[i * 32 + w * 8][0]);
      gload16(Bb + (size_t)(i * 32 + sRow) * ldb + kt + sCol, &Bs[i * 32 + w * 8][0]);
    }
    __syncthreads();

#pragma unroll
    for (int kk = 0; kk < 2; ++kk) {
      short8 af[4], bfv[4];
#pragma unroll
      for (int m = 0; m < 4; ++m) {
        const int ra = wr + m * 16 + (l & 15);
        af[m] = *(const short8*)&As[ra][(((kk * 4 + (l >> 4)) ^ (ra & 7)) << 3)];
      }
#pragma unroll
      for (int n = 0; n < 4; ++n) {
        const int rb = wc + n * 16 + (l & 15);
        bfv[n] = *(const short8*)&Bs[rb][(((kk * 4 + (l >> 4)) ^ (rb & 7)) << 3)];
      }
#pragma unroll
      for (int m = 0; m < 4; ++m)
#pragma unroll
        for (int n = 0; n < 4; ++n)
          acc[m][n] = __builtin_amdgcn_mfma_f32_16x16x32_bf16(af[m], bfv[n], acc[m][n], 0, 0, 0);
    }
  }

  const int rbase = bm + wr + (l >> 4) * 4;
  const int cbase = bn + wc + (l & 15);
#pragma unroll
  for (int m = 0; m < 4; ++m)
#pragma unroll
    for (int r = 0; r < 4; ++r) {
      const int row = rbase + m * 16 + r;
#pragma unroll
      for (int n = 0; n < 4; ++n) {
        const size_t idx = (size_t)row * N + (cbase + n * 16);
        float vacc = acc[m][n][r];
        if (EPI == 1) {
          ((float*)C)[idx] = vacc + ((const float*)R)[idx];
        } else if (EPI == 2) {
          const float u = b2f(((const bf16*)R)[idx]);
          ((bf16*)C)[idx] = f2b((u / (1.f + expf(-u))) * vacc);
        } else {
          ((bf16*)C)[idx] = f2b(vacc);
        }
      }
    }
}

// ---------------------------------------------------------------------------
// PATH B GEMM (round-3 verified): B operand f32, staged via gload_lds.
// ---------------------------------------------------------------------------
template <int EPI>
__global__ __launch_bounds__(256)
void gemm2(const bf16* __restrict__ A, const float* __restrict__ Bt,
           const void* __restrict__ R, void* __restrict__ C,
           int N, int K, int ldb, long long boff) {
  __shared__ __align__(16) bf16 As[128][64];
  __shared__ __align__(16) float Bsf[128][64];
  const int tid = threadIdx.x;
  const int w = tid >> 6;
  const int l = tid & 63;

  const int nwg = gridDim.x * gridDim.y;
  const int orig = blockIdx.x + blockIdx.y * gridDim.x;
  const int qq = nwg >> 3, rr8 = nwg & 7;
  const int xcd = orig & 7, idx8 = orig >> 3;
  const int wg = (xcd < rr8 ? xcd * (qq + 1) : rr8 * (qq + 1) + (xcd - rr8) * qq) + idx8;
  const int bm = (wg / gridDim.x) * 128;
  const int bn = (wg % gridDim.x) * 128;

  const int wr = (w >> 1) * 64;
  const int wc = (w & 1) * 64;
  f32x4 acc[4][4] = {};

  const bf16* Ab = A + (size_t)bm * K;
  const float* Bb = Bt + (size_t)bn * ldb + (size_t)boff;

  const int aSrcCol = (((l & 7) ^ (l >> 3)) << 3);
  const int bKey = (w * 4 + (l >> 4)) & 7;
  const int bSrcCol = (((l & 15) ^ bKey) << 2);

  for (int kt = 0; kt < K; kt += 64) {
    __syncthreads();
#pragma unroll
    for (int i = 0; i < 4; ++i)
      gload16(Ab + (size_t)(i * 32 + w * 8 + (l >> 3)) * K + kt + aSrcCol,
              &As[i * 32 + w * 8][0]);
#pragma unroll
    for (int i = 0; i < 8; ++i)
      gload16(Bb + (size_t)(i * 16 + w * 4 + (l >> 4)) * ldb + kt + bSrcCol,
              &Bsf[i * 16 + w * 4][0]);
    __syncthreads();

#pragma unroll
    for (int kk = 0; kk < 2; ++kk) {
      short8 af[4], bfv[4];
#pragma unroll
      for (int m = 0; m < 4; ++m) {
        const int ra = wr + m * 16 + (l & 15);
        const int pb = (kk * 4 + (l >> 4)) ^ (ra & 7);
        af[m] = *(const short8*)&As[ra][pb * 8];
      }
#pragma unroll
      for (int n = 0; n < 4; ++n) {
        const int rb = wc + n * 16 + (l & 15);
        const int b0 = kk * 8 + (l >> 4) * 2;
        const f32x4 x0 = *(const f32x4*)&Bsf[rb][(b0 ^ (rb & 7)) * 4];
        const f32x4 x1 = *(const f32x4*)&Bsf[rb][((b0 + 1) ^ (rb & 7)) * 4];
        union { short8 s; bf16 h[8]; } u;
#pragma unroll
        for (int j = 0; j < 4; ++j) { u.h[j] = f2b(x0[j]); u.h[j + 4] = f2b(x1[j]); }
        bfv[n] = u.s;
      }
#pragma unroll
      for (int m = 0; m < 4; ++m)
#pragma unroll
        for (int n = 0; n < 4; ++n)
          acc[m][n] = __builtin_amdgcn_mfma_f32_16x16x32_bf16(af[m], bfv[n], acc[m][n], 0, 0, 0);
    }
  }

  const int rbase = bm + wr + (l >> 4) * 4;
  const int cbase = bn + wc + (l & 15);
#pragma unroll
  for (int m = 0; m < 4; ++m)
#pragma unroll
    for (int r = 0; r < 4; ++r) {
      const int row = rbase + m * 16 + r;
#pragma unroll
      for (int n = 0; n < 4; ++n) {
        const size_t idx = (size_t)row * N + (cbase + n * 16);
        float vacc = acc[m][n][r];
        if (EPI == 1) {
          ((float*)C)[idx] = vacc + ((const float*)R)[idx];
        } else if (EPI == 2) {
          const float u = b2f(((const bf16*)R)[idx]);
          ((bf16*)C)[idx] = f2b((u / (1.f + expf(-u))) * vacc);
        } else {
          ((bf16*)C)[idx] = f2b(vacc);
        }
      }
    }
}

// ---------------------------------------------------------------------------
// RMSNorm: one block per row of 2048. f32 in, f32 g, bf16 out.
// ---------------------------------------------------------------------------
__global__ __launch_bounds__(256)
void rmsnorm_k(const float* __restrict__ xin, const float* __restrict__ g,
               bf16* __restrict__ out) {
  const int row = blockIdx.x;
  const int tid = threadIdx.x;
  const float* xp = xin + (size_t)row * Dq + tid * 8;
  f32x4 a = *(const f32x4*)xp, b = *(const f32x4*)(xp + 4);
  float xf[8];
#pragma unroll
  for (int j = 0; j < 4; ++j) { xf[j] = a[j]; xf[j + 4] = b[j]; }
  float ss = 0.f;
#pragma unroll
  for (int j = 0; j < 8; ++j) ss += xf[j] * xf[j];
#pragma unroll
  for (int off = 32; off > 0; off >>= 1) ss += __shfl_down(ss, off);
  __shared__ float red[4];
  if ((tid & 63) == 0) red[tid >> 6] = ss;
  __syncthreads();
  const float rms = rsqrtf((red[0] + red[1] + red[2] + red[3]) * (1.f / (float)Dq) + 1e-6f);
  const float* gp = g + tid * 8;
  f32x4 ga = *(const f32x4*)gp, gb = *(const f32x4*)(gp + 4);
  union { short8 s; bf16 h[8]; } uo;
#pragma unroll
  for (int j = 0; j < 4; ++j) {
    uo.h[j] = f2b(xf[j] * rms * ga[j]);
    uo.h[j + 4] = f2b(xf[j + 4] * rms * gb[j]);
  }
  *(short8*)(out + (size_t)row * Dq + tid * 8) = uo.s;
}

// ---------------------------------------------------------------------------
// RoPE in-place on q and k (bf16, row stride ld). One thread per (b,s,h,i<64).
// ---------------------------------------------------------------------------
__global__ __launch_bounds__(256)
void rope_k(bf16* __restrict__ q, bf16* __restrict__ k, int ld) {
  const size_t idx = (size_t)blockIdx.x * 256 + threadIdx.x;
  const int i = (int)(idx & 63);
  const int h = (int)((idx >> 6) & 15);
  const int s = (int)((idx >> 10) & 2047);
  const int b = (int)(idx >> 21);
  const float f = (float)s * powf(10000.f, -(float)i * (1.f / 64.f));
  float sn, cs;
  sincosf(f, &sn, &cs);
  const size_t base = ((size_t)(b * Sq + s)) * ld + h * DHq + i;
  const float qa = b2f(q[base]), qb_ = b2f(q[base + 64]);
  q[base] = f2b(qa * cs - qb_ * sn);
  q[base + 64] = f2b(qb_ * cs + qa * sn);
  const float ka = b2f(k[base]), kb_ = b2f(k[base + 64]);
  k[base] = f2b(ka * cs - kb_ * sn);
  k[base + 64] = f2b(kb_ * cs + ka * sn);
}

// ---------------------------------------------------------------------------
// Causal flash attention v3: 256 blocks (1/CU), 8 waves, BALANCED work.
// Block (x,h,b) owns q-tiles hi=15-x and lo=x (each 128 rows); both consume
// the SAME staged K/V tile (shared staging). Double-buffered K/V with
// prefetch: issue loads for t+1 before computing t; V scatter deferred past
// QK/softmax (issue-early/write-late); ONE barrier per tile.
// Swapped QK^T: lane owns one q-row; softmax = in-lane + 2 shfl.
// ---------------------------------------------------------------------------
__device__ __forceinline__ int swz8(int row) { return (((row >> 3) ^ row) & 7) << 3; }

#define ATTN_COMPUTE(AQ, QB, QROW, M_, L_, OACC, KV0, CUR)                        \
  {                                                                               \
    f32x4 sc[4] = {};                                                             \
    __builtin_amdgcn_s_setprio(1);                                                \
    _Pragma("unroll") for (int n = 0; n < 4; ++n) {                               \
      const int krow = n * 16 + c;                                                \
      const int sw = swz8(krow);                                                  \
      _Pragma("unroll") for (int kk = 0; kk < 4; ++kk) {                          \
        short8 ak = *(const short8*)&Ks[CUR][krow][(kk * 32 + g * 8) ^ sw];       \
        sc[n] = __builtin_amdgcn_mfma_f32_16x16x32_bf16(ak, AQ[kk], sc[n], 0, 0, 0); \
      }                                                                           \
    }                                                                             \
    __builtin_amdgcn_s_setprio(0);                                                \
    float p[4][4];                                                                \
    float tmax = -3.0e38f;                                                        \
    if ((KV0) + 63 <= (QB)) {                                                     \
      _Pragma("unroll") for (int n = 0; n < 4; ++n)                               \
        _Pragma("unroll") for (int r = 0; r < 4; ++r) {                           \
          const float val = sc[n][r] * SCALE;                                     \
          p[n][r] = val;                                                          \
          tmax = fmaxf(tmax, val);                                                \
        }                                                                         \
    } else {                                                                      \
      _Pragma("unroll") for (int n = 0; n < 4; ++n)                               \
        _Pragma("unroll") for (int r = 0; r < 4; ++r) {                           \
          const int kvg = (KV0) + n * 16 + g * 4 + r;                             \
          float val = sc[n][r] * SCALE;                                           \
          if (kvg > (QROW)) val = -3.0e38f;                                       \
          p[n][r] = val;                                                          \
          tmax = fmaxf(tmax, val);                                                \
        }                                                                         \
    }                                                                             \
    tmax = fmaxf(tmax, __shfl_xor(tmax, 16));                                     \
    tmax = fmaxf(tmax, __shfl_xor(tmax, 32));                                     \
    const bool grow = !__all(tmax <= M_);                                         \
    const float m_new = grow ? fmaxf(M_, tmax) : M_;                              \
    float tsum = 0.f;                                                             \
    _Pragma("unroll") for (int n = 0; n < 4; ++n)                                 \
      _Pragma("unroll") for (int r = 0; r < 4; ++r) {                             \
        const float pv = expf(p[n][r] - m_new);                                   \
        p[n][r] = pv;                                                             \
        tsum += pv;                                                               \
      }                                                                           \
    tsum += __shfl_xor(tsum, 16);                                                 \
    tsum += __shfl_xor(tsum, 32);                                                 \
    if (grow) {                                                                   \
      const float corr = expf(M_ - m_new);                                        \
      L_ = L_ * corr + tsum;                                                      \
      M_ = m_new;                                                                 \
      _Pragma("unroll") for (int dt = 0; dt < 8; ++dt) OACC[dt] *= corr;          \
    } else {                                                                      \
      L_ += tsum;                                                                 \
    }                                                                             \
    const int keyc = (c ^ (c >> 3)) & 7;                                          \
    _Pragma("unroll") for (int n = 0; n < 4; ++n) {                               \
      union { unsigned long long u; bf16 hh[4]; } pk;                             \
      _Pragma("unroll") for (int r = 0; r < 4; ++r) pk.hh[r] = f2b(p[n][r]);      \
      const int blk = (2 * n + (g >> 1)) ^ keyc;                                  \
      *(unsigned long long*)&Ps[w][c][blk * 8 + (g & 1) * 4] = pk.u;              \
    }                                                                             \
    short8 ap[2];                                                                 \
    _Pragma("unroll") for (int kk = 0; kk < 2; ++kk)                              \
      ap[kk] = *(const short8*)&Ps[w][c][(kk * 32 + g * 8) ^ (keyc << 3)];        \
    __builtin_amdgcn_s_setprio(1);                                                \
    _Pragma("unroll") for (int dt = 0; dt < 8; ++dt) {                            \
      const int vrow = dt * 16 + c;                                               \
      const int vsw = swz8(vrow);                                                 \
      _Pragma("unroll") for (int kk = 0; kk < 2; ++kk) {                          \
        short8 av = *(const short8*)&Vt[CUR][vrow][(kk * 32 + g * 8) ^ vsw];      \
        OACC[dt] = __builtin_amdgcn_mfma_f32_16x16x32_bf16(av, ap[kk], OACC[dt], 0, 0, 0); \
      }                                                                           \
    }                                                                             \
    __builtin_amdgcn_s_setprio(0);                                                \
  }

__global__ __launch_bounds__(512)
void attn_k(const bf16* __restrict__ q, const bf16* __restrict__ k,
            const bf16* __restrict__ v, bf16* __restrict__ o, int ld) {
  __shared__ __align__(16) bf16 Ks[2][64][128];
  __shared__ __align__(16) bf16 Vt[2][128][64];
  __shared__ __align__(16) bf16 Ps[8][16][64];
  const int tid = threadIdx.x;
  const int w = tid >> 6, l = tid & 63;
  const int g = l >> 4, c = l & 15;
  const int x = blockIdx.x;          // 0..7
  const int h = blockIdx.y;
  const int b = blockIdx.z;
  const size_t hoff = (size_t)h * DHq;
  const float SCALE = 0.08838834764831845f;  // 1/sqrt(128)

  const int q0h = (15 - x) * 128, q0l = x * 128;
  const int qbh = q0h + w * 16, qbl = q0l + w * 16;  // wave base rows
  const int qrh = qbh + c, qrl = qbl + c;            // lane-owned q rows

  short8 aqh[4], aql[4];
  {
    const bf16* qph = q + (size_t)(b * Sq + qrh) * ld + hoff + g * 8;
    const bf16* qpl = q + (size_t)(b * Sq + qrl) * ld + hoff + g * 8;
#pragma unroll
    for (int kk = 0; kk < 4; ++kk) {
      aqh[kk] = *(const short8*)(qph + kk * 32);
      aql[kk] = *(const short8*)(qpl + kk * 32);
    }
  }

  float mh = -3.0e38f, lh = 0.f, ml = -3.0e38f, ll_ = 0.f;
  f32x4 oh[8] = {}, ol[8] = {};

  const int stRow = tid >> 4;   // 0..31
  const int stBlk = tid & 15;
  const int ntiles = (q0h >> 6) + 2;  // 32 - 2x

  // prologue: stage tile 0 -> buf 0
  {
#pragma unroll
    for (int i = 0; i < 2; ++i) {
      const int kr = i * 32 + w * 4 + (l >> 4);
      const int key = (kr ^ (kr >> 3)) & 7;
      gload16(k + (size_t)(b * Sq + kr) * ld + hoff + ((c ^ key) << 3),
              &Ks[0][i * 32 + w * 4][0]);
    }
    const int c0 = stBlk * 8;
#pragma unroll
    for (int i = 0; i < 2; ++i) {
      const int vr = i * 32 + stRow;
      union { short8 s; bf16 hh[8]; } uv;
      uv.s = *(const short8*)(v + (size_t)(b * Sq + vr) * ld + hoff + c0);
#pragma unroll
      for (int j = 0; j < 8; ++j) Vt[0][c0 + j][vr ^ swz8(c0 + j)] = uv.hh[j];
    }
  }
  __syncthreads();

  for (int t = 0; t < ntiles; ++t) {
    const int cur = t & 1, nxt = cur ^ 1;
    const int kv0 = t * 64;
    const bool pf = (t + 1 < ntiles);
    short8 vpa, vpb;
    if (pf) {
      const int kvn = kv0 + 64;
#pragma unroll
      for (int i = 0; i < 2; ++i) {
        const int kr = i * 32 + w * 4 + (l >> 4);
        const int key = (kr ^ (kr >> 3)) & 7;
        gload16(k + (size_t)(b * Sq + kvn + kr) * ld + hoff + ((c ^ key) << 3),
                &Ks[nxt][i * 32 + w * 4][0]);
      }
      vpa = *(const short8*)(v + (size_t)(b * Sq + kvn + stRow) * ld + hoff + stBlk * 8);
      vpb = *(const short8*)(v + (size_t)(b * Sq + kvn + 32 + stRow) * ld + hoff + stBlk * 8);
    }

    // HI tile compute (from buf cur) -- covers HBM latency of the prefetch
    if (kv0 <= qbh + 15) ATTN_COMPUTE(aqh, qbh, qrh, mh, lh, oh, kv0, cur);

    // deferred V scatter of the prefetched tile (write-late)
    if (pf) {
      const int c0 = stBlk * 8;
      union { short8 s; bf16 hh[8]; } uv;
      uv.s = vpa;
#pragma unroll
      for (int j = 0; j < 8; ++j) Vt[nxt][c0 + j][stRow ^ swz8(c0 + j)] = uv.hh[j];
      uv.s = vpb;
#pragma unroll
      for (int j = 0; j < 8; ++j) Vt[nxt][c0 + j][(32 + stRow) ^ swz8(c0 + j)] = uv.hh[j];
    }

    // LO tile compute (from buf cur)
    if (kv0 <= qbl + 15) ATTN_COMPUTE(aql, qbl, qrl, ml, ll_, ol, kv0, cur);

    __syncthreads();  // buf nxt ready (vmcnt+lgkm drained); buf cur reads done
  }

  // epilogue: both q-tiles
  {
    const float inv = 1.f / lh;
    bf16* op = o + (size_t)(b * Sq + qrh) * Dq + hoff + g * 4;
#pragma unroll
    for (int dt = 0; dt < 8; ++dt) {
      union { unsigned long long u; bf16 hh[4]; } pk;
#pragma unroll
      for (int r = 0; r < 4; ++r) pk.hh[r] = f2b(oh[dt][r] * inv);
      *(unsigned long long*)(op + dt * 16) = pk.u;
    }
  }
  {
    const float inv = 1.f / ll_;
    bf16* op = o + (size_t)(b * Sq + qrl) * Dq + hoff + g * 4;
#pragma unroll
    for (int dt = 0; dt < 8; ++dt) {
      union { unsigned long long u; bf16 hh[4]; } pk;
#pragma unroll
      for (int r = 0; r < 4; ++r) pk.hh[r] = f2b(ol[dt][r] * inv);
      *(unsigned long long*)(op + dt * 16) = pk.u;
    }
  }
}

// ---------------------------------------------------------------------------
extern "C" void kernel_launch(void* const* d_in, const int* in_sizes, int n_in,
                              void* d_out, int out_size, void* d_ws, size_t ws_size,
                              hipStream_t stream) {
  (void)in_sizes; (void)n_in; (void)out_size;
  const float* x  = (const float*)d_in[0];
  const float* wq = (const float*)d_in[2];
  const float* wk = (const float*)d_in[3];
  const float* wv = (const float*)d_in[4];
  const float* wo = (const float*)d_in[5];
  const float* w1 = (const float*)d_in[6];
  const float* w2 = (const float*)d_in[7];
  const float* w3 = (const float*)d_in[8];
  const float* ga = (const float*)d_in[9];
  const float* gf = (const float*)d_in[10];
  float* out = (float*)d_out;

  char* ws = (char*)d_ws;
  dim3 blk(256);
  dim3 gA(8, Hq, Bq);     // 256 balanced blocks
  dim3 blkA(512);

  const size_t SZ_H   = (size_t)Mq * Dq * 2;        // 16.78 MB
  const size_t SZ_QKV = (size_t)Mq * 3 * Dq * 2;    // 50.33 MB
  const size_t SZ_W4  = (size_t)Dq * Dq * 2;        // 8.39 MB
  const size_t SZ_W13 = (size_t)FFq * Dq * 2;       // 33.55 MB
  const size_t ACT    = SZ_H + SZ_QKV;              // 67.11 MB
  const size_t WTS    = 3 * SZ_W4 + SZ_W4 + 3 * SZ_W13;
  const size_t NEED   = ACT + WTS;                  // ~201.6 MB

  if (ws_size >= NEED) {
    // ---- PATH A: bf16 weights ----
    bf16* h    = (bf16*)(ws);
    bf16* qkv  = (bf16*)(ws + SZ_H);                // [4096][6144]
    bf16* ob   = h;
    bf16* h2   = qkv;
    bf16* ub   = (bf16*)(ws + SZ_H + SZ_H);         // M x 4096
    char* wb   = ws + ACT;
    bf16* wqkv_b = (bf16*)(wb);                     // [6144][2048]
    bf16* wo_b   = (bf16*)(wb + 3 * SZ_W4);
    bf16* w1_b   = (bf16*)(wb + 4 * SZ_W4);
    bf16* w3_b   = (bf16*)(wb + 4 * SZ_W4 + SZ_W13);
    bf16* w2_b   = (bf16*)(wb + 4 * SZ_W4 + 2 * SZ_W13);

    const long nW4 = (long)Dq * Dq, nW13 = (long)FFq * Dq;
    conv_k<<<1024, blk, 0, stream>>>(wq, wqkv_b, nW4);
    conv_k<<<1024, blk, 0, stream>>>(wk, wqkv_b + nW4, nW4);
    conv_k<<<1024, blk, 0, stream>>>(wv, wqkv_b + 2 * nW4, nW4);
    conv_k<<<1024, blk, 0, stream>>>(wo, wo_b, nW4);
    conv_k<<<2048, blk, 0, stream>>>(w1, w1_b, nW13);
    conv_k<<<2048, blk, 0, stream>>>(w3, w3_b, nW13);
    conv_k<<<2048, blk, 0, stream>>>(w2, w2_b, nW13);

    rmsnorm_k<<<Mq, blk, 0, stream>>>(x, ga, h);
    gemm3<0><<<dim3(48, 32), blk, 0, stream>>>(h, wqkv_b, nullptr, qkv, 6144, Dq, Dq, 0);
    rope_k<<<(Bq * Sq * Hq * 64) / 256, blk, 0, stream>>>(qkv, qkv + Dq, 3 * Dq);
    attn_k<<<gA, blkA, 0, stream>>>(qkv, qkv + Dq, qkv + 2 * Dq, ob, 3 * Dq);
    gemm3<1><<<dim3(16, 32), blk, 0, stream>>>(ob, wo_b, x, out, Dq, Dq, Dq, 0);
    rmsnorm_k<<<Mq, blk, 0, stream>>>(out, gf, h2);
    for (int hh = 0; hh < 2; ++hh) {
      bf16* w1h = w1_b + (size_t)hh * 4096 * Dq;
      bf16* w3h = w3_b + (size_t)hh * 4096 * Dq;
      gemm3<0><<<dim3(32, 32), blk, 0, stream>>>(h2, w1h, nullptr, ub, 4096, Dq, Dq, 0);
      gemm3<2><<<dim3(32, 32), blk, 0, stream>>>(h2, w3h, ub, ub, 4096, Dq, Dq, 0);
      gemm3<1><<<dim3(16, 32), blk, 0, stream>>>(ub, w2_b, out, out, Dq, 4096, FFq,
                                                 (long long)hh * 4096);
    }
  } else {
    // ---- PATH B: f32-weight fallback (64 MiB ws) ----
    const size_t MS = (size_t)Mq * Dq * 2;
    bf16* h  = (bf16*)(ws);
    bf16* kb = (bf16*)(ws + MS);
    bf16* vb = (bf16*)(ws + 2 * MS);
    bf16* qb = (bf16*)(ws + 3 * MS);
    bf16* ub = (bf16*)(ws);
    bf16* ob = h;
    bf16* h2 = qb;

    dim3 gD(Dq / 128, Mq / 128);
    dim3 gU(32, Mq / 128);

    rmsnorm_k<<<Mq, blk, 0, stream>>>(x, ga, h);
    gemm2<0><<<gD, blk, 0, stream>>>(h, wq, nullptr, qb, Dq, Dq, Dq, 0);
    gemm2<0><<<gD, blk, 0, stream>>>(h, wk, nullptr, kb, Dq, Dq, Dq, 0);
    gemm2<0><<<gD, blk, 0, stream>>>(h, wv, nullptr, vb, Dq, Dq, Dq, 0);
    rope_k<<<(Bq * Sq * Hq * 64) / 256, blk, 0, stream>>>(qb, kb, Dq);
    attn_k<<<gA, blkA, 0, stream>>>(qb, kb, vb, ob, Dq);
    gemm2<1><<<gD, blk, 0, stream>>>(ob, wo, x, out, Dq, Dq, Dq, 0);
    rmsnorm_k<<<Mq, blk, 0, stream>>>(out, gf, h2);
    for (int hh = 0; hh < 2; ++hh) {
      const long long bo13 = (long long)hh * 4096 * 2048;
      gemm2<0><<<gU, blk, 0, stream>>>(h2, w1, nullptr, ub, 4096, Dq, Dq, bo13);
      gemm2<2><<<gU, blk, 0, stream>>>(h2, w3, ub, ub, 4096, Dq, Dq, bo13);
      gemm2<1><<<gD, blk, 0, stream>>>(ub, w2, out, out, Dq, 4096, FFq,
                                       (long long)hh * 4096);
    }
  }
}

// Round 8
// 930.613 us; speedup vs baseline: 2.4136x; 1.0244x over previous
//
#include <hip/hip_runtime.h>
#include <hip/hip_bf16.h>
#include <math.h>

typedef __hip_bfloat16 bf16;
typedef short short8 __attribute__((ext_vector_type(8)));
typedef float f32x4 __attribute__((ext_vector_type(4)));

#define Bq 2
#define Sq 2048
#define Dq 2048
#define Hq 16
#define DHq 128
#define FFq 8192
#define Mq 4096  // Bq*Sq

__device__ __forceinline__ float b2f(bf16 x) { return __bfloat162float(x); }
__device__ __forceinline__ bf16 f2b(float x) { return __float2bfloat16(x); }

__device__ __forceinline__ void gload16(const void* g, void* lds_base) {
  __builtin_amdgcn_global_load_lds(
      (const __attribute__((address_space(1))) void*)g,
      (__attribute__((address_space(3))) void*)lds_base,
      16, 0, 0);
}

__global__ __launch_bounds__(256)
void conv_k(const float* __restrict__ src, bf16* __restrict__ dst, long n) {
  const long stride = (long)gridDim.x * 256 * 8;
  for (long i = ((long)blockIdx.x * 256 + threadIdx.x) * 8; i < n; i += stride) {
    f32x4 a = *(const f32x4*)(src + i);
    f32x4 b = *(const f32x4*)(src + i + 4);
    union { short8 s; bf16 h[8]; } u;
#pragma unroll
    for (int j = 0; j < 4; ++j) { u.h[j] = f2b(a[j]); u.h[j + 4] = f2b(b[j]); }
    *(short8*)(dst + i) = u.s;
  }
}

// ---------------------------------------------------------------------------
// gemm8: 256x256 tile, BK=64, 8 waves (2Mx4N), 8-phase schedule with counted
// vmcnt (T3+T4) + XOR-8 swizzle (verified 0-conflict) + setprio (T5).
// Per K-tile per wave: 64 MFMA in 4 quadrant phases of 16.
// Stage stream (half-tile = 128 rows x 64 cols = 2 gload16/wave-group):
//   prologue: t0.A0,A1,B0,B1 -> buf0 ; t1.B0,t1.A0 -> buf1 ; vmcnt(4); bar
//   ph1:(t+1).A1  ph2:(t+1).B1  ph3:(t+2).B0  ph4:(t+2).A0 +vmcnt(4)
//   ph5:(t+2).A1  ph6:(t+2).B1  ph7:(t+3).B0  ph8:(t+3).A0 +vmcnt(4)
// Write-after-read safety: As[cur] read ph1,ph3 (free ph4+); Bs[cur] read
// ph1,ph2 (free ph3+); As[nxt] free ph8+/ph1'; Bs[nxt] free ph7+.  All stage
// slots above respect these via the phase-end barriers.
// ---------------------------------------------------------------------------
#define SB8()  __builtin_amdgcn_sched_barrier(0)
#define BAR8() { asm volatile("" ::: "memory"); __builtin_amdgcn_s_barrier(); asm volatile("" ::: "memory"); }
#define VMC4() { asm volatile("s_waitcnt vmcnt(4)" ::: "memory"); SB8(); }
#define LGK0() { asm volatile("s_waitcnt lgkmcnt(0)" ::: "memory"); SB8(); }

#define STG8(Gp, ldX, rowOff, kt, XsBuf)                                        \
  gload16(Gp + (size_t)((rowOff) + w8 + lr) * (size_t)(ldX) + (kt) + sCol,      \
          &XsBuf[(rowOff) + w8][0]);                                            \
  gload16(Gp + (size_t)((rowOff) + 64 + w8 + lr) * (size_t)(ldX) + (kt) + sCol, \
          &XsBuf[(rowOff) + 64 + w8][0]);

#define RD_A8(dst, XsBuf, mb)                                                   \
  _Pragma("unroll") for (int mi = 0; mi < 4; ++mi) {                            \
    const int ra = wmBase + ((mb) + mi) * 16 + c;                               \
    _Pragma("unroll") for (int kk = 0; kk < 2; ++kk)                            \
      dst[mi][kk] = *(const short8*)&XsBuf[ra][(((kk * 4 + g) ^ (ra & 7)) << 3)]; \
  }

#define RD_B8(dst, XsBuf, nb_)                                                  \
  _Pragma("unroll") for (int ni = 0; ni < 2; ++ni) {                            \
    const int rb = wnBase + ((nb_) + ni) * 16 + c;                              \
    _Pragma("unroll") for (int kk = 0; kk < 2; ++kk)                            \
      dst[ni][kk] = *(const short8*)&XsBuf[rb][(((kk * 4 + g) ^ (rb & 7)) << 3)]; \
  }

#define MFMA_Q8(afv, bfv, mb, nb_)                                              \
  __builtin_amdgcn_s_setprio(1);                                                \
  _Pragma("unroll") for (int mi = 0; mi < 4; ++mi)                              \
    _Pragma("unroll") for (int ni = 0; ni < 2; ++ni)                            \
      _Pragma("unroll") for (int kk = 0; kk < 2; ++kk)                          \
        acc[(mb) + mi][(nb_) + ni] = __builtin_amdgcn_mfma_f32_16x16x32_bf16(   \
            afv[mi][kk], bfv[ni][kk], acc[(mb) + mi][(nb_) + ni], 0, 0, 0);     \
  __builtin_amdgcn_s_setprio(0);

template <int EPI>
__global__ __launch_bounds__(512, 2)
void gemm8(const bf16* __restrict__ A, const bf16* __restrict__ Bt,
           const void* __restrict__ R, void* __restrict__ C,
           int N, int K, int ldb, long long boff) {
  __shared__ __align__(16) bf16 As[2][256][64];
  __shared__ __align__(16) bf16 Bs[2][256][64];
  const int tid = threadIdx.x;
  const int w = tid >> 6, l = tid & 63;
  const int g = l >> 4, c = l & 15;
  const int w8 = w * 8, lr = l >> 3;
  const int sCol = (((l & 7) ^ lr) << 3);

  const int nwg = gridDim.x * gridDim.y;
  const int orig = blockIdx.x + blockIdx.y * gridDim.x;
  const int qq = nwg >> 3, rr8 = nwg & 7;
  const int xcd = orig & 7, idx8 = orig >> 3;
  const int wg = (xcd < rr8 ? xcd * (qq + 1) : rr8 * (qq + 1) + (xcd - rr8) * qq) + idx8;
  const int bm = (wg / gridDim.x) * 256;
  const int bn = (wg % gridDim.x) * 256;

  const int wmBase = (w >> 2) * 128;
  const int wnBase = (w & 3) * 64;

  const bf16* Ab = A + (size_t)bm * K;
  const bf16* Bb = Bt + (size_t)bn * ldb + (size_t)boff;

  f32x4 acc[8][4] = {};
  const int nt = K >> 6;

  // prologue
  STG8(Ab, K, 0, 0, As[0]); STG8(Ab, K, 128, 0, As[0]);
  STG8(Bb, ldb, 0, 0, Bs[0]); STG8(Bb, ldb, 128, 0, Bs[0]);
  STG8(Bb, ldb, 0, 64, Bs[1]);
  STG8(Ab, K, 0, 64, As[1]);
  VMC4(); BAR8();

  short8 af[4][2], bf[2][2], af2[4][2], bf2[2][2];
  for (int it = 0; it < (nt >> 1); ++it) {
    const int t = it * 2;
    const int kt1 = (t + 1) << 6;
    const int kt2 = (t + 2 < nt ? t + 2 : nt - 1) << 6;
    const int kt3 = (t + 3 < nt ? t + 3 : nt - 1) << 6;
    // ph1
    RD_A8(af, As[0], 0); RD_B8(bf, Bs[0], 0);
    STG8(Ab, K, 128, kt1, As[1]);
    BAR8(); LGK0(); MFMA_Q8(af, bf, 0, 0); BAR8();
    // ph2
    RD_B8(bf2, Bs[0], 2);
    STG8(Bb, ldb, 128, kt1, Bs[1]);
    BAR8(); LGK0(); MFMA_Q8(af, bf2, 0, 2); BAR8();
    // ph3
    RD_A8(af2, As[0], 4);
    STG8(Bb, ldb, 0, kt2, Bs[0]);
    BAR8(); LGK0(); MFMA_Q8(af2, bf, 4, 0); BAR8();
    // ph4
    STG8(Ab, K, 0, kt2, As[0]);
    VMC4(); BAR8(); MFMA_Q8(af2, bf2, 4, 2); BAR8();
    // ph5
    RD_A8(af, As[1], 0); RD_B8(bf, Bs[1], 0);
    STG8(Ab, K, 128, kt2, As[0]);
    BAR8(); LGK0(); MFMA_Q8(af, bf, 0, 0); BAR8();
    // ph6
    RD_B8(bf2, Bs[1], 2);
    STG8(Bb, ldb, 128, kt2, Bs[0]);
    BAR8(); LGK0(); MFMA_Q8(af, bf2, 0, 2); BAR8();
    // ph7
    RD_A8(af2, As[1], 4);
    STG8(Bb, ldb, 0, kt3, Bs[1]);
    BAR8(); LGK0(); MFMA_Q8(af2, bf, 4, 0); BAR8();
    // ph8
    STG8(Ab, K, 0, kt3, As[1]);
    VMC4(); BAR8(); MFMA_Q8(af2, bf2, 4, 2); BAR8();
  }

  // epilogue: C/D col = c + n*16, row = g*4 + r within each 16x16
  const int rbase = bm + wmBase + g * 4;
  const int cbase = bn + wnBase + c;
#pragma unroll
  for (int m = 0; m < 8; ++m)
#pragma unroll
    for (int r = 0; r < 4; ++r) {
      const int row = rbase + m * 16 + r;
#pragma unroll
      for (int n = 0; n < 4; ++n) {
        const size_t idx = (size_t)row * N + (cbase + n * 16);
        float vacc = acc[m][n][r];
        if (EPI == 1) {
          ((float*)C)[idx] = vacc + ((const float*)R)[idx];
        } else if (EPI == 2) {
          const float u = b2f(((const bf16*)R)[idx]);
          ((bf16*)C)[idx] = f2b((u / (1.f + expf(-u))) * vacc);
        } else {
          ((bf16*)C)[idx] = f2b(vacc);
        }
      }
    }
}

// ---------------------------------------------------------------------------
// gemm3 (round-4 verified): 128x128, kept for w2 (and as reference).
// ---------------------------------------------------------------------------
template <int EPI>
__global__ __launch_bounds__(256)
void gemm3(const bf16* __restrict__ A, const bf16* __restrict__ Bt,
           const void* __restrict__ R, void* __restrict__ C,
           int N, int K, int ldb, long long boff) {
  __shared__ __align__(16) bf16 As[128][64];
  __shared__ __align__(16) bf16 Bs[128][64];
  const int tid = threadIdx.x;
  const int w = tid >> 6;
  const int l = tid & 63;

  const int nwg = gridDim.x * gridDim.y;
  const int orig = blockIdx.x + blockIdx.y * gridDim.x;
  const int qq = nwg >> 3, rr8 = nwg & 7;
  const int xcd = orig & 7, idx8 = orig >> 3;
  const int wg = (xcd < rr8 ? xcd * (qq + 1) : rr8 * (qq + 1) + (xcd - rr8) * qq) + idx8;
  const int bm = (wg / gridDim.x) * 128;
  const int bn = (wg % gridDim.x) * 128;

  const int wr = (w >> 1) * 64;
  const int wc = (w & 1) * 64;
  f32x4 acc[4][4] = {};

  const bf16* Ab = A + (size_t)bm * K;
  const bf16* Bb = Bt + (size_t)bn * ldb + (size_t)boff;

  const int sRow = w * 8 + (l >> 3);
  const int sCol = (((l & 7) ^ (l >> 3)) << 3);

  for (int kt = 0; kt < K; kt += 64) {
    __syncthreads();
#pragma unroll
    for (int i = 0; i < 4; ++i) {
      gload16(Ab + (size_t)(i * 32 + sRow) * K + kt + sCol, &As[i * 32 + w * 8][0]);
      gload16(Bb + (size_t)(i * 32 + sRow) * ldb + kt + sCol, &Bs[i * 32 + w * 8][0]);
    }
    __syncthreads();

#pragma unroll
    for (int kk = 0; kk < 2; ++kk) {
      short8 af[4], bfv[4];
#pragma unroll
      for (int m = 0; m < 4; ++m) {
        const int ra = wr + m * 16 + (l & 15);
        af[m] = *(const short8*)&As[ra][(((kk * 4 + (l >> 4)) ^ (ra & 7)) << 3)];
      }
#pragma unroll
      for (int n = 0; n < 4; ++n) {
        const int rb = wc + n * 16 + (l & 15);
        bfv[n] = *(const short8*)&Bs[rb][(((kk * 4 + (l >> 4)) ^ (rb & 7)) << 3)];
      }
#pragma unroll
      for (int m = 0; m < 4; ++m)
#pragma unroll
        for (int n = 0; n < 4; ++n)
          acc[m][n] = __builtin_amdgcn_mfma_f32_16x16x32_bf16(af[m], bfv[n], acc[m][n], 0, 0, 0);
    }
  }

  const int rbase = bm + wr + (l >> 4) * 4;
  const int cbase = bn + wc + (l & 15);
#pragma unroll
  for (int m = 0; m < 4; ++m)
#pragma unroll
    for (int r = 0; r < 4; ++r) {
      const int row = rbase + m * 16 + r;
#pragma unroll
      for (int n = 0; n < 4; ++n) {
        const size_t idx = (size_t)row * N + (cbase + n * 16);
        float vacc = acc[m][n][r];
        if (EPI == 1) {
          ((float*)C)[idx] = vacc + ((const float*)R)[idx];
        } else if (EPI == 2) {
          const float u = b2f(((const bf16*)R)[idx]);
          ((bf16*)C)[idx] = f2b((u / (1.f + expf(-u))) * vacc);
        } else {
          ((bf16*)C)[idx] = f2b(vacc);
        }
      }
    }
}

// ---------------------------------------------------------------------------
// PATH B GEMM (f32 weights) - fallback only.
// ---------------------------------------------------------------------------
template <int EPI>
__global__ __launch_bounds__(256)
void gemm2(const bf16* __restrict__ A, const float* __restrict__ Bt,
           const void* __restrict__ R, void* __restrict__ C,
           int N, int K, int ldb, long long boff) {
  __shared__ __align__(16) bf16 As[128][64];
  __shared__ __align__(16) float Bsf[128][64];
  const int tid = threadIdx.x;
  const int w = tid >> 6;
  const int l = tid & 63;

  const int nwg = gridDim.x * gridDim.y;
  const int orig = blockIdx.x + blockIdx.y * gridDim.x;
  const int qq = nwg >> 3, rr8 = nwg & 7;
  const int xcd = orig & 7, idx8 = orig >> 3;
  const int wg = (xcd < rr8 ? xcd * (qq + 1) : rr8 * (qq + 1) + (xcd - rr8) * qq) + idx8;
  const int bm = (wg / gridDim.x) * 128;
  const int bn = (wg % gridDim.x) * 128;

  const int wr = (w >> 1) * 64;
  const int wc = (w & 1) * 64;
  f32x4 acc[4][4] = {};

  const bf16* Ab = A + (size_t)bm * K;
  const float* Bb = Bt + (size_t)bn * ldb + (size_t)boff;

  const int aSrcCol = (((l & 7) ^ (l >> 3)) << 3);
  const int bKey = (w * 4 + (l >> 4)) & 7;
  const int bSrcCol = (((l & 15) ^ bKey) << 2);

  for (int kt = 0; kt < K; kt += 64) {
    __syncthreads();
#pragma unroll
    for (int i = 0; i < 4; ++i)
      gload16(Ab + (size_t)(i * 32 + w * 8 + (l >> 3)) * K + kt + aSrcCol,
              &As[i * 32 + w * 8][0]);
#pragma unroll
    for (int i = 0; i < 8; ++i)
      gload16(Bb + (size_t)(i * 16 + w * 4 + (l >> 4)) * ldb + kt + bSrcCol,
              &Bsf[i * 16 + w * 4][0]);
    __syncthreads();

#pragma unroll
    for (int kk = 0; kk < 2; ++kk) {
      short8 af[4], bfv[4];
#pragma unroll
      for (int m = 0; m < 4; ++m) {
        const int ra = wr + m * 16 + (l & 15);
        const int pb = (kk * 4 + (l >> 4)) ^ (ra & 7);
        af[m] = *(const short8*)&As[ra][pb * 8];
      }
#pragma unroll
      for (int n = 0; n < 4; ++n) {
        const int rb = wc + n * 16 + (l & 15);
        const int b0 = kk * 8 + (l >> 4) * 2;
        const f32x4 x0 = *(const f32x4*)&Bsf[rb][(b0 ^ (rb & 7)) * 4];
        const f32x4 x1 = *(const f32x4*)&Bsf[rb][((b0 + 1) ^ (rb & 7)) * 4];
        union { short8 s; bf16 h[8]; } u;
#pragma unroll
        for (int j = 0; j < 4; ++j) { u.h[j] = f2b(x0[j]); u.h[j + 4] = f2b(x1[j]); }
        bfv[n] = u.s;
      }
#pragma unroll
      for (int m = 0; m < 4; ++m)
#pragma unroll
        for (int n = 0; n < 4; ++n)
          acc[m][n] = __builtin_amdgcn_mfma_f32_16x16x32_bf16(af[m], bfv[n], acc[m][n], 0, 0, 0);
    }
  }

  const int rbase = bm + wr + (l >> 4) * 4;
  const int cbase = bn + wc + (l & 15);
#pragma unroll
  for (int m = 0; m < 4; ++m)
#pragma unroll
    for (int r = 0; r < 4; ++r) {
      const int row = rbase + m * 16 + r;
#pragma unroll
      for (int n = 0; n < 4; ++n) {
        const size_t idx = (size_t)row * N + (cbase + n * 16);
        float vacc = acc[m][n][r];
        if (EPI == 1) {
          ((float*)C)[idx] = vacc + ((const float*)R)[idx];
        } else if (EPI == 2) {
          const float u = b2f(((const bf16*)R)[idx]);
          ((bf16*)C)[idx] = f2b((u / (1.f + expf(-u))) * vacc);
        } else {
          ((bf16*)C)[idx] = f2b(vacc);
        }
      }
    }
}

// ---------------------------------------------------------------------------
__global__ __launch_bounds__(256)
void rmsnorm_k(const float* __restrict__ xin, const float* __restrict__ g,
               bf16* __restrict__ out) {
  const int row = blockIdx.x;
  const int tid = threadIdx.x;
  const float* xp = xin + (size_t)row * Dq + tid * 8;
  f32x4 a = *(const f32x4*)xp, b = *(const f32x4*)(xp + 4);
  float xf[8];
#pragma unroll
  for (int j = 0; j < 4; ++j) { xf[j] = a[j]; xf[j + 4] = b[j]; }
  float ss = 0.f;
#pragma unroll
  for (int j = 0; j < 8; ++j) ss += xf[j] * xf[j];
#pragma unroll
  for (int off = 32; off > 0; off >>= 1) ss += __shfl_down(ss, off);
  __shared__ float red[4];
  if ((tid & 63) == 0) red[tid >> 6] = ss;
  __syncthreads();
  const float rms = rsqrtf((red[0] + red[1] + red[2] + red[3]) * (1.f / (float)Dq) + 1e-6f);
  const float* gp = g + tid * 8;
  f32x4 ga = *(const f32x4*)gp, gb = *(const f32x4*)(gp + 4);
  union { short8 s; bf16 h[8]; } uo;
#pragma unroll
  for (int j = 0; j < 4; ++j) {
    uo.h[j] = f2b(xf[j] * rms * ga[j]);
    uo.h[j + 4] = f2b(xf[j + 4] * rms * gb[j]);
  }
  *(short8*)(out + (size_t)row * Dq + tid * 8) = uo.s;
}

// ---------------------------------------------------------------------------
__global__ __launch_bounds__(256)
void rope_k(bf16* __restrict__ q, bf16* __restrict__ k, int ld) {
  const size_t idx = (size_t)blockIdx.x * 256 + threadIdx.x;
  const int i = (int)(idx & 63);
  const int h = (int)((idx >> 6) & 15);
  const int s = (int)((idx >> 10) & 2047);
  const int b = (int)(idx >> 21);
  const float f = (float)s * powf(10000.f, -(float)i * (1.f / 64.f));
  float sn, cs;
  sincosf(f, &sn, &cs);
  const size_t base = ((size_t)(b * Sq + s)) * ld + h * DHq + i;
  const float qa = b2f(q[base]), qb_ = b2f(q[base + 64]);
  q[base] = f2b(qa * cs - qb_ * sn);
  q[base + 64] = f2b(qb_ * cs + qa * sn);
  const float ka = b2f(k[base]), kb_ = b2f(k[base + 64]);
  k[base] = f2b(ka * cs - kb_ * sn);
  k[base + 64] = f2b(kb_ * cs + ka * sn);
}

// ---------------------------------------------------------------------------
// Causal flash attention v3 (round-7 verified): balanced 256 blocks, dbuf
// prefetch, swapped QK^T, one barrier/tile.
// ---------------------------------------------------------------------------
__device__ __forceinline__ int swz8(int row) { return (((row >> 3) ^ row) & 7) << 3; }

#define ATTN_COMPUTE(AQ, QB, QROW, M_, L_, OACC, KV0, CUR)                        \
  {                                                                               \
    f32x4 sc[4] = {};                                                             \
    __builtin_amdgcn_s_setprio(1);                                                \
    _Pragma("unroll") for (int n = 0; n < 4; ++n) {                               \
      const int krow = n * 16 + c;                                                \
      const int sw = swz8(krow);                                                  \
      _Pragma("unroll") for (int kk = 0; kk < 4; ++kk) {                          \
        short8 ak = *(const short8*)&Ks[CUR][krow][(kk * 32 + g * 8) ^ sw];       \
        sc[n] = __builtin_amdgcn_mfma_f32_16x16x32_bf16(ak, AQ[kk], sc[n], 0, 0, 0); \
      }                                                                           \
    }                                                                             \
    __builtin_amdgcn_s_setprio(0);                                                \
    float p[4][4];                                                                \
    float tmax = -3.0e38f;                                                        \
    if ((KV0) + 63 <= (QB)) {                                                     \
      _Pragma("unroll") for (int n = 0; n < 4; ++n)                               \
        _Pragma("unroll") for (int r = 0; r < 4; ++r) {                           \
          const float val = sc[n][r] * SCALE;                                     \
          p[n][r] = val;                                                          \
          tmax = fmaxf(tmax, val);                                                \
        }                                                                         \
    } else {                                                                      \
      _Pragma("unroll") for (int n = 0; n < 4; ++n)                               \
        _Pragma("unroll") for (int r = 0; r < 4; ++r) {                           \
          const int kvg = (KV0) + n * 16 + g * 4 + r;                             \
          float val = sc[n][r] * SCALE;                                           \
          if (kvg > (QROW)) val = -3.0e38f;                                       \
          p[n][r] = val;                                                          \
          tmax = fmaxf(tmax, val);                                                \
        }                                                                         \
    }                                                                             \
    tmax = fmaxf(tmax, __shfl_xor(tmax, 16));                                     \
    tmax = fmaxf(tmax, __shfl_xor(tmax, 32));                                     \
    const bool grow = !__all(tmax <= M_);                                         \
    const float m_new = grow ? fmaxf(M_, tmax) : M_;                              \
    float tsum = 0.f;                                                             \
    _Pragma("unroll") for (int n = 0; n < 4; ++n)                                 \
      _Pragma("unroll") for (int r = 0; r < 4; ++r) {                             \
        const float pv = expf(p[n][r] - m_new);                                   \
        p[n][r] = pv;                                                             \
        tsum += pv;                                                               \
      }                                                                           \
    tsum += __shfl_xor(tsum, 16);                                                 \
    tsum += __shfl_xor(tsum, 32);                                                 \
    if (grow) {                                                                   \
      const float corr = expf(M_ - m_new);                                        \
      L_ = L_ * corr + tsum;                                                      \
      M_ = m_new;                                                                 \
      _Pragma("unroll") for (int dt = 0; dt < 8; ++dt) OACC[dt] *= corr;          \
    } else {                                                                      \
      L_ += tsum;                                                                 \
    }                                                                             \
    const int keyc = (c ^ (c >> 3)) & 7;                                          \
    _Pragma("unroll") for (int n = 0; n < 4; ++n) {                               \
      union { unsigned long long u; bf16 hh[4]; } pk;                             \
      _Pragma("unroll") for (int r = 0; r < 4; ++r) pk.hh[r] = f2b(p[n][r]);      \
      const int blk = (2 * n + (g >> 1)) ^ keyc;                                  \
      *(unsigned long long*)&Ps[w][c][blk * 8 + (g & 1) * 4] = pk.u;              \
    }                                                                             \
    short8 ap[2];                                                                 \
    _Pragma("unroll") for (int kk = 0; kk < 2; ++kk)                              \
      ap[kk] = *(const short8*)&Ps[w][c][(kk * 32 + g * 8) ^ (keyc << 3)];        \
    __builtin_amdgcn_s_setprio(1);                                                \
    _Pragma("unroll") for (int dt = 0; dt < 8; ++dt) {                            \
      const int vrow = dt * 16 + c;                                               \
      const int vsw = swz8(vrow);                                                 \
      _Pragma("unroll") for (int kk = 0; kk < 2; ++kk) {                          \
        short8 av = *(const short8*)&Vt[CUR][vrow][(kk * 32 + g * 8) ^ vsw];      \
        OACC[dt] = __builtin_amdgcn_mfma_f32_16x16x32_bf16(av, ap[kk], OACC[dt], 0, 0, 0); \
      }                                                                           \
    }                                                                             \
    __builtin_amdgcn_s_setprio(0);                                                \
  }

__global__ __launch_bounds__(512)
void attn_k(const bf16* __restrict__ q, const bf16* __restrict__ k,
            const bf16* __restrict__ v, bf16* __restrict__ o, int ld) {
  __shared__ __align__(16) bf16 Ks[2][64][128];
  __shared__ __align__(16) bf16 Vt[2][128][64];
  __shared__ __align__(16) bf16 Ps[8][16][64];
  const int tid = threadIdx.x;
  const int w = tid >> 6, l = tid & 63;
  const int g = l >> 4, c = l & 15;
  const int x = blockIdx.x;
  const int h = blockIdx.y;
  const int b = blockIdx.z;
  const size_t hoff = (size_t)h * DHq;
  const float SCALE = 0.08838834764831845f;

  const int q0h = (15 - x) * 128, q0l = x * 128;
  const int qbh = q0h + w * 16, qbl = q0l + w * 16;
  const int qrh = qbh + c, qrl = qbl + c;

  short8 aqh[4], aql[4];
  {
    const bf16* qph = q + (size_t)(b * Sq + qrh) * ld + hoff + g * 8;
    const bf16* qpl = q + (size_t)(b * Sq + qrl) * ld + hoff + g * 8;
#pragma unroll
    for (int kk = 0; kk < 4; ++kk) {
      aqh[kk] = *(const short8*)(qph + kk * 32);
      aql[kk] = *(const short8*)(qpl + kk * 32);
    }
  }

  float mh = -3.0e38f, lh = 0.f, ml = -3.0e38f, ll_ = 0.f;
  f32x4 oh[8] = {}, ol[8] = {};

  const int stRow = tid >> 4;
  const int stBlk = tid & 15;
  const int ntiles = (q0h >> 6) + 2;

  {
#pragma unroll
    for (int i = 0; i < 2; ++i) {
      const int kr = i * 32 + w * 4 + (l >> 4);
      const int key = (kr ^ (kr >> 3)) & 7;
      gload16(k + (size_t)(b * Sq + kr) * ld + hoff + ((c ^ key) << 3),
              &Ks[0][i * 32 + w * 4][0]);
    }
    const int c0 = stBlk * 8;
#pragma unroll
    for (int i = 0; i < 2; ++i) {
      const int vr = i * 32 + stRow;
      union { short8 s; bf16 hh[8]; } uv;
      uv.s = *(const short8*)(v + (size_t)(b * Sq + vr) * ld + hoff + c0);
#pragma unroll
      for (int j = 0; j < 8; ++j) Vt[0][c0 + j][vr ^ swz8(c0 + j)] = uv.hh[j];
    }
  }
  __syncthreads();

  for (int t = 0; t < ntiles; ++t) {
    const int cur = t & 1, nxt = cur ^ 1;
    const int kv0 = t * 64;
    const bool pf = (t + 1 < ntiles);
    short8 vpa, vpb;
    if (pf) {
      const int kvn = kv0 + 64;
#pragma unroll
      for (int i = 0; i < 2; ++i) {
        const int kr = i * 32 + w * 4 + (l >> 4);
        const int key = (kr ^ (kr >> 3)) & 7;
        gload16(k + (size_t)(b * Sq + kvn + kr) * ld + hoff + ((c ^ key) << 3),
                &Ks[nxt][i * 32 + w * 4][0]);
      }
      vpa = *(const short8*)(v + (size_t)(b * Sq + kvn + stRow) * ld + hoff + stBlk * 8);
      vpb = *(const short8*)(v + (size_t)(b * Sq + kvn + 32 + stRow) * ld + hoff + stBlk * 8);
    }

    if (kv0 <= qbh + 15) ATTN_COMPUTE(aqh, qbh, qrh, mh, lh, oh, kv0, cur);

    if (pf) {
      const int c0 = stBlk * 8;
      union { short8 s; bf16 hh[8]; } uv;
      uv.s = vpa;
#pragma unroll
      for (int j = 0; j < 8; ++j) Vt[nxt][c0 + j][stRow ^ swz8(c0 + j)] = uv.hh[j];
      uv.s = vpb;
#pragma unroll
      for (int j = 0; j < 8; ++j) Vt[nxt][c0 + j][(32 + stRow) ^ swz8(c0 + j)] = uv.hh[j];
    }

    if (kv0 <= qbl + 15) ATTN_COMPUTE(aql, qbl, qrl, ml, ll_, ol, kv0, cur);

    __syncthreads();
  }

  {
    const float inv = 1.f / lh;
    bf16* op = o + (size_t)(b * Sq + qrh) * Dq + hoff + g * 4;
#pragma unroll
    for (int dt = 0; dt < 8; ++dt) {
      union { unsigned long long u; bf16 hh[4]; } pk;
#pragma unroll
      for (int r = 0; r < 4; ++r) pk.hh[r] = f2b(oh[dt][r] * inv);
      *(unsigned long long*)(op + dt * 16) = pk.u;
    }
  }
  {
    const float inv = 1.f / ll_;
    bf16* op = o + (size_t)(b * Sq + qrl) * Dq + hoff + g * 4;
#pragma unroll
    for (int dt = 0; dt < 8; ++dt) {
      union { unsigned long long u; bf16 hh[4]; } pk;
#pragma unroll
      for (int r = 0; r < 4; ++r) pk.hh[r] = f2b(ol[dt][r] * inv);
      *(unsigned long long*)(op + dt * 16) = pk.u;
    }
  }
}

// ---------------------------------------------------------------------------
extern "C" void kernel_launch(void* const* d_in, const int* in_sizes, int n_in,
                              void* d_out, int out_size, void* d_ws, size_t ws_size,
                              hipStream_t stream) {
  (void)in_sizes; (void)n_in; (void)out_size;
  const float* x  = (const float*)d_in[0];
  const float* wq = (const float*)d_in[2];
  const float* wk = (const float*)d_in[3];
  const float* wv = (const float*)d_in[4];
  const float* wo = (const float*)d_in[5];
  const float* w1 = (const float*)d_in[6];
  const float* w2 = (const float*)d_in[7];
  const float* w3 = (const float*)d_in[8];
  const float* ga = (const float*)d_in[9];
  const float* gf = (const float*)d_in[10];
  float* out = (float*)d_out;

  char* ws = (char*)d_ws;
  dim3 blk(256);
  dim3 gA(8, Hq, Bq);
  dim3 blkA(512);
  dim3 blk8(512);

  const size_t SZ_H   = (size_t)Mq * Dq * 2;
  const size_t SZ_QKV = (size_t)Mq * 3 * Dq * 2;
  const size_t SZ_W4  = (size_t)Dq * Dq * 2;
  const size_t SZ_W13 = (size_t)FFq * Dq * 2;
  const size_t ACT    = SZ_H + SZ_QKV;
  const size_t WTS    = 3 * SZ_W4 + SZ_W4 + 3 * SZ_W13;
  const size_t NEED   = ACT + WTS;

  if (ws_size >= NEED) {
    // ---- PATH A: bf16 weights, 8-phase GEMMs where grid quantization allows
    bf16* h    = (bf16*)(ws);
    bf16* qkv  = (bf16*)(ws + SZ_H);
    bf16* ob   = h;
    bf16* h2   = qkv;
    bf16* ub   = (bf16*)(ws + SZ_H + SZ_H);
    char* wb   = ws + ACT;
    bf16* wqkv_b = (bf16*)(wb);
    bf16* wo_b   = (bf16*)(wb + 3 * SZ_W4);
    bf16* w1_b   = (bf16*)(wb + 4 * SZ_W4);
    bf16* w3_b   = (bf16*)(wb + 4 * SZ_W4 + SZ_W13);
    bf16* w2_b   = (bf16*)(wb + 4 * SZ_W4 + 2 * SZ_W13);

    const long nW4 = (long)Dq * Dq, nW13 = (long)FFq * Dq;
    conv_k<<<1024, blk, 0, stream>>>(wq, wqkv_b, nW4);
    conv_k<<<1024, blk, 0, stream>>>(wk, wqkv_b + nW4, nW4);
    conv_k<<<1024, blk, 0, stream>>>(wv, wqkv_b + 2 * nW4, nW4);
    conv_k<<<1024, blk, 0, stream>>>(wo, wo_b, nW4);
    conv_k<<<2048, blk, 0, stream>>>(w1, w1_b, nW13);
    conv_k<<<2048, blk, 0, stream>>>(w3, w3_b, nW13);
    conv_k<<<2048, blk, 0, stream>>>(w2, w2_b, nW13);

    rmsnorm_k<<<Mq, blk, 0, stream>>>(x, ga, h);
    gemm8<0><<<dim3(24, 16), blk8, 0, stream>>>(h, wqkv_b, nullptr, qkv, 6144, Dq, Dq, 0);
    rope_k<<<(Bq * Sq * Hq * 64) / 256, blk, 0, stream>>>(qkv, qkv + Dq, 3 * Dq);
    attn_k<<<gA, blkA, 0, stream>>>(qkv, qkv + Dq, qkv + 2 * Dq, ob, 3 * Dq);
    gemm8<1><<<dim3(8, 16), blk8, 0, stream>>>(ob, wo_b, x, out, Dq, Dq, Dq, 0);
    rmsnorm_k<<<Mq, blk, 0, stream>>>(out, gf, h2);
    for (int hh = 0; hh < 2; ++hh) {
      bf16* w1h = w1_b + (size_t)hh * 4096 * Dq;
      bf16* w3h = w3_b + (size_t)hh * 4096 * Dq;
      gemm8<0><<<dim3(16, 16), blk8, 0, stream>>>(h2, w1h, nullptr, ub, 4096, Dq, Dq, 0);
      gemm8<2><<<dim3(16, 16), blk8, 0, stream>>>(h2, w3h, ub, ub, 4096, Dq, Dq, 0);
      gemm3<1><<<dim3(16, 32), blk, 0, stream>>>(ub, w2_b, out, out, Dq, 4096, FFq,
                                                 (long long)hh * 4096);
    }
  } else {
    // ---- PATH B: f32-weight fallback ----
    const size_t MS = (size_t)Mq * Dq * 2;
    bf16* h  = (bf16*)(ws);
    bf16* kb = (bf16*)(ws + MS);
    bf16* vb = (bf16*)(ws + 2 * MS);
    bf16* qb = (bf16*)(ws + 3 * MS);
    bf16* ub = (bf16*)(ws);
    bf16* ob = h;
    bf16* h2 = qb;

    dim3 gD(Dq / 128, Mq / 128);
    dim3 gU(32, Mq / 128);

    rmsnorm_k<<<Mq, blk, 0, stream>>>(x, ga, h);
    gemm2<0><<<gD, blk, 0, stream>>>(h, wq, nullptr, qb, Dq, Dq, Dq, 0);
    gemm2<0><<<gD, blk, 0, stream>>>(h, wk, nullptr, kb, Dq, Dq, Dq, 0);
    gemm2<0><<<gD, blk, 0, stream>>>(h, wv, nullptr, vb, Dq, Dq, Dq, 0);
    rope_k<<<(Bq * Sq * Hq * 64) / 256, blk, 0, stream>>>(qb, kb, Dq);
    attn_k<<<gA, blkA, 0, stream>>>(qb, kb, vb, ob, Dq);
    gemm2<1><<<gD, blk, 0, stream>>>(ob, wo, x, out, Dq, Dq, Dq, 0);
    rmsnorm_k<<<Mq, blk, 0, stream>>>(out, gf, h2);
    for (int hh = 0; hh < 2; ++hh) {
      const long long bo13 = (long long)hh * 4096 * 2048;
      gemm2<0><<<gU, blk, 0, stream>>>(h2, w1, nullptr, ub, 4096, Dq, Dq, bo13);
      gemm2<2><<<gU, blk, 0, stream>>>(h2, w3, ub, ub, 4096, Dq, Dq, bo13);
      gemm2<1><<<gD, blk, 0, stream>>>(ub, w2, out, out, Dq, 4096, FFq,
                                       (long long)hh * 4096);
    }
  }
}

// Round 9
// 891.931 us; speedup vs baseline: 2.5182x; 1.0434x over previous
//
#include <hip/hip_runtime.h>
#include <hip/hip_bf16.h>
#include <math.h>

typedef __hip_bfloat16 bf16;
typedef short short8 __attribute__((ext_vector_type(8)));
typedef float f32x4 __attribute__((ext_vector_type(4)));

#define Bq 2
#define Sq 2048
#define Dq 2048
#define Hq 16
#define DHq 128
#define FFq 8192
#define Mq 4096  // Bq*Sq

__device__ __forceinline__ float b2f(bf16 x) { return __bfloat162float(x); }
__device__ __forceinline__ bf16 f2b(float x) { return __float2bfloat16(x); }

__device__ __forceinline__ void gload16(const void* g, void* lds_base) {
  __builtin_amdgcn_global_load_lds(
      (const __attribute__((address_space(1))) void*)g,
      (__attribute__((address_space(3))) void*)lds_base,
      16, 0, 0);
}

__global__ __launch_bounds__(256)
void conv_k(const float* __restrict__ src, bf16* __restrict__ dst, long n) {
  const long stride = (long)gridDim.x * 256 * 8;
  for (long i = ((long)blockIdx.x * 256 + threadIdx.x) * 8; i < n; i += stride) {
    f32x4 a = *(const f32x4*)(src + i);
    f32x4 b = *(const f32x4*)(src + i + 4);
    union { short8 s; bf16 h[8]; } u;
#pragma unroll
    for (int j = 0; j < 4; ++j) { u.h[j] = f2b(a[j]); u.h[j + 4] = f2b(b[j]); }
    *(short8*)(dst + i) = u.s;
  }
}

// ---------------------------------------------------------------------------
// gemm8 v2: 256x256, BK=64, 8 waves (2Mx4N). 4 phases per 2 K-tiles, counted
// vmcnt(4), NO explicit lgkm waits (compiler emits fine-grained per-use
// waits -> ds_reads drain under the 32-MFMA clusters). 8 barriers/iter.
// Stage slotting (halves; buf0=even tiles, buf1=odd):
//   prologue: t0.{A0,A1,B0,B1}->buf0, t1.{B0,B1}->buf1; vmcnt(4); bar
//   P1: RD buf0 af(A0),bf(B0),bf2(B1); STG t+1.{A0,A1}->buf1 ; MFMA mb0-3
//   P2: RD buf0 af2(A1);               STG t+2.{B0,B1}->buf0 ; MFMA mb4-7; vmcnt(4)
//   P3: RD buf1 af,bf,bf2;             STG t+2.{A0,A1}->buf0 ; MFMA mb0-3
//   P4: RD buf1 af2;                   STG t+3.{B0,B1}->buf1 ; MFMA mb4-7; vmcnt(4)
// WAR: every ds_read is consumed (=> waitcnt-drained) within its phase before
// the closing barrier; each STG targets rows whose reads finished >=1 phase
// earlier. RAW: vmcnt(4)+barrier drains tile t+1 at P2-close, t+2 at P4-close.
// ---------------------------------------------------------------------------
#define BAR8() { asm volatile("" ::: "memory"); __builtin_amdgcn_s_barrier(); asm volatile("" ::: "memory"); }
#define VMC4() { asm volatile("s_waitcnt vmcnt(4)" ::: "memory"); __builtin_amdgcn_sched_barrier(0); }

#define STG8(Gp, ldX, rowOff, kt, XsBuf)                                        \
  gload16(Gp + (size_t)((rowOff) + w8 + lr) * (size_t)(ldX) + (kt) + sCol,      \
          &XsBuf[(rowOff) + w8][0]);                                            \
  gload16(Gp + (size_t)((rowOff) + 64 + w8 + lr) * (size_t)(ldX) + (kt) + sCol, \
          &XsBuf[(rowOff) + 64 + w8][0]);

#define RD_A8(dst, XsBuf, mb)                                                   \
  _Pragma("unroll") for (int mi = 0; mi < 4; ++mi) {                            \
    const int ra = wmBase + ((mb) + mi) * 16 + c;                               \
    _Pragma("unroll") for (int kk = 0; kk < 2; ++kk)                            \
      dst[mi][kk] = *(const short8*)&XsBuf[ra][(((kk * 4 + g) ^ (ra & 7)) << 3)]; \
  }

#define RD_B8(dst, XsBuf, nb_)                                                  \
  _Pragma("unroll") for (int ni = 0; ni < 2; ++ni) {                            \
    const int rb = wnBase + ((nb_) + ni) * 16 + c;                              \
    _Pragma("unroll") for (int kk = 0; kk < 2; ++kk)                            \
      dst[ni][kk] = *(const short8*)&XsBuf[rb][(((kk * 4 + g) ^ (rb & 7)) << 3)]; \
  }

#define MFMA_Q8(afv, bfv, mb, nb_)                                              \
  __builtin_amdgcn_s_setprio(1);                                                \
  _Pragma("unroll") for (int mi = 0; mi < 4; ++mi)                              \
    _Pragma("unroll") for (int ni = 0; ni < 2; ++ni)                            \
      _Pragma("unroll") for (int kk = 0; kk < 2; ++kk)                          \
        acc[(mb) + mi][(nb_) + ni] = __builtin_amdgcn_mfma_f32_16x16x32_bf16(   \
            afv[mi][kk], bfv[ni][kk], acc[(mb) + mi][(nb_) + ni], 0, 0, 0);     \
  __builtin_amdgcn_s_setprio(0);

template <int EPI>
__global__ __launch_bounds__(512, 2)
void gemm8(const bf16* __restrict__ A, const bf16* __restrict__ Bt,
           const void* __restrict__ R, void* __restrict__ C,
           int N, int K, int ldb, long long boff) {
  __shared__ __align__(16) bf16 As[2][256][64];
  __shared__ __align__(16) bf16 Bs[2][256][64];
  const int tid = threadIdx.x;
  const int w = tid >> 6, l = tid & 63;
  const int g = l >> 4, c = l & 15;
  const int w8 = w * 8, lr = l >> 3;
  const int sCol = (((l & 7) ^ lr) << 3);

  const int nwg = gridDim.x * gridDim.y;
  const int orig = blockIdx.x + blockIdx.y * gridDim.x;
  const int qq = nwg >> 3, rr8 = nwg & 7;
  const int xcd = orig & 7, idx8 = orig >> 3;
  const int wg = (xcd < rr8 ? xcd * (qq + 1) : rr8 * (qq + 1) + (xcd - rr8) * qq) + idx8;
  const int bm = (wg / gridDim.x) * 256;
  const int bn = (wg % gridDim.x) * 256;

  const int wmBase = (w >> 2) * 128;
  const int wnBase = (w & 3) * 64;

  const bf16* Ab = A + (size_t)bm * K;
  const bf16* Bb = Bt + (size_t)bn * ldb + (size_t)boff;

  f32x4 acc[8][4] = {};
  const int nt = K >> 6;

  // prologue: t0 complete + t1.{B0,B1}
  STG8(Ab, K, 0, 0, As[0]); STG8(Ab, K, 128, 0, As[0]);
  STG8(Bb, ldb, 0, 0, Bs[0]); STG8(Bb, ldb, 128, 0, Bs[0]);
  STG8(Bb, ldb, 0, 64, Bs[1]); STG8(Bb, ldb, 128, 64, Bs[1]);
  VMC4(); BAR8();

  short8 af[4][2], af2[4][2], bf[2][2], bf2[2][2];
  for (int it = 0; it < (nt >> 1); ++it) {
    const int t = it * 2;
    const int kt1 = (t + 1) << 6;
    const int kt2 = (t + 2 < nt ? t + 2 : nt - 1) << 6;
    const int kt3 = (t + 3 < nt ? t + 3 : nt - 1) << 6;
    // P1 (tile t, buf0)
    RD_A8(af, As[0], 0); RD_B8(bf, Bs[0], 0); RD_B8(bf2, Bs[0], 2);
    STG8(Ab, K, 0, kt1, As[1]); STG8(Ab, K, 128, kt1, As[1]);
    BAR8();
    MFMA_Q8(af, bf, 0, 0); MFMA_Q8(af, bf2, 0, 2);
    BAR8();
    // P2
    RD_A8(af2, As[0], 4);
    STG8(Bb, ldb, 0, kt2, Bs[0]); STG8(Bb, ldb, 128, kt2, Bs[0]);
    BAR8();
    MFMA_Q8(af2, bf, 4, 0); MFMA_Q8(af2, bf2, 4, 2);
    VMC4(); BAR8();
    // P3 (tile t+1, buf1)
    RD_A8(af, As[1], 0); RD_B8(bf, Bs[1], 0); RD_B8(bf2, Bs[1], 2);
    STG8(Ab, K, 0, kt2, As[0]); STG8(Ab, K, 128, kt2, As[0]);
    BAR8();
    MFMA_Q8(af, bf, 0, 0); MFMA_Q8(af, bf2, 0, 2);
    BAR8();
    // P4
    RD_A8(af2, As[1], 4);
    STG8(Bb, ldb, 0, kt3, Bs[1]); STG8(Bb, ldb, 128, kt3, Bs[1]);
    BAR8();
    MFMA_Q8(af2, bf, 4, 0); MFMA_Q8(af2, bf2, 4, 2);
    VMC4(); BAR8();
  }

  // epilogue: C/D col = c + n*16, row = g*4 + r within each 16x16
  const int rbase = bm + wmBase + g * 4;
  const int cbase = bn + wnBase + c;
#pragma unroll
  for (int m = 0; m < 8; ++m)
#pragma unroll
    for (int r = 0; r < 4; ++r) {
      const int row = rbase + m * 16 + r;
#pragma unroll
      for (int n = 0; n < 4; ++n) {
        const size_t idx = (size_t)row * N + (cbase + n * 16);
        float vacc = acc[m][n][r];
        if (EPI == 1) {
          ((float*)C)[idx] = vacc + ((const float*)R)[idx];
        } else if (EPI == 2) {
          const float u = b2f(((const bf16*)R)[idx]);
          ((bf16*)C)[idx] = f2b((u / (1.f + expf(-u))) * vacc);
        } else {
          ((bf16*)C)[idx] = f2b(vacc);
        }
      }
    }
}

// ---------------------------------------------------------------------------
// gemm3 (verified): 128x128, 4 waves, 36.6% MfmaUtil. Used for QKV/wo/w2.
// ---------------------------------------------------------------------------
template <int EPI>
__global__ __launch_bounds__(256)
void gemm3(const bf16* __restrict__ A, const bf16* __restrict__ Bt,
           const void* __restrict__ R, void* __restrict__ C,
           int N, int K, int ldb, long long boff) {
  __shared__ __align__(16) bf16 As[128][64];
  __shared__ __align__(16) bf16 Bs[128][64];
  const int tid = threadIdx.x;
  const int w = tid >> 6;
  const int l = tid & 63;

  const int nwg = gridDim.x * gridDim.y;
  const int orig = blockIdx.x + blockIdx.y * gridDim.x;
  const int qq = nwg >> 3, rr8 = nwg & 7;
  const int xcd = orig & 7, idx8 = orig >> 3;
  const int wg = (xcd < rr8 ? xcd * (qq + 1) : rr8 * (qq + 1) + (xcd - rr8) * qq) + idx8;
  const int bm = (wg / gridDim.x) * 128;
  const int bn = (wg % gridDim.x) * 128;

  const int wr = (w >> 1) * 64;
  const int wc = (w & 1) * 64;
  f32x4 acc[4][4] = {};

  const bf16* Ab = A + (size_t)bm * K;
  const bf16* Bb = Bt + (size_t)bn * ldb + (size_t)boff;

  const int sRow = w * 8 + (l >> 3);
  const int sCol = (((l & 7) ^ (l >> 3)) << 3);

  for (int kt = 0; kt < K; kt += 64) {
    __syncthreads();
#pragma unroll
    for (int i = 0; i < 4; ++i) {
      gload16(Ab + (size_t)(i * 32 + sRow) * K + kt + sCol, &As[i * 32 + w * 8][0]);
      gload16(Bb + (size_t)(i * 32 + sRow) * ldb + kt + sCol, &Bs[i * 32 + w * 8][0]);
    }
    __syncthreads();

#pragma unroll
    for (int kk = 0; kk < 2; ++kk) {
      short8 af[4], bfv[4];
#pragma unroll
      for (int m = 0; m < 4; ++m) {
        const int ra = wr + m * 16 + (l & 15);
        af[m] = *(const short8*)&As[ra][(((kk * 4 + (l >> 4)) ^ (ra & 7)) << 3)];
      }
#pragma unroll
      for (int n = 0; n < 4; ++n) {
        const int rb = wc + n * 16 + (l & 15);
        bfv[n] = *(const short8*)&Bs[rb][(((kk * 4 + (l >> 4)) ^ (rb & 7)) << 3)];
      }
#pragma unroll
      for (int m = 0; m < 4; ++m)
#pragma unroll
        for (int n = 0; n < 4; ++n)
          acc[m][n] = __builtin_amdgcn_mfma_f32_16x16x32_bf16(af[m], bfv[n], acc[m][n], 0, 0, 0);
    }
  }

  const int rbase = bm + wr + (l >> 4) * 4;
  const int cbase = bn + wc + (l & 15);
#pragma unroll
  for (int m = 0; m < 4; ++m)
#pragma unroll
    for (int r = 0; r < 4; ++r) {
      const int row = rbase + m * 16 + r;
#pragma unroll
      for (int n = 0; n < 4; ++n) {
        const size_t idx = (size_t)row * N + (cbase + n * 16);
        float vacc = acc[m][n][r];
        if (EPI == 1) {
          ((float*)C)[idx] = vacc + ((const float*)R)[idx];
        } else if (EPI == 2) {
          const float u = b2f(((const bf16*)R)[idx]);
          ((bf16*)C)[idx] = f2b((u / (1.f + expf(-u))) * vacc);
        } else {
          ((bf16*)C)[idx] = f2b(vacc);
        }
      }
    }
}

// ---------------------------------------------------------------------------
// PATH B GEMM (f32 weights) - fallback only.
// ---------------------------------------------------------------------------
template <int EPI>
__global__ __launch_bounds__(256)
void gemm2(const bf16* __restrict__ A, const float* __restrict__ Bt,
           const void* __restrict__ R, void* __restrict__ C,
           int N, int K, int ldb, long long boff) {
  __shared__ __align__(16) bf16 As[128][64];
  __shared__ __align__(16) float Bsf[128][64];
  const int tid = threadIdx.x;
  const int w = tid >> 6;
  const int l = tid & 63;

  const int nwg = gridDim.x * gridDim.y;
  const int orig = blockIdx.x + blockIdx.y * gridDim.x;
  const int qq = nwg >> 3, rr8 = nwg & 7;
  const int xcd = orig & 7, idx8 = orig >> 3;
  const int wg = (xcd < rr8 ? xcd * (qq + 1) : rr8 * (qq + 1) + (xcd - rr8) * qq) + idx8;
  const int bm = (wg / gridDim.x) * 128;
  const int bn = (wg % gridDim.x) * 128;

  const int wr = (w >> 1) * 64;
  const int wc = (w & 1) * 64;
  f32x4 acc[4][4] = {};

  const bf16* Ab = A + (size_t)bm * K;
  const float* Bb = Bt + (size_t)bn * ldb + (size_t)boff;

  const int aSrcCol = (((l & 7) ^ (l >> 3)) << 3);
  const int bKey = (w * 4 + (l >> 4)) & 7;
  const int bSrcCol = (((l & 15) ^ bKey) << 2);

  for (int kt = 0; kt < K; kt += 64) {
    __syncthreads();
#pragma unroll
    for (int i = 0; i < 4; ++i)
      gload16(Ab + (size_t)(i * 32 + w * 8 + (l >> 3)) * K + kt + aSrcCol,
              &As[i * 32 + w * 8][0]);
#pragma unroll
    for (int i = 0; i < 8; ++i)
      gload16(Bb + (size_t)(i * 16 + w * 4 + (l >> 4)) * ldb + kt + bSrcCol,
              &Bsf[i * 16 + w * 4][0]);
    __syncthreads();

#pragma unroll
    for (int kk = 0; kk < 2; ++kk) {
      short8 af[4], bfv[4];
#pragma unroll
      for (int m = 0; m < 4; ++m) {
        const int ra = wr + m * 16 + (l & 15);
        const int pb = (kk * 4 + (l >> 4)) ^ (ra & 7);
        af[m] = *(const short8*)&As[ra][pb * 8];
      }
#pragma unroll
      for (int n = 0; n < 4; ++n) {
        const int rb = wc + n * 16 + (l & 15);
        const int b0 = kk * 8 + (l >> 4) * 2;
        const f32x4 x0 = *(const f32x4*)&Bsf[rb][(b0 ^ (rb & 7)) * 4];
        const f32x4 x1 = *(const f32x4*)&Bsf[rb][((b0 + 1) ^ (rb & 7)) * 4];
        union { short8 s; bf16 h[8]; } u;
#pragma unroll
        for (int j = 0; j < 4; ++j) { u.h[j] = f2b(x0[j]); u.h[j + 4] = f2b(x1[j]); }
        bfv[n] = u.s;
      }
#pragma unroll
      for (int m = 0; m < 4; ++m)
#pragma unroll
        for (int n = 0; n < 4; ++n)
          acc[m][n] = __builtin_amdgcn_mfma_f32_16x16x32_bf16(af[m], bfv[n], acc[m][n], 0, 0, 0);
    }
  }

  const int rbase = bm + wr + (l >> 4) * 4;
  const int cbase = bn + wc + (l & 15);
#pragma unroll
  for (int m = 0; m < 4; ++m)
#pragma unroll
    for (int r = 0; r < 4; ++r) {
      const int row = rbase + m * 16 + r;
#pragma unroll
      for (int n = 0; n < 4; ++n) {
        const size_t idx = (size_t)row * N + (cbase + n * 16);
        float vacc = acc[m][n][r];
        if (EPI == 1) {
          ((float*)C)[idx] = vacc + ((const float*)R)[idx];
        } else if (EPI == 2) {
          const float u = b2f(((const bf16*)R)[idx]);
          ((bf16*)C)[idx] = f2b((u / (1.f + expf(-u))) * vacc);
        } else {
          ((bf16*)C)[idx] = f2b(vacc);
        }
      }
    }
}

// ---------------------------------------------------------------------------
__global__ __launch_bounds__(256)
void rmsnorm_k(const float* __restrict__ xin, const float* __restrict__ g,
               bf16* __restrict__ out) {
  const int row = blockIdx.x;
  const int tid = threadIdx.x;
  const float* xp = xin + (size_t)row * Dq + tid * 8;
  f32x4 a = *(const f32x4*)xp, b = *(const f32x4*)(xp + 4);
  float xf[8];
#pragma unroll
  for (int j = 0; j < 4; ++j) { xf[j] = a[j]; xf[j + 4] = b[j]; }
  float ss = 0.f;
#pragma unroll
  for (int j = 0; j < 8; ++j) ss += xf[j] * xf[j];
#pragma unroll
  for (int off = 32; off > 0; off >>= 1) ss += __shfl_down(ss, off);
  __shared__ float red[4];
  if ((tid & 63) == 0) red[tid >> 6] = ss;
  __syncthreads();
  const float rms = rsqrtf((red[0] + red[1] + red[2] + red[3]) * (1.f / (float)Dq) + 1e-6f);
  const float* gp = g + tid * 8;
  f32x4 ga = *(const f32x4*)gp, gb = *(const f32x4*)(gp + 4);
  union { short8 s; bf16 h[8]; } uo;
#pragma unroll
  for (int j = 0; j < 4; ++j) {
    uo.h[j] = f2b(xf[j] * rms * ga[j]);
    uo.h[j + 4] = f2b(xf[j + 4] * rms * gb[j]);
  }
  *(short8*)(out + (size_t)row * Dq + tid * 8) = uo.s;
}

// ---------------------------------------------------------------------------
__global__ __launch_bounds__(256)
void rope_k(bf16* __restrict__ q, bf16* __restrict__ k, int ld) {
  const size_t idx = (size_t)blockIdx.x * 256 + threadIdx.x;
  const int i = (int)(idx & 63);
  const int h = (int)((idx >> 6) & 15);
  const int s = (int)((idx >> 10) & 2047);
  const int b = (int)(idx >> 21);
  const float f = (float)s * powf(10000.f, -(float)i * (1.f / 64.f));
  float sn, cs;
  sincosf(f, &sn, &cs);
  const size_t base = ((size_t)(b * Sq + s)) * ld + h * DHq + i;
  const float qa = b2f(q[base]), qb_ = b2f(q[base + 64]);
  q[base] = f2b(qa * cs - qb_ * sn);
  q[base + 64] = f2b(qb_ * cs + qa * sn);
  const float ka = b2f(k[base]), kb_ = b2f(k[base + 64]);
  k[base] = f2b(ka * cs - kb_ * sn);
  k[base + 64] = f2b(kb_ * cs + ka * sn);
}

// ---------------------------------------------------------------------------
// Causal flash attention v3 (round-7 verified): balanced 256 blocks, dbuf
// prefetch, swapped QK^T, one barrier/tile.
// ---------------------------------------------------------------------------
__device__ __forceinline__ int swz8(int row) { return (((row >> 3) ^ row) & 7) << 3; }

#define ATTN_COMPUTE(AQ, QB, QROW, M_, L_, OACC, KV0, CUR)                        \
  {                                                                               \
    f32x4 sc[4] = {};                                                             \
    __builtin_amdgcn_s_setprio(1);                                                \
    _Pragma("unroll") for (int n = 0; n < 4; ++n) {                               \
      const int krow = n * 16 + c;                                                \
      const int sw = swz8(krow);                                                  \
      _Pragma("unroll") for (int kk = 0; kk < 4; ++kk) {                          \
        short8 ak = *(const short8*)&Ks[CUR][krow][(kk * 32 + g * 8) ^ sw];       \
        sc[n] = __builtin_amdgcn_mfma_f32_16x16x32_bf16(ak, AQ[kk], sc[n], 0, 0, 0); \
      }                                                                           \
    }                                                                             \
    __builtin_amdgcn_s_setprio(0);                                                \
    float p[4][4];                                                                \
    float tmax = -3.0e38f;                                                        \
    if ((KV0) + 63 <= (QB)) {                                                     \
      _Pragma("unroll") for (int n = 0; n < 4; ++n)                               \
        _Pragma("unroll") for (int r = 0; r < 4; ++r) {                           \
          const float val = sc[n][r] * SCALE;                                     \
          p[n][r] = val;                                                          \
          tmax = fmaxf(tmax, val);                                                \
        }                                                                         \
    } else {                                                                      \
      _Pragma("unroll") for (int n = 0; n < 4; ++n)                               \
        _Pragma("unroll") for (int r = 0; r < 4; ++r) {                           \
          const int kvg = (KV0) + n * 16 + g * 4 + r;                             \
          float val = sc[n][r] * SCALE;                                           \
          if (kvg > (QROW)) val = -3.0e38f;                                       \
          p[n][r] = val;                                                          \
          tmax = fmaxf(tmax, val);                                                \
        }                                                                         \
    }                                                                             \
    tmax = fmaxf(tmax, __shfl_xor(tmax, 16));                                     \
    tmax = fmaxf(tmax, __shfl_xor(tmax, 32));                                     \
    const bool grow = !__all(tmax <= M_);                                         \
    const float m_new = grow ? fmaxf(M_, tmax) : M_;                              \
    float tsum = 0.f;                                                             \
    _Pragma("unroll") for (int n = 0; n < 4; ++n)                                 \
      _Pragma("unroll") for (int r = 0; r < 4; ++r) {                             \
        const float pv = expf(p[n][r] - m_new);                                   \
        p[n][r] = pv;                                                             \
        tsum += pv;                                                               \
      }                                                                           \
    tsum += __shfl_xor(tsum, 16);                                                 \
    tsum += __shfl_xor(tsum, 32);                                                 \
    if (grow) {                                                                   \
      const float corr = expf(M_ - m_new);                                        \
      L_ = L_ * corr + tsum;                                                      \
      M_ = m_new;                                                                 \
      _Pragma("unroll") for (int dt = 0; dt < 8; ++dt) OACC[dt] *= corr;          \
    } else {                                                                      \
      L_ += tsum;                                                                 \
    }                                                                             \
    const int keyc = (c ^ (c >> 3)) & 7;                                          \
    _Pragma("unroll") for (int n = 0; n < 4; ++n) {                               \
      union { unsigned long long u; bf16 hh[4]; } pk;                             \
      _Pragma("unroll") for (int r = 0; r < 4; ++r) pk.hh[r] = f2b(p[n][r]);      \
      const int blk = (2 * n + (g >> 1)) ^ keyc;                                  \
      *(unsigned long long*)&Ps[w][c][blk * 8 + (g & 1) * 4] = pk.u;              \
    }                                                                             \
    short8 ap[2];                                                                 \
    _Pragma("unroll") for (int kk = 0; kk < 2; ++kk)                              \
      ap[kk] = *(const short8*)&Ps[w][c][(kk * 32 + g * 8) ^ (keyc << 3)];        \
    __builtin_amdgcn_s_setprio(1);                                                \
    _Pragma("unroll") for (int dt = 0; dt < 8; ++dt) {                            \
      const int vrow = dt * 16 + c;                                               \
      const int vsw = swz8(vrow);                                                 \
      _Pragma("unroll") for (int kk = 0; kk < 2; ++kk) {                          \
        short8 av = *(const short8*)&Vt[CUR][vrow][(kk * 32 + g * 8) ^ vsw];      \
        OACC[dt] = __builtin_amdgcn_mfma_f32_16x16x32_bf16(av, ap[kk], OACC[dt], 0, 0, 0); \
      }                                                                           \
    }                                                                             \
    __builtin_amdgcn_s_setprio(0);                                                \
  }

__global__ __launch_bounds__(512)
void attn_k(const bf16* __restrict__ q, const bf16* __restrict__ k,
            const bf16* __restrict__ v, bf16* __restrict__ o, int ld) {
  __shared__ __align__(16) bf16 Ks[2][64][128];
  __shared__ __align__(16) bf16 Vt[2][128][64];
  __shared__ __align__(16) bf16 Ps[8][16][64];
  const int tid = threadIdx.x;
  const int w = tid >> 6, l = tid & 63;
  const int g = l >> 4, c = l & 15;
  const int x = blockIdx.x;
  const int h = blockIdx.y;
  const int b = blockIdx.z;
  const size_t hoff = (size_t)h * DHq;
  const float SCALE = 0.08838834764831845f;

  const int q0h = (15 - x) * 128, q0l = x * 128;
  const int qbh = q0h + w * 16, qbl = q0l + w * 16;
  const int qrh = qbh + c, qrl = qbl + c;

  short8 aqh[4], aql[4];
  {
    const bf16* qph = q + (size_t)(b * Sq + qrh) * ld + hoff + g * 8;
    const bf16* qpl = q + (size_t)(b * Sq + qrl) * ld + hoff + g * 8;
#pragma unroll
    for (int kk = 0; kk < 4; ++kk) {
      aqh[kk] = *(const short8*)(qph + kk * 32);
      aql[kk] = *(const short8*)(qpl + kk * 32);
    }
  }

  float mh = -3.0e38f, lh = 0.f, ml = -3.0e38f, ll_ = 0.f;
  f32x4 oh[8] = {}, ol[8] = {};

  const int stRow = tid >> 4;
  const int stBlk = tid & 15;
  const int ntiles = (q0h >> 6) + 2;

  {
#pragma unroll
    for (int i = 0; i < 2; ++i) {
      const int kr = i * 32 + w * 4 + (l >> 4);
      const int key = (kr ^ (kr >> 3)) & 7;
      gload16(k + (size_t)(b * Sq + kr) * ld + hoff + ((c ^ key) << 3),
              &Ks[0][i * 32 + w * 4][0]);
    }
    const int c0 = stBlk * 8;
#pragma unroll
    for (int i = 0; i < 2; ++i) {
      const int vr = i * 32 + stRow;
      union { short8 s; bf16 hh[8]; } uv;
      uv.s = *(const short8*)(v + (size_t)(b * Sq + vr) * ld + hoff + c0);
#pragma unroll
      for (int j = 0; j < 8; ++j) Vt[0][c0 + j][vr ^ swz8(c0 + j)] = uv.hh[j];
    }
  }
  __syncthreads();

  for (int t = 0; t < ntiles; ++t) {
    const int cur = t & 1, nxt = cur ^ 1;
    const int kv0 = t * 64;
    const bool pf = (t + 1 < ntiles);
    short8 vpa, vpb;
    if (pf) {
      const int kvn = kv0 + 64;
#pragma unroll
      for (int i = 0; i < 2; ++i) {
        const int kr = i * 32 + w * 4 + (l >> 4);
        const int key = (kr ^ (kr >> 3)) & 7;
        gload16(k + (size_t)(b * Sq + kvn + kr) * ld + hoff + ((c ^ key) << 3),
                &Ks[nxt][i * 32 + w * 4][0]);
      }
      vpa = *(const short8*)(v + (size_t)(b * Sq + kvn + stRow) * ld + hoff + stBlk * 8);
      vpb = *(const short8*)(v + (size_t)(b * Sq + kvn + 32 + stRow) * ld + hoff + stBlk * 8);
    }

    if (kv0 <= qbh + 15) ATTN_COMPUTE(aqh, qbh, qrh, mh, lh, oh, kv0, cur);

    if (pf) {
      const int c0 = stBlk * 8;
      union { short8 s; bf16 hh[8]; } uv;
      uv.s = vpa;
#pragma unroll
      for (int j = 0; j < 8; ++j) Vt[nxt][c0 + j][stRow ^ swz8(c0 + j)] = uv.hh[j];
      uv.s = vpb;
#pragma unroll
      for (int j = 0; j < 8; ++j) Vt[nxt][c0 + j][(32 + stRow) ^ swz8(c0 + j)] = uv.hh[j];
    }

    if (kv0 <= qbl + 15) ATTN_COMPUTE(aql, qbl, qrl, ml, ll_, ol, kv0, cur);

    __syncthreads();
  }

  {
    const float inv = 1.f / lh;
    bf16* op = o + (size_t)(b * Sq + qrh) * Dq + hoff + g * 4;
#pragma unroll
    for (int dt = 0; dt < 8; ++dt) {
      union { unsigned long long u; bf16 hh[4]; } pk;
#pragma unroll
      for (int r = 0; r < 4; ++r) pk.hh[r] = f2b(oh[dt][r] * inv);
      *(unsigned long long*)(op + dt * 16) = pk.u;
    }
  }
  {
    const float inv = 1.f / ll_;
    bf16* op = o + (size_t)(b * Sq + qrl) * Dq + hoff + g * 4;
#pragma unroll
    for (int dt = 0; dt < 8; ++dt) {
      union { unsigned long long u; bf16 hh[4]; } pk;
#pragma unroll
      for (int r = 0; r < 4; ++r) pk.hh[r] = f2b(ol[dt][r] * inv);
      *(unsigned long long*)(op + dt * 16) = pk.u;
    }
  }
}

// ---------------------------------------------------------------------------
extern "C" void kernel_launch(void* const* d_in, const int* in_sizes, int n_in,
                              void* d_out, int out_size, void* d_ws, size_t ws_size,
                              hipStream_t stream) {
  (void)in_sizes; (void)n_in; (void)out_size;
  const float* x  = (const float*)d_in[0];
  const float* wq = (const float*)d_in[2];
  const float* wk = (const float*)d_in[3];
  const float* wv = (const float*)d_in[4];
  const float* wo = (const float*)d_in[5];
  const float* w1 = (const float*)d_in[6];
  const float* w2 = (const float*)d_in[7];
  const float* w3 = (const float*)d_in[8];
  const float* ga = (const float*)d_in[9];
  const float* gf = (const float*)d_in[10];
  float* out = (float*)d_out;

  char* ws = (char*)d_ws;
  dim3 blk(256);
  dim3 gA(8, Hq, Bq);
  dim3 blkA(512);
  dim3 blk8(512);

  const size_t SZ_H   = (size_t)Mq * Dq * 2;
  const size_t SZ_QKV = (size_t)Mq * 3 * Dq * 2;
  const size_t SZ_W4  = (size_t)Dq * Dq * 2;
  const size_t SZ_W13 = (size_t)FFq * Dq * 2;
  const size_t ACT    = SZ_H + SZ_QKV;
  const size_t WTS    = 3 * SZ_W4 + SZ_W4 + 3 * SZ_W13;
  const size_t NEED   = ACT + WTS;

  if (ws_size >= NEED) {
    // ---- PATH A: bf16 weights. gemm3 for QKV/wo/w2 (quantization-friendly),
    //      gemm8 v2 (4-phase) for w1/w3 (256 blocks = exact 1/CU fit).
    bf16* h    = (bf16*)(ws);
    bf16* qkv  = (bf16*)(ws + SZ_H);
    bf16* ob   = h;
    bf16* h2   = qkv;
    bf16* ub   = (bf16*)(ws + SZ_H + SZ_H);
    char* wb   = ws + ACT;
    bf16* wqkv_b = (bf16*)(wb);
    bf16* wo_b   = (bf16*)(wb + 3 * SZ_W4);
    bf16* w1_b   = (bf16*)(wb + 4 * SZ_W4);
    bf16* w3_b   = (bf16*)(wb + 4 * SZ_W4 + SZ_W13);
    bf16* w2_b   = (bf16*)(wb + 4 * SZ_W4 + 2 * SZ_W13);

    const long nW4 = (long)Dq * Dq, nW13 = (long)FFq * Dq;
    conv_k<<<1024, blk, 0, stream>>>(wq, wqkv_b, nW4);
    conv_k<<<1024, blk, 0, stream>>>(wk, wqkv_b + nW4, nW4);
    conv_k<<<1024, blk, 0, stream>>>(wv, wqkv_b + 2 * nW4, nW4);
    conv_k<<<1024, blk, 0, stream>>>(wo, wo_b, nW4);
    conv_k<<<2048, blk, 0, stream>>>(w1, w1_b, nW13);
    conv_k<<<2048, blk, 0, stream>>>(w3, w3_b, nW13);
    conv_k<<<2048, blk, 0, stream>>>(w2, w2_b, nW13);

    rmsnorm_k<<<Mq, blk, 0, stream>>>(x, ga, h);
    gemm3<0><<<dim3(48, 32), blk, 0, stream>>>(h, wqkv_b, nullptr, qkv, 6144, Dq, Dq, 0);
    rope_k<<<(Bq * Sq * Hq * 64) / 256, blk, 0, stream>>>(qkv, qkv + Dq, 3 * Dq);
    attn_k<<<gA, blkA, 0, stream>>>(qkv, qkv + Dq, qkv + 2 * Dq, ob, 3 * Dq);
    gemm3<1><<<dim3(16, 32), blk, 0, stream>>>(ob, wo_b, x, out, Dq, Dq, Dq, 0);
    rmsnorm_k<<<Mq, blk, 0, stream>>>(out, gf, h2);
    for (int hh = 0; hh < 2; ++hh) {
      bf16* w1h = w1_b + (size_t)hh * 4096 * Dq;
      bf16* w3h = w3_b + (size_t)hh * 4096 * Dq;
      gemm8<0><<<dim3(16, 16), blk8, 0, stream>>>(h2, w1h, nullptr, ub, 4096, Dq, Dq, 0);
      gemm8<2><<<dim3(16, 16), blk8, 0, stream>>>(h2, w3h, ub, ub, 4096, Dq, Dq, 0);
      gemm3<1><<<dim3(16, 32), blk, 0, stream>>>(ub, w2_b, out, out, Dq, 4096, FFq,
                                                 (long long)hh * 4096);
    }
  } else {
    // ---- PATH B: f32-weight fallback ----
    const size_t MS = (size_t)Mq * Dq * 2;
    bf16* h  = (bf16*)(ws);
    bf16* kb = (bf16*)(ws + MS);
    bf16* vb = (bf16*)(ws + 2 * MS);
    bf16* qb = (bf16*)(ws + 3 * MS);
    bf16* ub = (bf16*)(ws);
    bf16* ob = h;
    bf16* h2 = qb;

    dim3 gD(Dq / 128, Mq / 128);
    dim3 gU(32, Mq / 128);

    rmsnorm_k<<<Mq, blk, 0, stream>>>(x, ga, h);
    gemm2<0><<<gD, blk, 0, stream>>>(h, wq, nullptr, qb, Dq, Dq, Dq, 0);
    gemm2<0><<<gD, blk, 0, stream>>>(h, wk, nullptr, kb, Dq, Dq, Dq, 0);
    gemm2<0><<<gD, blk, 0, stream>>>(h, wv, nullptr, vb, Dq, Dq, Dq, 0);
    rope_k<<<(Bq * Sq * Hq * 64) / 256, blk, 0, stream>>>(qb, kb, Dq);
    attn_k<<<gA, blkA, 0, stream>>>(qb, kb, vb, ob, Dq);
    gemm2<1><<<gD, blk, 0, stream>>>(ob, wo, x, out, Dq, Dq, Dq, 0);
    rmsnorm_k<<<Mq, blk, 0, stream>>>(out, gf, h2);
    for (int hh = 0; hh < 2; ++hh) {
      const long long bo13 = (long long)hh * 4096 * 2048;
      gemm2<0><<<gU, blk, 0, stream>>>(h2, w1, nullptr, ub, 4096, Dq, Dq, bo13);
      gemm2<2><<<gU, blk, 0, stream>>>(h2, w3, ub, ub, 4096, Dq, Dq, bo13);
      gemm2<1><<<gD, blk, 0, stream>>>(ub, w2, out, out, Dq, 4096, FFq,
                                       (long long)hh * 4096);
    }
  }
}

// Round 10
// 883.349 us; speedup vs baseline: 2.5427x; 1.0097x over previous
//
#include <hip/hip_runtime.h>
#include <hip/hip_bf16.h>
#include <math.h>

typedef __hip_bfloat16 bf16;
typedef short short8 __attribute__((ext_vector_type(8)));
typedef float f32x4 __attribute__((ext_vector_type(4)));

#define Bq 2
#define Sq 2048
#define Dq 2048
#define Hq 16
#define DHq 128
#define FFq 8192
#define Mq 4096  // Bq*Sq

__device__ __forceinline__ float b2f(bf16 x) { return __bfloat162float(x); }
__device__ __forceinline__ bf16 f2b(float x) { return __float2bfloat16(x); }

__device__ __forceinline__ void gload16(const void* g, void* lds_base) {
  __builtin_amdgcn_global_load_lds(
      (const __attribute__((address_space(1))) void*)g,
      (__attribute__((address_space(3))) void*)lds_base,
      16, 0, 0);
}

__global__ __launch_bounds__(256)
void conv_k(const float* __restrict__ src, bf16* __restrict__ dst, long n) {
  const long stride = (long)gridDim.x * 256 * 8;
  for (long i = ((long)blockIdx.x * 256 + threadIdx.x) * 8; i < n; i += stride) {
    f32x4 a = *(const f32x4*)(src + i);
    f32x4 b = *(const f32x4*)(src + i + 4);
    union { short8 s; bf16 h[8]; } u;
#pragma unroll
    for (int j = 0; j < 4; ++j) { u.h[j] = f2b(a[j]); u.h[j + 4] = f2b(b[j]); }
    *(short8*)(dst + i) = u.s;
  }
}

// ---------------------------------------------------------------------------
// Shared scheduling macros
// ---------------------------------------------------------------------------
#define BAR8() { asm volatile("" ::: "memory"); __builtin_amdgcn_s_barrier(); asm volatile("" ::: "memory"); }
#define VMC4() { asm volatile("s_waitcnt vmcnt(4)" ::: "memory"); __builtin_amdgcn_sched_barrier(0); }
#define VMC2() { asm volatile("s_waitcnt vmcnt(2)" ::: "memory"); __builtin_amdgcn_sched_barrier(0); }

// one STG8 line = 2 gload16/thread, covers 128 rows x 64 cols
#define STG8(Gp, ldX, rowOff, kt, XsBuf)                                        \
  gload16(Gp + (size_t)((rowOff) + w8 + lr) * (size_t)(ldX) + (kt) + sCol,      \
          &XsBuf[(rowOff) + w8][0]);                                            \
  gload16(Gp + (size_t)((rowOff) + 64 + w8 + lr) * (size_t)(ldX) + (kt) + sCol, \
          &XsBuf[(rowOff) + 64 + w8][0]);

// ---------------------------------------------------------------------------
// gemm8 v2 (round-9 verified): 256x256, BK=64, 8 waves, 4 phases / 2 K-tiles.
// Used for w1/w3 (grid 256 = exact 1/CU fit).
// ---------------------------------------------------------------------------
#define RD_A8(dst, XsBuf, mb)                                                   \
  _Pragma("unroll") for (int mi = 0; mi < 4; ++mi) {                            \
    const int ra = wmBase + ((mb) + mi) * 16 + c;                               \
    _Pragma("unroll") for (int kk = 0; kk < 2; ++kk)                            \
      dst[mi][kk] = *(const short8*)&XsBuf[ra][(((kk * 4 + g) ^ (ra & 7)) << 3)]; \
  }

#define RD_B8(dst, XsBuf, nb_)                                                  \
  _Pragma("unroll") for (int ni = 0; ni < 2; ++ni) {                            \
    const int rb = wnBase + ((nb_) + ni) * 16 + c;                              \
    _Pragma("unroll") for (int kk = 0; kk < 2; ++kk)                            \
      dst[ni][kk] = *(const short8*)&XsBuf[rb][(((kk * 4 + g) ^ (rb & 7)) << 3)]; \
  }

#define MFMA_Q8(afv, bfv, mb, nb_)                                              \
  __builtin_amdgcn_s_setprio(1);                                                \
  _Pragma("unroll") for (int mi = 0; mi < 4; ++mi)                              \
    _Pragma("unroll") for (int ni = 0; ni < 2; ++ni)                            \
      _Pragma("unroll") for (int kk = 0; kk < 2; ++kk)                          \
        acc[(mb) + mi][(nb_) + ni] = __builtin_amdgcn_mfma_f32_16x16x32_bf16(   \
            afv[mi][kk], bfv[ni][kk], acc[(mb) + mi][(nb_) + ni], 0, 0, 0);     \
  __builtin_amdgcn_s_setprio(0);

template <int EPI>
__global__ __launch_bounds__(512, 2)
void gemm8(const bf16* __restrict__ A, const bf16* __restrict__ Bt,
           const void* __restrict__ R, void* __restrict__ C,
           int N, int K, int ldb, long long boff) {
  __shared__ __align__(16) bf16 As[2][256][64];
  __shared__ __align__(16) bf16 Bs[2][256][64];
  const int tid = threadIdx.x;
  const int w = tid >> 6, l = tid & 63;
  const int g = l >> 4, c = l & 15;
  const int w8 = w * 8, lr = l >> 3;
  const int sCol = (((l & 7) ^ lr) << 3);

  const int nwg = gridDim.x * gridDim.y;
  const int orig = blockIdx.x + blockIdx.y * gridDim.x;
  const int qq = nwg >> 3, rr8 = nwg & 7;
  const int xcd = orig & 7, idx8 = orig >> 3;
  const int wg = (xcd < rr8 ? xcd * (qq + 1) : rr8 * (qq + 1) + (xcd - rr8) * qq) + idx8;
  const int bm = (wg / gridDim.x) * 256;
  const int bn = (wg % gridDim.x) * 256;

  const int wmBase = (w >> 2) * 128;
  const int wnBase = (w & 3) * 64;

  const bf16* Ab = A + (size_t)bm * K;
  const bf16* Bb = Bt + (size_t)bn * ldb + (size_t)boff;

  f32x4 acc[8][4] = {};
  const int nt = K >> 6;

  STG8(Ab, K, 0, 0, As[0]); STG8(Ab, K, 128, 0, As[0]);
  STG8(Bb, ldb, 0, 0, Bs[0]); STG8(Bb, ldb, 128, 0, Bs[0]);
  STG8(Bb, ldb, 0, 64, Bs[1]); STG8(Bb, ldb, 128, 64, Bs[1]);
  VMC4(); BAR8();

  short8 af[4][2], af2[4][2], bf[2][2], bf2[2][2];
  for (int it = 0; it < (nt >> 1); ++it) {
    const int t = it * 2;
    const int kt1 = (t + 1) << 6;
    const int kt2 = (t + 2 < nt ? t + 2 : nt - 1) << 6;
    const int kt3 = (t + 3 < nt ? t + 3 : nt - 1) << 6;
    // P1 (tile t, buf0)
    RD_A8(af, As[0], 0); RD_B8(bf, Bs[0], 0); RD_B8(bf2, Bs[0], 2);
    STG8(Ab, K, 0, kt1, As[1]); STG8(Ab, K, 128, kt1, As[1]);
    BAR8();
    MFMA_Q8(af, bf, 0, 0); MFMA_Q8(af, bf2, 0, 2);
    BAR8();
    // P2
    RD_A8(af2, As[0], 4);
    STG8(Bb, ldb, 0, kt2, Bs[0]); STG8(Bb, ldb, 128, kt2, Bs[0]);
    BAR8();
    MFMA_Q8(af2, bf, 4, 0); MFMA_Q8(af2, bf2, 4, 2);
    VMC4(); BAR8();
    // P3 (tile t+1, buf1)
    RD_A8(af, As[1], 0); RD_B8(bf, Bs[1], 0); RD_B8(bf2, Bs[1], 2);
    STG8(Ab, K, 0, kt2, As[0]); STG8(Ab, K, 128, kt2, As[0]);
    BAR8();
    MFMA_Q8(af, bf, 0, 0); MFMA_Q8(af, bf2, 0, 2);
    BAR8();
    // P4
    RD_A8(af2, As[1], 4);
    STG8(Bb, ldb, 0, kt3, Bs[1]); STG8(Bb, ldb, 128, kt3, Bs[1]);
    BAR8();
    MFMA_Q8(af2, bf, 4, 0); MFMA_Q8(af2, bf2, 4, 2);
    VMC4(); BAR8();
  }

  const int rbase = bm + wmBase + g * 4;
  const int cbase = bn + wnBase + c;
#pragma unroll
  for (int m = 0; m < 8; ++m)
#pragma unroll
    for (int r = 0; r < 4; ++r) {
      const int row = rbase + m * 16 + r;
#pragma unroll
      for (int n = 0; n < 4; ++n) {
        const size_t idx = (size_t)row * N + (cbase + n * 16);
        float vacc = acc[m][n][r];
        if (EPI == 1) {
          ((float*)C)[idx] = vacc + ((const float*)R)[idx];
        } else if (EPI == 2) {
          const float u = b2f(((const bf16*)R)[idx]);
          ((bf16*)C)[idx] = f2b((u / (1.f + expf(-u))) * vacc);
        } else {
          ((bf16*)C)[idx] = f2b(vacc);
        }
      }
    }
}

// ---------------------------------------------------------------------------
// gemm12: 128x256 tile, BK=64, 8 waves (2Mx4N, wave=64x64). 4 phases per
// 2 K-tiles, counted vmcnt(2). Grid fits exactly: QKV 768=3 rounds,
// wo/w2 256=1 round. LDS 96 KiB.
// Schedule (buf0=even tile t, buf1=odd t+1):
//  P1: RD af=A(t) all, bfa01=B(t) n0-1 ; STG t+1.B->Bs[1] ; MFMA af x bfa01
//  P2: RD bfa23                        ; STG t+2.A->As[0] ; MFMA af x bfa23 ; VMC2
//  P3: RD af2=A(t+1), bfb01           ; STG t+2.B->Bs[0] ; MFMA af2 x bfb01
//  P4: RD bfb23                        ; STG t+3.A->As[1] ; MFMA af2 x bfb23 ; VMC2
// WAR: each buffer's reads are consumed (drained) in the phase before any
// stage targets it (A(t) consumed P1, staged P2; B(t) consumed P2, staged P3;
// A(t+1) consumed P3, staged P4; B(t+1) consumed P4, staged next-P1).
// RAW: VMC2 @P2-close drains t+1.{A,B}; @P4-close drains t+2.{A,B}.
// Outstanding loads/wave: max 8, floor 2 (never 0).
// ---------------------------------------------------------------------------
#define RD_A12(dst, XsBuf)                                                      \
  _Pragma("unroll") for (int mi = 0; mi < 4; ++mi) {                            \
    const int ra = wmB12 + mi * 16 + c;                                         \
    _Pragma("unroll") for (int kk = 0; kk < 2; ++kk)                            \
      dst[mi][kk] = *(const short8*)&XsBuf[ra][(((kk * 4 + g) ^ (ra & 7)) << 3)]; \
  }

#define RD_B12(dst, XsBuf, nb_)                                                 \
  _Pragma("unroll") for (int ni = 0; ni < 2; ++ni) {                            \
    const int rb = wnB12 + ((nb_) + ni) * 16 + c;                               \
    _Pragma("unroll") for (int kk = 0; kk < 2; ++kk)                            \
      dst[ni][kk] = *(const short8*)&XsBuf[rb][(((kk * 4 + g) ^ (rb & 7)) << 3)]; \
  }

#define MFMA_H12(afv, bfv, nb_)                                                 \
  __builtin_amdgcn_s_setprio(1);                                                \
  _Pragma("unroll") for (int mi = 0; mi < 4; ++mi)                              \
    _Pragma("unroll") for (int ni = 0; ni < 2; ++ni)                            \
      _Pragma("unroll") for (int kk = 0; kk < 2; ++kk)                          \
        acc[mi][(nb_) + ni] = __builtin_amdgcn_mfma_f32_16x16x32_bf16(          \
            afv[mi][kk], bfv[ni][kk], acc[mi][(nb_) + ni], 0, 0, 0);            \
  __builtin_amdgcn_s_setprio(0);

template <int EPI>
__global__ __launch_bounds__(512, 2)
void gemm12(const bf16* __restrict__ A, const bf16* __restrict__ Bt,
            const void* __restrict__ R, void* __restrict__ C,
            int N, int K, int ldb, long long boff) {
  __shared__ __align__(16) bf16 As[2][128][64];
  __shared__ __align__(16) bf16 Bs[2][256][64];
  const int tid = threadIdx.x;
  const int w = tid >> 6, l = tid & 63;
  const int g = l >> 4, c = l & 15;
  const int w8 = w * 8, lr = l >> 3;
  const int sCol = (((l & 7) ^ lr) << 3);

  const int nwg = gridDim.x * gridDim.y;
  const int orig = blockIdx.x + blockIdx.y * gridDim.x;
  const int qq = nwg >> 3, rr8 = nwg & 7;
  const int xcd = orig & 7, idx8 = orig >> 3;
  const int wg = (xcd < rr8 ? xcd * (qq + 1) : rr8 * (qq + 1) + (xcd - rr8) * qq) + idx8;
  const int bm = (wg / gridDim.x) * 128;
  const int bn = (wg % gridDim.x) * 256;

  const int wmB12 = (w >> 2) * 64;
  const int wnB12 = (w & 3) * 64;

  const bf16* Ab = A + (size_t)bm * K;
  const bf16* Bb = Bt + (size_t)bn * ldb + (size_t)boff;

  f32x4 acc[4][4] = {};
  const int nt = K >> 6;

  // prologue: t0.A, t0.B, t1.A ; drain t0, leave t1.A in flight
  STG8(Ab, K, 0, 0, As[0]);
  STG8(Bb, ldb, 0, 0, Bs[0]); STG8(Bb, ldb, 128, 0, Bs[0]);
  STG8(Ab, K, 0, 64, As[1]);
  VMC2(); BAR8();

  short8 af[4][2], af2[4][2], bfa[2][2], bfa2[2][2], bfb[2][2], bfb2[2][2];
  for (int it = 0; it < (nt >> 1); ++it) {
    const int t = it * 2;
    const int kt1 = (t + 1) << 6;
    const int kt2 = (t + 2 < nt ? t + 2 : nt - 1) << 6;
    const int kt3 = (t + 3 < nt ? t + 3 : nt - 1) << 6;
    // P1 (tile t, buf0)
    RD_A12(af, As[0]); RD_B12(bfa, Bs[0], 0);
    STG8(Bb, ldb, 0, kt1, Bs[1]); STG8(Bb, ldb, 128, kt1, Bs[1]);
    BAR8();
    MFMA_H12(af, bfa, 0);
    BAR8();
    // P2
    RD_B12(bfa2, Bs[0], 2);
    STG8(Ab, K, 0, kt2, As[0]);
    BAR8();
    MFMA_H12(af, bfa2, 2);
    VMC2(); BAR8();
    // P3 (tile t+1, buf1)
    RD_A12(af2, As[1]); RD_B12(bfb, Bs[1], 0);
    STG8(Bb, ldb, 0, kt2, Bs[0]); STG8(Bb, ldb, 128, kt2, Bs[0]);
    BAR8();
    MFMA_H12(af2, bfb, 0);
    BAR8();
    // P4
    RD_B12(bfb2, Bs[1], 2);
    STG8(Ab, K, 0, kt3, As[1]);
    BAR8();
    MFMA_H12(af2, bfb2, 2);
    VMC2(); BAR8();
  }

  // epilogue: wave tile 64x64; row = bm+wmB12+mi*16+g*4+r, col = bn+wnB12+ni*16+c
  const int rbase = bm + wmB12 + g * 4;
  const int cbase = bn + wnB12 + c;
#pragma unroll
  for (int m = 0; m < 4; ++m)
#pragma unroll
    for (int r = 0; r < 4; ++r) {
      const int row = rbase + m * 16 + r;
#pragma unroll
      for (int n = 0; n < 4; ++n) {
        const size_t idx = (size_t)row * N + (cbase + n * 16);
        float vacc = acc[m][n][r];
        if (EPI == 1) {
          ((float*)C)[idx] = vacc + ((const float*)R)[idx];
        } else if (EPI == 2) {
          const float u = b2f(((const bf16*)R)[idx]);
          ((bf16*)C)[idx] = f2b((u / (1.f + expf(-u))) * vacc);
        } else {
          ((bf16*)C)[idx] = f2b(vacc);
        }
      }
    }
}

// ---------------------------------------------------------------------------
// PATH B GEMM (f32 weights) - fallback only.
// ---------------------------------------------------------------------------
template <int EPI>
__global__ __launch_bounds__(256)
void gemm2(const bf16* __restrict__ A, const float* __restrict__ Bt,
           const void* __restrict__ R, void* __restrict__ C,
           int N, int K, int ldb, long long boff) {
  __shared__ __align__(16) bf16 As[128][64];
  __shared__ __align__(16) float Bsf[128][64];
  const int tid = threadIdx.x;
  const int w = tid >> 6;
  const int l = tid & 63;

  const int nwg = gridDim.x * gridDim.y;
  const int orig = blockIdx.x + blockIdx.y * gridDim.x;
  const int qq = nwg >> 3, rr8 = nwg & 7;
  const int xcd = orig & 7, idx8 = orig >> 3;
  const int wg = (xcd < rr8 ? xcd * (qq + 1) : rr8 * (qq + 1) + (xcd - rr8) * qq) + idx8;
  const int bm = (wg / gridDim.x) * 128;
  const int bn = (wg % gridDim.x) * 128;

  const int wr = (w >> 1) * 64;
  const int wc = (w & 1) * 64;
  f32x4 acc[4][4] = {};

  const bf16* Ab = A + (size_t)bm * K;
  const float* Bb = Bt + (size_t)bn * ldb + (size_t)boff;

  const int aSrcCol = (((l & 7) ^ (l >> 3)) << 3);
  const int bKey = (w * 4 + (l >> 4)) & 7;
  const int bSrcCol = (((l & 15) ^ bKey) << 2);

  for (int kt = 0; kt < K; kt += 64) {
    __syncthreads();
#pragma unroll
    for (int i = 0; i < 4; ++i)
      gload16(Ab + (size_t)(i * 32 + w * 8 + (l >> 3)) * K + kt + aSrcCol,
              &As[i * 32 + w * 8][0]);
#pragma unroll
    for (int i = 0; i < 8; ++i)
      gload16(Bb + (size_t)(i * 16 + w * 4 + (l >> 4)) * ldb + kt + bSrcCol,
              &Bsf[i * 16 + w * 4][0]);
    __syncthreads();

#pragma unroll
    for (int kk = 0; kk < 2; ++kk) {
      short8 af[4], bfv[4];
#pragma unroll
      for (int m = 0; m < 4; ++m) {
        const int ra = wr + m * 16 + (l & 15);
        const int pb = (kk * 4 + (l >> 4)) ^ (ra & 7);
        af[m] = *(const short8*)&As[ra][pb * 8];
      }
#pragma unroll
      for (int n = 0; n < 4; ++n) {
        const int rb = wc + n * 16 + (l & 15);
        const int b0 = kk * 8 + (l >> 4) * 2;
        const f32x4 x0 = *(const f32x4*)&Bsf[rb][(b0 ^ (rb & 7)) * 4];
        const f32x4 x1 = *(const f32x4*)&Bsf[rb][((b0 + 1) ^ (rb & 7)) * 4];
        union { short8 s; bf16 h[8]; } u;
#pragma unroll
        for (int j = 0; j < 4; ++j) { u.h[j] = f2b(x0[j]); u.h[j + 4] = f2b(x1[j]); }
        bfv[n] = u.s;
      }
#pragma unroll
      for (int m = 0; m < 4; ++m)
#pragma unroll
        for (int n = 0; n < 4; ++n)
          acc[m][n] = __builtin_amdgcn_mfma_f32_16x16x32_bf16(af[m], bfv[n], acc[m][n], 0, 0, 0);
    }
  }

  const int rbase = bm + wr + (l >> 4) * 4;
  const int cbase = bn + wc + (l & 15);
#pragma unroll
  for (int m = 0; m < 4; ++m)
#pragma unroll
    for (int r = 0; r < 4; ++r) {
      const int row = rbase + m * 16 + r;
#pragma unroll
      for (int n = 0; n < 4; ++n) {
        const size_t idx = (size_t)row * N + (cbase + n * 16);
        float vacc = acc[m][n][r];
        if (EPI == 1) {
          ((float*)C)[idx] = vacc + ((const float*)R)[idx];
        } else if (EPI == 2) {
          const float u = b2f(((const bf16*)R)[idx]);
          ((bf16*)C)[idx] = f2b((u / (1.f + expf(-u))) * vacc);
        } else {
          ((bf16*)C)[idx] = f2b(vacc);
        }
      }
    }
}

// ---------------------------------------------------------------------------
__global__ __launch_bounds__(256)
void rmsnorm_k(const float* __restrict__ xin, const float* __restrict__ g,
               bf16* __restrict__ out) {
  const int row = blockIdx.x;
  const int tid = threadIdx.x;
  const float* xp = xin + (size_t)row * Dq + tid * 8;
  f32x4 a = *(const f32x4*)xp, b = *(const f32x4*)(xp + 4);
  float xf[8];
#pragma unroll
  for (int j = 0; j < 4; ++j) { xf[j] = a[j]; xf[j + 4] = b[j]; }
  float ss = 0.f;
#pragma unroll
  for (int j = 0; j < 8; ++j) ss += xf[j] * xf[j];
#pragma unroll
  for (int off = 32; off > 0; off >>= 1) ss += __shfl_down(ss, off);
  __shared__ float red[4];
  if ((tid & 63) == 0) red[tid >> 6] = ss;
  __syncthreads();
  const float rms = rsqrtf((red[0] + red[1] + red[2] + red[3]) * (1.f / (float)Dq) + 1e-6f);
  const float* gp = g + tid * 8;
  f32x4 ga = *(const f32x4*)gp, gb = *(const f32x4*)(gp + 4);
  union { short8 s; bf16 h[8]; } uo;
#pragma unroll
  for (int j = 0; j < 4; ++j) {
    uo.h[j] = f2b(xf[j] * rms * ga[j]);
    uo.h[j + 4] = f2b(xf[j + 4] * rms * gb[j]);
  }
  *(short8*)(out + (size_t)row * Dq + tid * 8) = uo.s;
}

// ---------------------------------------------------------------------------
__global__ __launch_bounds__(256)
void rope_k(bf16* __restrict__ q, bf16* __restrict__ k, int ld) {
  const size_t idx = (size_t)blockIdx.x * 256 + threadIdx.x;
  const int i = (int)(idx & 63);
  const int h = (int)((idx >> 6) & 15);
  const int s = (int)((idx >> 10) & 2047);
  const int b = (int)(idx >> 21);
  const float f = (float)s * powf(10000.f, -(float)i * (1.f / 64.f));
  float sn, cs;
  sincosf(f, &sn, &cs);
  const size_t base = ((size_t)(b * Sq + s)) * ld + h * DHq + i;
  const float qa = b2f(q[base]), qb_ = b2f(q[base + 64]);
  q[base] = f2b(qa * cs - qb_ * sn);
  q[base + 64] = f2b(qb_ * cs + qa * sn);
  const float ka = b2f(k[base]), kb_ = b2f(k[base + 64]);
  k[base] = f2b(ka * cs - kb_ * sn);
  k[base + 64] = f2b(kb_ * cs + ka * sn);
}

// ---------------------------------------------------------------------------
// Causal flash attention v3 (round-7 verified).
// ---------------------------------------------------------------------------
__device__ __forceinline__ int swz8(int row) { return (((row >> 3) ^ row) & 7) << 3; }

#define ATTN_COMPUTE(AQ, QB, QROW, M_, L_, OACC, KV0, CUR)                        \
  {                                                                               \
    f32x4 sc[4] = {};                                                             \
    __builtin_amdgcn_s_setprio(1);                                                \
    _Pragma("unroll") for (int n = 0; n < 4; ++n) {                               \
      const int krow = n * 16 + c;                                                \
      const int sw = swz8(krow);                                                  \
      _Pragma("unroll") for (int kk = 0; kk < 4; ++kk) {                          \
        short8 ak = *(const short8*)&Ks[CUR][krow][(kk * 32 + g * 8) ^ sw];       \
        sc[n] = __builtin_amdgcn_mfma_f32_16x16x32_bf16(ak, AQ[kk], sc[n], 0, 0, 0); \
      }                                                                           \
    }                                                                             \
    __builtin_amdgcn_s_setprio(0);                                                \
    float p[4][4];                                                                \
    float tmax = -3.0e38f;                                                        \
    if ((KV0) + 63 <= (QB)) {                                                     \
      _Pragma("unroll") for (int n = 0; n < 4; ++n)                               \
        _Pragma("unroll") for (int r = 0; r < 4; ++r) {                           \
          const float val = sc[n][r] * SCALE;                                     \
          p[n][r] = val;                                                          \
          tmax = fmaxf(tmax, val);                                                \
        }                                                                         \
    } else {                                                                      \
      _Pragma("unroll") for (int n = 0; n < 4; ++n)                               \
        _Pragma("unroll") for (int r = 0; r < 4; ++r) {                           \
          const int kvg = (KV0) + n * 16 + g * 4 + r;                             \
          float val = sc[n][r] * SCALE;                                           \
          if (kvg > (QROW)) val = -3.0e38f;                                       \
          p[n][r] = val;                                                          \
          tmax = fmaxf(tmax, val);                                                \
        }                                                                         \
    }                                                                             \
    tmax = fmaxf(tmax, __shfl_xor(tmax, 16));                                     \
    tmax = fmaxf(tmax, __shfl_xor(tmax, 32));                                     \
    const bool grow = !__all(tmax <= M_);                                         \
    const float m_new = grow ? fmaxf(M_, tmax) : M_;                              \
    float tsum = 0.f;                                                             \
    _Pragma("unroll") for (int n = 0; n < 4; ++n)                                 \
      _Pragma("unroll") for (int r = 0; r < 4; ++r) {                             \
        const float pv = expf(p[n][r] - m_new);                                   \
        p[n][r] = pv;                                                             \
        tsum += pv;                                                               \
      }                                                                           \
    tsum += __shfl_xor(tsum, 16);                                                 \
    tsum += __shfl_xor(tsum, 32);                                                 \
    if (grow) {                                                                   \
      const float corr = expf(M_ - m_new);                                        \
      L_ = L_ * corr + tsum;                                                      \
      M_ = m_new;                                                                 \
      _Pragma("unroll") for (int dt = 0; dt < 8; ++dt) OACC[dt] *= corr;          \
    } else {                                                                      \
      L_ += tsum;                                                                 \
    }                                                                             \
    const int keyc = (c ^ (c >> 3)) & 7;                                          \
    _Pragma("unroll") for (int n = 0; n < 4; ++n) {                               \
      union { unsigned long long u; bf16 hh[4]; } pk;                             \
      _Pragma("unroll") for (int r = 0; r < 4; ++r) pk.hh[r] = f2b(p[n][r]);      \
      const int blk = (2 * n + (g >> 1)) ^ keyc;                                  \
      *(unsigned long long*)&Ps[w][c][blk * 8 + (g & 1) * 4] = pk.u;              \
    }                                                                             \
    short8 ap[2];                                                                 \
    _Pragma("unroll") for (int kk = 0; kk < 2; ++kk)                              \
      ap[kk] = *(const short8*)&Ps[w][c][(kk * 32 + g * 8) ^ (keyc << 3)];        \
    __builtin_amdgcn_s_setprio(1);                                                \
    _Pragma("unroll") for (int dt = 0; dt < 8; ++dt) {                            \
      const int vrow = dt * 16 + c;                                               \
      const int vsw = swz8(vrow);                                                 \
      _Pragma("unroll") for (int kk = 0; kk < 2; ++kk) {                          \
        short8 av = *(const short8*)&Vt[CUR][vrow][(kk * 32 + g * 8) ^ vsw];      \
        OACC[dt] = __builtin_amdgcn_mfma_f32_16x16x32_bf16(av, ap[kk], OACC[dt], 0, 0, 0); \
      }                                                                           \
    }                                                                             \
    __builtin_amdgcn_s_setprio(0);                                                \
  }

__global__ __launch_bounds__(512)
void attn_k(const bf16* __restrict__ q, const bf16* __restrict__ k,
            const bf16* __restrict__ v, bf16* __restrict__ o, int ld) {
  __shared__ __align__(16) bf16 Ks[2][64][128];
  __shared__ __align__(16) bf16 Vt[2][128][64];
  __shared__ __align__(16) bf16 Ps[8][16][64];
  const int tid = threadIdx.x;
  const int w = tid >> 6, l = tid & 63;
  const int g = l >> 4, c = l & 15;
  const int x = blockIdx.x;
  const int h = blockIdx.y;
  const int b = blockIdx.z;
  const size_t hoff = (size_t)h * DHq;
  const float SCALE = 0.08838834764831845f;

  const int q0h = (15 - x) * 128, q0l = x * 128;
  const int qbh = q0h + w * 16, qbl = q0l + w * 16;
  const int qrh = qbh + c, qrl = qbl + c;

  short8 aqh[4], aql[4];
  {
    const bf16* qph = q + (size_t)(b * Sq + qrh) * ld + hoff + g * 8;
    const bf16* qpl = q + (size_t)(b * Sq + qrl) * ld + hoff + g * 8;
#pragma unroll
    for (int kk = 0; kk < 4; ++kk) {
      aqh[kk] = *(const short8*)(qph + kk * 32);
      aql[kk] = *(const short8*)(qpl + kk * 32);
    }
  }

  float mh = -3.0e38f, lh = 0.f, ml = -3.0e38f, ll_ = 0.f;
  f32x4 oh[8] = {}, ol[8] = {};

  const int stRow = tid >> 4;
  const int stBlk = tid & 15;
  const int ntiles = (q0h >> 6) + 2;

  {
#pragma unroll
    for (int i = 0; i < 2; ++i) {
      const int kr = i * 32 + w * 4 + (l >> 4);
      const int key = (kr ^ (kr >> 3)) & 7;
      gload16(k + (size_t)(b * Sq + kr) * ld + hoff + ((c ^ key) << 3),
              &Ks[0][i * 32 + w * 4][0]);
    }
    const int c0 = stBlk * 8;
#pragma unroll
    for (int i = 0; i < 2; ++i) {
      const int vr = i * 32 + stRow;
      union { short8 s; bf16 hh[8]; } uv;
      uv.s = *(const short8*)(v + (size_t)(b * Sq + vr) * ld + hoff + c0);
#pragma unroll
      for (int j = 0; j < 8; ++j) Vt[0][c0 + j][vr ^ swz8(c0 + j)] = uv.hh[j];
    }
  }
  __syncthreads();

  for (int t = 0; t < ntiles; ++t) {
    const int cur = t & 1, nxt = cur ^ 1;
    const int kv0 = t * 64;
    const bool pf = (t + 1 < ntiles);
    short8 vpa, vpb;
    if (pf) {
      const int kvn = kv0 + 64;
#pragma unroll
      for (int i = 0; i < 2; ++i) {
        const int kr = i * 32 + w * 4 + (l >> 4);
        const int key = (kr ^ (kr >> 3)) & 7;
        gload16(k + (size_t)(b * Sq + kvn + kr) * ld + hoff + ((c ^ key) << 3),
                &Ks[nxt][i * 32 + w * 4][0]);
      }
      vpa = *(const short8*)(v + (size_t)(b * Sq + kvn + stRow) * ld + hoff + stBlk * 8);
      vpb = *(const short8*)(v + (size_t)(b * Sq + kvn + 32 + stRow) * ld + hoff + stBlk * 8);
    }

    if (kv0 <= qbh + 15) ATTN_COMPUTE(aqh, qbh, qrh, mh, lh, oh, kv0, cur);

    if (pf) {
      const int c0 = stBlk * 8;
      union { short8 s; bf16 hh[8]; } uv;
      uv.s = vpa;
#pragma unroll
      for (int j = 0; j < 8; ++j) Vt[nxt][c0 + j][stRow ^ swz8(c0 + j)] = uv.hh[j];
      uv.s = vpb;
#pragma unroll
      for (int j = 0; j < 8; ++j) Vt[nxt][c0 + j][(32 + stRow) ^ swz8(c0 + j)] = uv.hh[j];
    }

    if (kv0 <= qbl + 15) ATTN_COMPUTE(aql, qbl, qrl, ml, ll_, ol, kv0, cur);

    __syncthreads();
  }

  {
    const float inv = 1.f / lh;
    bf16* op = o + (size_t)(b * Sq + qrh) * Dq + hoff + g * 4;
#pragma unroll
    for (int dt = 0; dt < 8; ++dt) {
      union { unsigned long long u; bf16 hh[4]; } pk;
#pragma unroll
      for (int r = 0; r < 4; ++r) pk.hh[r] = f2b(oh[dt][r] * inv);
      *(unsigned long long*)(op + dt * 16) = pk.u;
    }
  }
  {
    const float inv = 1.f / ll_;
    bf16* op = o + (size_t)(b * Sq + qrl) * Dq + hoff + g * 4;
#pragma unroll
    for (int dt = 0; dt < 8; ++dt) {
      union { unsigned long long u; bf16 hh[4]; } pk;
#pragma unroll
      for (int r = 0; r < 4; ++r) pk.hh[r] = f2b(ol[dt][r] * inv);
      *(unsigned long long*)(op + dt * 16) = pk.u;
    }
  }
}

// ---------------------------------------------------------------------------
extern "C" void kernel_launch(void* const* d_in, const int* in_sizes, int n_in,
                              void* d_out, int out_size, void* d_ws, size_t ws_size,
                              hipStream_t stream) {
  (void)in_sizes; (void)n_in; (void)out_size;
  const float* x  = (const float*)d_in[0];
  const float* wq = (const float*)d_in[2];
  const float* wk = (const float*)d_in[3];
  const float* wv = (const float*)d_in[4];
  const float* wo = (const float*)d_in[5];
  const float* w1 = (const float*)d_in[6];
  const float* w2 = (const float*)d_in[7];
  const float* w3 = (const float*)d_in[8];
  const float* ga = (const float*)d_in[9];
  const float* gf = (const float*)d_in[10];
  float* out = (float*)d_out;

  char* ws = (char*)d_ws;
  dim3 blk(256);
  dim3 gA(8, Hq, Bq);
  dim3 blkA(512);
  dim3 blk8(512);

  const size_t SZ_H   = (size_t)Mq * Dq * 2;
  const size_t SZ_QKV = (size_t)Mq * 3 * Dq * 2;
  const size_t SZ_W4  = (size_t)Dq * Dq * 2;
  const size_t SZ_W13 = (size_t)FFq * Dq * 2;
  const size_t ACT    = SZ_H + SZ_QKV;
  const size_t WTS    = 3 * SZ_W4 + SZ_W4 + 3 * SZ_W13;
  const size_t NEED   = ACT + WTS;

  if (ws_size >= NEED) {
    // ---- PATH A: bf16 weights. gemm12 (128x256, exact grid fit) for
    //      QKV(768=3 rounds)/wo(256)/w2(256); gemm8 v2 (256x256) for w1/w3.
    bf16* h    = (bf16*)(ws);
    bf16* qkv  = (bf16*)(ws + SZ_H);
    bf16* ob   = h;
    bf16* h2   = qkv;
    bf16* ub   = (bf16*)(ws + SZ_H + SZ_H);
    char* wb   = ws + ACT;
    bf16* wqkv_b = (bf16*)(wb);
    bf16* wo_b   = (bf16*)(wb + 3 * SZ_W4);
    bf16* w1_b   = (bf16*)(wb + 4 * SZ_W4);
    bf16* w3_b   = (bf16*)(wb + 4 * SZ_W4 + SZ_W13);
    bf16* w2_b   = (bf16*)(wb + 4 * SZ_W4 + 2 * SZ_W13);

    const long nW4 = (long)Dq * Dq, nW13 = (long)FFq * Dq;
    conv_k<<<1024, blk, 0, stream>>>(wq, wqkv_b, nW4);
    conv_k<<<1024, blk, 0, stream>>>(wk, wqkv_b + nW4, nW4);
    conv_k<<<1024, blk, 0, stream>>>(wv, wqkv_b + 2 * nW4, nW4);
    conv_k<<<1024, blk, 0, stream>>>(wo, wo_b, nW4);
    conv_k<<<2048, blk, 0, stream>>>(w1, w1_b, nW13);
    conv_k<<<2048, blk, 0, stream>>>(w3, w3_b, nW13);
    conv_k<<<2048, blk, 0, stream>>>(w2, w2_b, nW13);

    rmsnorm_k<<<Mq, blk, 0, stream>>>(x, ga, h);
    gemm12<0><<<dim3(24, 32), blk8, 0, stream>>>(h, wqkv_b, nullptr, qkv, 6144, Dq, Dq, 0);
    rope_k<<<(Bq * Sq * Hq * 64) / 256, blk, 0, stream>>>(qkv, qkv + Dq, 3 * Dq);
    attn_k<<<gA, blkA, 0, stream>>>(qkv, qkv + Dq, qkv + 2 * Dq, ob, 3 * Dq);
    gemm12<1><<<dim3(8, 32), blk8, 0, stream>>>(ob, wo_b, x, out, Dq, Dq, Dq, 0);
    rmsnorm_k<<<Mq, blk, 0, stream>>>(out, gf, h2);
    for (int hh = 0; hh < 2; ++hh) {
      bf16* w1h = w1_b + (size_t)hh * 4096 * Dq;
      bf16* w3h = w3_b + (size_t)hh * 4096 * Dq;
      gemm8<0><<<dim3(16, 16), blk8, 0, stream>>>(h2, w1h, nullptr, ub, 4096, Dq, Dq, 0);
      gemm8<2><<<dim3(16, 16), blk8, 0, stream>>>(h2, w3h, ub, ub, 4096, Dq, Dq, 0);
      gemm12<1><<<dim3(8, 32), blk8, 0, stream>>>(ub, w2_b, out, out, Dq, 4096, FFq,
                                                  (long long)hh * 4096);
    }
  } else {
    // ---- PATH B: f32-weight fallback ----
    const size_t MS = (size_t)Mq * Dq * 2;
    bf16* h  = (bf16*)(ws);
    bf16* kb = (bf16*)(ws + MS);
    bf16* vb = (bf16*)(ws + 2 * MS);
    bf16* qb = (bf16*)(ws + 3 * MS);
    bf16* ub = (bf16*)(ws);
    bf16* ob = h;
    bf16* h2 = qb;

    dim3 gD(Dq / 128, Mq / 128);
    dim3 gU(32, Mq / 128);

    rmsnorm_k<<<Mq, blk, 0, stream>>>(x, ga, h);
    gemm2<0><<<gD, blk, 0, stream>>>(h, wq, nullptr, qb, Dq, Dq, Dq, 0);
    gemm2<0><<<gD, blk, 0, stream>>>(h, wk, nullptr, kb, Dq, Dq, Dq, 0);
    gemm2<0><<<gD, blk, 0, stream>>>(h, wv, nullptr, vb, Dq, Dq, Dq, 0);
    rope_k<<<(Bq * Sq * Hq * 64) / 256, blk, 0, stream>>>(qb, kb, Dq);
    attn_k<<<gA, blkA, 0, stream>>>(qb, kb, vb, ob, Dq);
    gemm2<1><<<gD, blk, 0, stream>>>(ob, wo, x, out, Dq, Dq, Dq, 0);
    rmsnorm_k<<<Mq, blk, 0, stream>>>(out, gf, h2);
    for (int hh = 0; hh < 2; ++hh) {
      const long long bo13 = (long long)hh * 4096 * 2048;
      gemm2<0><<<gU, blk, 0, stream>>>(h2, w1, nullptr, ub, 4096, Dq, Dq, bo13);
      gemm2<2><<<gU, blk, 0, stream>>>(h2, w3, ub, ub, 4096, Dq, Dq, bo13);
      gemm2<1><<<gD, blk, 0, stream>>>(ub, w2, out, out, Dq, 4096, FFq,
                                       (long long)hh * 4096);
    }
  }
}

// Round 11
// 832.233 us; speedup vs baseline: 2.6989x; 1.0614x over previous
//
#include <hip/hip_runtime.h>
#include <hip/hip_bf16.h>
#include <math.h>

typedef __hip_bfloat16 bf16;
typedef short short8 __attribute__((ext_vector_type(8)));
typedef float f32x4 __attribute__((ext_vector_type(4)));

#define Bq 2
#define Sq 2048
#define Dq 2048
#define Hq 16
#define DHq 128
#define FFq 8192
#define Mq 4096  // Bq*Sq

__device__ __forceinline__ float b2f(bf16 x) { return __bfloat162float(x); }
__device__ __forceinline__ bf16 f2b(float x) { return __float2bfloat16(x); }

__device__ __forceinline__ void gload16(const void* g, void* lds_base) {
  __builtin_amdgcn_global_load_lds(
      (const __attribute__((address_space(1))) void*)g,
      (__attribute__((address_space(3))) void*)lds_base,
      16, 0, 0);
}

__global__ __launch_bounds__(256)
void conv_k(const float* __restrict__ src, bf16* __restrict__ dst, long n) {
  const long stride = (long)gridDim.x * 256 * 8;
  for (long i = ((long)blockIdx.x * 256 + threadIdx.x) * 8; i < n; i += stride) {
    f32x4 a = *(const f32x4*)(src + i);
    f32x4 b = *(const f32x4*)(src + i + 4);
    union { short8 s; bf16 h[8]; } u;
#pragma unroll
    for (int j = 0; j < 4; ++j) { u.h[j] = f2b(a[j]); u.h[j + 4] = f2b(b[j]); }
    *(short8*)(dst + i) = u.s;
  }
}

// ---------------------------------------------------------------------------
// Scheduling macros. Phase = {RD; STG; MFMA; [vmcnt]; BAR}. Correctness of
// the single-barrier phase: every ds_read is consumed by an MFMA in the same
// phase (compiler's lgkmcnt waits drain them before the last MFMA); the
// phase-end barrier then orders completed reads vs the next phase's stages;
// every stage targets a region whose last read completed >=1 phase earlier.
// ---------------------------------------------------------------------------
#define BAR8() { asm volatile("" ::: "memory"); __builtin_amdgcn_s_barrier(); asm volatile("" ::: "memory"); }
#define VMC4() { asm volatile("s_waitcnt vmcnt(4)" ::: "memory"); __builtin_amdgcn_sched_barrier(0); }
#define VMC2() { asm volatile("s_waitcnt vmcnt(2)" ::: "memory"); __builtin_amdgcn_sched_barrier(0); }

// one STG8 line = 2 gload16/thread, covers 128 rows x 64 cols
#define STG8(Gp, ldX, rowOff, kt, XsBuf)                                        \
  gload16(Gp + (size_t)((rowOff) + w8 + lr) * (size_t)(ldX) + (kt) + sCol,      \
          &XsBuf[(rowOff) + w8][0]);                                            \
  gload16(Gp + (size_t)((rowOff) + 64 + w8 + lr) * (size_t)(ldX) + (kt) + sCol, \
          &XsBuf[(rowOff) + 64 + w8][0]);

// ---------------------------------------------------------------------------
// gemm8: 256x256, BK=64, 8 waves, 4 single-barrier phases / 2 K-tiles.
// Used for w1/w3 full (512 blocks = 2 exact rounds).
// ---------------------------------------------------------------------------
#define RD_A8(dst, XsBuf, mb)                                                   \
  _Pragma("unroll") for (int mi = 0; mi < 4; ++mi) {                            \
    const int ra = wmBase + ((mb) + mi) * 16 + c;                               \
    _Pragma("unroll") for (int kk = 0; kk < 2; ++kk)                            \
      dst[mi][kk] = *(const short8*)&XsBuf[ra][(((kk * 4 + g) ^ (ra & 7)) << 3)]; \
  }

#define RD_B8(dst, XsBuf, nb_)                                                  \
  _Pragma("unroll") for (int ni = 0; ni < 2; ++ni) {                            \
    const int rb = wnBase + ((nb_) + ni) * 16 + c;                              \
    _Pragma("unroll") for (int kk = 0; kk < 2; ++kk)                            \
      dst[ni][kk] = *(const short8*)&XsBuf[rb][(((kk * 4 + g) ^ (rb & 7)) << 3)]; \
  }

#define MFMA_Q8(afv, bfv, mb, nb_)                                              \
  __builtin_amdgcn_s_setprio(1);                                                \
  _Pragma("unroll") for (int mi = 0; mi < 4; ++mi)                              \
    _Pragma("unroll") for (int ni = 0; ni < 2; ++ni)                            \
      _Pragma("unroll") for (int kk = 0; kk < 2; ++kk)                          \
        acc[(mb) + mi][(nb_) + ni] = __builtin_amdgcn_mfma_f32_16x16x32_bf16(   \
            afv[mi][kk], bfv[ni][kk], acc[(mb) + mi][(nb_) + ni], 0, 0, 0);     \
  __builtin_amdgcn_s_setprio(0);

template <int EPI>
__global__ __launch_bounds__(512, 2)
void gemm8(const bf16* __restrict__ A, const bf16* __restrict__ Bt,
           const void* __restrict__ R, void* __restrict__ C,
           int N, int K, int ldb, long long boff) {
  __shared__ __align__(16) bf16 As[2][256][64];
  __shared__ __align__(16) bf16 Bs[2][256][64];
  const int tid = threadIdx.x;
  const int w = tid >> 6, l = tid & 63;
  const int g = l >> 4, c = l & 15;
  const int w8 = w * 8, lr = l >> 3;
  const int sCol = (((l & 7) ^ lr) << 3);

  const int nwg = gridDim.x * gridDim.y;
  const int orig = blockIdx.x + blockIdx.y * gridDim.x;
  const int qq = nwg >> 3, rr8 = nwg & 7;
  const int xcd = orig & 7, idx8 = orig >> 3;
  const int wg = (xcd < rr8 ? xcd * (qq + 1) : rr8 * (qq + 1) + (xcd - rr8) * qq) + idx8;
  const int bm = (wg / gridDim.x) * 256;
  const int bn = (wg % gridDim.x) * 256;

  const int wmBase = (w >> 2) * 128;
  const int wnBase = (w & 3) * 64;

  const bf16* Ab = A + (size_t)bm * K;
  const bf16* Bb = Bt + (size_t)bn * ldb + (size_t)boff;

  f32x4 acc[8][4] = {};
  const int nt = K >> 6;

  STG8(Ab, K, 0, 0, As[0]); STG8(Ab, K, 128, 0, As[0]);
  STG8(Bb, ldb, 0, 0, Bs[0]); STG8(Bb, ldb, 128, 0, Bs[0]);
  STG8(Bb, ldb, 0, 64, Bs[1]); STG8(Bb, ldb, 128, 64, Bs[1]);
  VMC4(); BAR8();

  short8 af[4][2], af2[4][2], bf[2][2], bf2[2][2];
  for (int it = 0; it < (nt >> 1); ++it) {
    const int t = it * 2;
    const int kt1 = (t + 1) << 6;
    const int kt2 = (t + 2 < nt ? t + 2 : nt - 1) << 6;
    const int kt3 = (t + 3 < nt ? t + 3 : nt - 1) << 6;
    // P1 (tile t, buf0)
    RD_A8(af, As[0], 0); RD_B8(bf, Bs[0], 0); RD_B8(bf2, Bs[0], 2);
    STG8(Ab, K, 0, kt1, As[1]); STG8(Ab, K, 128, kt1, As[1]);
    MFMA_Q8(af, bf, 0, 0); MFMA_Q8(af, bf2, 0, 2);
    BAR8();
    // P2
    RD_A8(af2, As[0], 4);
    STG8(Bb, ldb, 0, kt2, Bs[0]); STG8(Bb, ldb, 128, kt2, Bs[0]);
    MFMA_Q8(af2, bf, 4, 0); MFMA_Q8(af2, bf2, 4, 2);
    VMC4(); BAR8();
    // P3 (tile t+1, buf1)
    RD_A8(af, As[1], 0); RD_B8(bf, Bs[1], 0); RD_B8(bf2, Bs[1], 2);
    STG8(Ab, K, 0, kt2, As[0]); STG8(Ab, K, 128, kt2, As[0]);
    MFMA_Q8(af, bf, 0, 0); MFMA_Q8(af, bf2, 0, 2);
    BAR8();
    // P4
    RD_A8(af2, As[1], 4);
    STG8(Bb, ldb, 0, kt3, Bs[1]); STG8(Bb, ldb, 128, kt3, Bs[1]);
    MFMA_Q8(af2, bf, 4, 0); MFMA_Q8(af2, bf2, 4, 2);
    VMC4(); BAR8();
  }

  const int rbase = bm + wmBase + g * 4;
  const int cbase = bn + wnBase + c;
#pragma unroll
  for (int m = 0; m < 8; ++m)
#pragma unroll
    for (int r = 0; r < 4; ++r) {
      const int row = rbase + m * 16 + r;
#pragma unroll
      for (int n = 0; n < 4; ++n) {
        const size_t idx = (size_t)row * N + (cbase + n * 16);
        float vacc = acc[m][n][r];
        if (EPI == 1) {
          ((float*)C)[idx] = vacc + ((const float*)R)[idx];
        } else if (EPI == 2) {
          const float u = b2f(((const bf16*)R)[idx]);
          ((bf16*)C)[idx] = f2b((u / (1.f + expf(-u))) * vacc);
        } else {
          ((bf16*)C)[idx] = f2b(vacc);
        }
      }
    }
}

// ---------------------------------------------------------------------------
// gemm12: 128x256 tile, BK=64, 8 waves (wave=64x64), 4 single-barrier phases
// per 2 K-tiles, counted vmcnt(2). QKV 768=3 rounds, wo 256, w2 256.
// ---------------------------------------------------------------------------
#define RD_A12(dst, XsBuf)                                                      \
  _Pragma("unroll") for (int mi = 0; mi < 4; ++mi) {                            \
    const int ra = wmB12 + mi * 16 + c;                                         \
    _Pragma("unroll") for (int kk = 0; kk < 2; ++kk)                            \
      dst[mi][kk] = *(const short8*)&XsBuf[ra][(((kk * 4 + g) ^ (ra & 7)) << 3)]; \
  }

#define RD_B12(dst, XsBuf, nb_)                                                 \
  _Pragma("unroll") for (int ni = 0; ni < 2; ++ni) {                            \
    const int rb = wnB12 + ((nb_) + ni) * 16 + c;                               \
    _Pragma("unroll") for (int kk = 0; kk < 2; ++kk)                            \
      dst[ni][kk] = *(const short8*)&XsBuf[rb][(((kk * 4 + g) ^ (rb & 7)) << 3)]; \
  }

#define MFMA_H12(afv, bfv, nb_)                                                 \
  __builtin_amdgcn_s_setprio(1);                                                \
  _Pragma("unroll") for (int mi = 0; mi < 4; ++mi)                              \
    _Pragma("unroll") for (int ni = 0; ni < 2; ++ni)                            \
      _Pragma("unroll") for (int kk = 0; kk < 2; ++kk)                          \
        acc[mi][(nb_) + ni] = __builtin_amdgcn_mfma_f32_16x16x32_bf16(          \
            afv[mi][kk], bfv[ni][kk], acc[mi][(nb_) + ni], 0, 0, 0);            \
  __builtin_amdgcn_s_setprio(0);

template <int EPI>
__global__ __launch_bounds__(512, 2)
void gemm12(const bf16* __restrict__ A, const bf16* __restrict__ Bt,
            const void* __restrict__ R, void* __restrict__ C,
            int N, int K, int ldb, long long boff) {
  __shared__ __align__(16) bf16 As[2][128][64];
  __shared__ __align__(16) bf16 Bs[2][256][64];
  const int tid = threadIdx.x;
  const int w = tid >> 6, l = tid & 63;
  const int g = l >> 4, c = l & 15;
  const int w8 = w * 8, lr = l >> 3;
  const int sCol = (((l & 7) ^ lr) << 3);

  const int nwg = gridDim.x * gridDim.y;
  const int orig = blockIdx.x + blockIdx.y * gridDim.x;
  const int qq = nwg >> 3, rr8 = nwg & 7;
  const int xcd = orig & 7, idx8 = orig >> 3;
  const int wg = (xcd < rr8 ? xcd * (qq + 1) : rr8 * (qq + 1) + (xcd - rr8) * qq) + idx8;
  const int bm = (wg / gridDim.x) * 128;
  const int bn = (wg % gridDim.x) * 256;

  const int wmB12 = (w >> 2) * 64;
  const int wnB12 = (w & 3) * 64;

  const bf16* Ab = A + (size_t)bm * K;
  const bf16* Bb = Bt + (size_t)bn * ldb + (size_t)boff;

  f32x4 acc[4][4] = {};
  const int nt = K >> 6;

  STG8(Ab, K, 0, 0, As[0]);
  STG8(Bb, ldb, 0, 0, Bs[0]); STG8(Bb, ldb, 128, 0, Bs[0]);
  STG8(Ab, K, 0, 64, As[1]);
  VMC2(); BAR8();

  short8 af[4][2], af2[4][2], bfa[2][2], bfa2[2][2], bfb[2][2], bfb2[2][2];
  for (int it = 0; it < (nt >> 1); ++it) {
    const int t = it * 2;
    const int kt1 = (t + 1) << 6;
    const int kt2 = (t + 2 < nt ? t + 2 : nt - 1) << 6;
    const int kt3 = (t + 3 < nt ? t + 3 : nt - 1) << 6;
    // P1 (tile t, buf0)
    RD_A12(af, As[0]); RD_B12(bfa, Bs[0], 0);
    STG8(Bb, ldb, 0, kt1, Bs[1]); STG8(Bb, ldb, 128, kt1, Bs[1]);
    MFMA_H12(af, bfa, 0);
    BAR8();
    // P2
    RD_B12(bfa2, Bs[0], 2);
    STG8(Ab, K, 0, kt2, As[0]);
    MFMA_H12(af, bfa2, 2);
    VMC2(); BAR8();
    // P3 (tile t+1, buf1)
    RD_A12(af2, As[1]); RD_B12(bfb, Bs[1], 0);
    STG8(Bb, ldb, 0, kt2, Bs[0]); STG8(Bb, ldb, 128, kt2, Bs[0]);
    MFMA_H12(af2, bfb, 0);
    BAR8();
    // P4
    RD_B12(bfb2, Bs[1], 2);
    STG8(Ab, K, 0, kt3, As[1]);
    MFMA_H12(af2, bfb2, 2);
    VMC2(); BAR8();
  }

  const int rbase = bm + wmB12 + g * 4;
  const int cbase = bn + wnB12 + c;
#pragma unroll
  for (int m = 0; m < 4; ++m)
#pragma unroll
    for (int r = 0; r < 4; ++r) {
      const int row = rbase + m * 16 + r;
#pragma unroll
      for (int n = 0; n < 4; ++n) {
        const size_t idx = (size_t)row * N + (cbase + n * 16);
        float vacc = acc[m][n][r];
        if (EPI == 1) {
          ((float*)C)[idx] = vacc + ((const float*)R)[idx];
        } else if (EPI == 2) {
          const float u = b2f(((const bf16*)R)[idx]);
          ((bf16*)C)[idx] = f2b((u / (1.f + expf(-u))) * vacc);
        } else {
          ((bf16*)C)[idx] = f2b(vacc);
        }
      }
    }
}

// ---------------------------------------------------------------------------
// PATH B GEMM (f32 weights) - fallback only.
// ---------------------------------------------------------------------------
template <int EPI>
__global__ __launch_bounds__(256)
void gemm2(const bf16* __restrict__ A, const float* __restrict__ Bt,
           const void* __restrict__ R, void* __restrict__ C,
           int N, int K, int ldb, long long boff) {
  __shared__ __align__(16) bf16 As[128][64];
  __shared__ __align__(16) float Bsf[128][64];
  const int tid = threadIdx.x;
  const int w = tid >> 6;
  const int l = tid & 63;

  const int nwg = gridDim.x * gridDim.y;
  const int orig = blockIdx.x + blockIdx.y * gridDim.x;
  const int qq = nwg >> 3, rr8 = nwg & 7;
  const int xcd = orig & 7, idx8 = orig >> 3;
  const int wg = (xcd < rr8 ? xcd * (qq + 1) : rr8 * (qq + 1) + (xcd - rr8) * qq) + idx8;
  const int bm = (wg / gridDim.x) * 128;
  const int bn = (wg % gridDim.x) * 128;

  const int wr = (w >> 1) * 64;
  const int wc = (w & 1) * 64;
  f32x4 acc[4][4] = {};

  const bf16* Ab = A + (size_t)bm * K;
  const float* Bb = Bt + (size_t)bn * ldb + (size_t)boff;

  const int aSrcCol = (((l & 7) ^ (l >> 3)) << 3);
  const int bKey = (w * 4 + (l >> 4)) & 7;
  const int bSrcCol = (((l & 15) ^ bKey) << 2);

  for (int kt = 0; kt < K; kt += 64) {
    __syncthreads();
#pragma unroll
    for (int i = 0; i < 4; ++i)
      gload16(Ab + (size_t)(i * 32 + w * 8 + (l >> 3)) * K + kt + aSrcCol,
              &As[i * 32 + w * 8][0]);
#pragma unroll
    for (int i = 0; i < 8; ++i)
      gload16(Bb + (size_t)(i * 16 + w * 4 + (l >> 4)) * ldb + kt + bSrcCol,
              &Bsf[i * 16 + w * 4][0]);
    __syncthreads();

#pragma unroll
    for (int kk = 0; kk < 2; ++kk) {
      short8 af[4], bfv[4];
#pragma unroll
      for (int m = 0; m < 4; ++m) {
        const int ra = wr + m * 16 + (l & 15);
        const int pb = (kk * 4 + (l >> 4)) ^ (ra & 7);
        af[m] = *(const short8*)&As[ra][pb * 8];
      }
#pragma unroll
      for (int n = 0; n < 4; ++n) {
        const int rb = wc + n * 16 + (l & 15);
        const int b0 = kk * 8 + (l >> 4) * 2;
        const f32x4 x0 = *(const f32x4*)&Bsf[rb][(b0 ^ (rb & 7)) * 4];
        const f32x4 x1 = *(const f32x4*)&Bsf[rb][((b0 + 1) ^ (rb & 7)) * 4];
        union { short8 s; bf16 h[8]; } u;
#pragma unroll
        for (int j = 0; j < 4; ++j) { u.h[j] = f2b(x0[j]); u.h[j + 4] = f2b(x1[j]); }
        bfv[n] = u.s;
      }
#pragma unroll
      for (int m = 0; m < 4; ++m)
#pragma unroll
        for (int n = 0; n < 4; ++n)
          acc[m][n] = __builtin_amdgcn_mfma_f32_16x16x32_bf16(af[m], bfv[n], acc[m][n], 0, 0, 0);
    }
  }

  const int rbase = bm + wr + (l >> 4) * 4;
  const int cbase = bn + wc + (l & 15);
#pragma unroll
  for (int m = 0; m < 4; ++m)
#pragma unroll
    for (int r = 0; r < 4; ++r) {
      const int row = rbase + m * 16 + r;
#pragma unroll
      for (int n = 0; n < 4; ++n) {
        const size_t idx = (size_t)row * N + (cbase + n * 16);
        float vacc = acc[m][n][r];
        if (EPI == 1) {
          ((float*)C)[idx] = vacc + ((const float*)R)[idx];
        } else if (EPI == 2) {
          const float u = b2f(((const bf16*)R)[idx]);
          ((bf16*)C)[idx] = f2b((u / (1.f + expf(-u))) * vacc);
        } else {
          ((bf16*)C)[idx] = f2b(vacc);
        }
      }
    }
}

// ---------------------------------------------------------------------------
__global__ __launch_bounds__(256)
void rmsnorm_k(const float* __restrict__ xin, const float* __restrict__ g,
               bf16* __restrict__ out) {
  const int row = blockIdx.x;
  const int tid = threadIdx.x;
  const float* xp = xin + (size_t)row * Dq + tid * 8;
  f32x4 a = *(const f32x4*)xp, b = *(const f32x4*)(xp + 4);
  float xf[8];
#pragma unroll
  for (int j = 0; j < 4; ++j) { xf[j] = a[j]; xf[j + 4] = b[j]; }
  float ss = 0.f;
#pragma unroll
  for (int j = 0; j < 8; ++j) ss += xf[j] * xf[j];
#pragma unroll
  for (int off = 32; off > 0; off >>= 1) ss += __shfl_down(ss, off);
  __shared__ float red[4];
  if ((tid & 63) == 0) red[tid >> 6] = ss;
  __syncthreads();
  const float rms = rsqrtf((red[0] + red[1] + red[2] + red[3]) * (1.f / (float)Dq) + 1e-6f);
  const float* gp = g + tid * 8;
  f32x4 ga = *(const f32x4*)gp, gb = *(const f32x4*)(gp + 4);
  union { short8 s; bf16 h[8]; } uo;
#pragma unroll
  for (int j = 0; j < 4; ++j) {
    uo.h[j] = f2b(xf[j] * rms * ga[j]);
    uo.h[j + 4] = f2b(xf[j + 4] * rms * gb[j]);
  }
  *(short8*)(out + (size_t)row * Dq + tid * 8) = uo.s;
}

// ---------------------------------------------------------------------------
__global__ __launch_bounds__(256)
void rope_k(bf16* __restrict__ q, bf16* __restrict__ k, int ld) {
  const size_t idx = (size_t)blockIdx.x * 256 + threadIdx.x;
  const int i = (int)(idx & 63);
  const int h = (int)((idx >> 6) & 15);
  const int s = (int)((idx >> 10) & 2047);
  const int b = (int)(idx >> 21);
  const float f = (float)s * powf(10000.f, -(float)i * (1.f / 64.f));
  float sn, cs;
  sincosf(f, &sn, &cs);
  const size_t base = ((size_t)(b * Sq + s)) * ld + h * DHq + i;
  const float qa = b2f(q[base]), qb_ = b2f(q[base + 64]);
  q[base] = f2b(qa * cs - qb_ * sn);
  q[base + 64] = f2b(qb_ * cs + qa * sn);
  const float ka = b2f(k[base]), kb_ = b2f(k[base + 64]);
  k[base] = f2b(ka * cs - kb_ * sn);
  k[base + 64] = f2b(kb_ * cs + ka * sn);
}

// ---------------------------------------------------------------------------
// Causal flash attention v3 (round-7 verified).
// ---------------------------------------------------------------------------
__device__ __forceinline__ int swz8(int row) { return (((row >> 3) ^ row) & 7) << 3; }

#define ATTN_COMPUTE(AQ, QB, QROW, M_, L_, OACC, KV0, CUR)                        \
  {                                                                               \
    f32x4 sc[4] = {};                                                             \
    __builtin_amdgcn_s_setprio(1);                                                \
    _Pragma("unroll") for (int n = 0; n < 4; ++n) {                               \
      const int krow = n * 16 + c;                                                \
      const int sw = swz8(krow);                                                  \
      _Pragma("unroll") for (int kk = 0; kk < 4; ++kk) {                          \
        short8 ak = *(const short8*)&Ks[CUR][krow][(kk * 32 + g * 8) ^ sw];       \
        sc[n] = __builtin_amdgcn_mfma_f32_16x16x32_bf16(ak, AQ[kk], sc[n], 0, 0, 0); \
      }                                                                           \
    }                                                                             \
    __builtin_amdgcn_s_setprio(0);                                                \
    float p[4][4];                                                                \
    float tmax = -3.0e38f;                                                        \
    if ((KV0) + 63 <= (QB)) {                                                     \
      _Pragma("unroll") for (int n = 0; n < 4; ++n)                               \
        _Pragma("unroll") for (int r = 0; r < 4; ++r) {                           \
          const float val = sc[n][r] * SCALE;                                     \
          p[n][r] = val;                                                          \
          tmax = fmaxf(tmax, val);                                                \
        }                                                                         \
    } else {                                                                      \
      _Pragma("unroll") for (int n = 0; n < 4; ++n)                               \
        _Pragma("unroll") for (int r = 0; r < 4; ++r) {                           \
          const int kvg = (KV0) + n * 16 + g * 4 + r;                             \
          float val = sc[n][r] * SCALE;                                           \
          if (kvg > (QROW)) val = -3.0e38f;                                       \
          p[n][r] = val;                                                          \
          tmax = fmaxf(tmax, val);                                                \
        }                                                                         \
    }                                                                             \
    tmax = fmaxf(tmax, __shfl_xor(tmax, 16));                                     \
    tmax = fmaxf(tmax, __shfl_xor(tmax, 32));                                     \
    const bool grow = !__all(tmax <= M_);                                         \
    const float m_new = grow ? fmaxf(M_, tmax) : M_;                              \
    float tsum = 0.f;                                                             \
    _Pragma("unroll") for (int n = 0; n < 4; ++n)                                 \
      _Pragma("unroll") for (int r = 0; r < 4; ++r) {                             \
        const float pv = expf(p[n][r] - m_new);                                   \
        p[n][r] = pv;                                                             \
        tsum += pv;                                                               \
      }                                                                           \
    tsum += __shfl_xor(tsum, 16);                                                 \
    tsum += __shfl_xor(tsum, 32);                                                 \
    if (grow) {                                                                   \
      const float corr = expf(M_ - m_new);                                        \
      L_ = L_ * corr + tsum;                                                      \
      M_ = m_new;                                                                 \
      _Pragma("unroll") for (int dt = 0; dt < 8; ++dt) OACC[dt] *= corr;          \
    } else {                                                                      \
      L_ += tsum;                                                                 \
    }                                                                             \
    const int keyc = (c ^ (c >> 3)) & 7;                                          \
    _Pragma("unroll") for (int n = 0; n < 4; ++n) {                               \
      union { unsigned long long u; bf16 hh[4]; } pk;                             \
      _Pragma("unroll") for (int r = 0; r < 4; ++r) pk.hh[r] = f2b(p[n][r]);      \
      const int blk = (2 * n + (g >> 1)) ^ keyc;                                  \
      *(unsigned long long*)&Ps[w][c][blk * 8 + (g & 1) * 4] = pk.u;              \
    }                                                                             \
    short8 ap[2];                                                                 \
    _Pragma("unroll") for (int kk = 0; kk < 2; ++kk)                              \
      ap[kk] = *(const short8*)&Ps[w][c][(kk * 32 + g * 8) ^ (keyc << 3)];        \
    __builtin_amdgcn_s_setprio(1);                                                \
    _Pragma("unroll") for (int dt = 0; dt < 8; ++dt) {                            \
      const int vrow = dt * 16 + c;                                               \
      const int vsw = swz8(vrow);                                                 \
      _Pragma("unroll") for (int kk = 0; kk < 2; ++kk) {                          \
        short8 av = *(const short8*)&Vt[CUR][vrow][(kk * 32 + g * 8) ^ vsw];      \
        OACC[dt] = __builtin_amdgcn_mfma_f32_16x16x32_bf16(av, ap[kk], OACC[dt], 0, 0, 0); \
      }                                                                           \
    }                                                                             \
    __builtin_amdgcn_s_setprio(0);                                                \
  }

__global__ __launch_bounds__(512)
void attn_k(const bf16* __restrict__ q, const bf16* __restrict__ k,
            const bf16* __restrict__ v, bf16* __restrict__ o, int ld) {
  __shared__ __align__(16) bf16 Ks[2][64][128];
  __shared__ __align__(16) bf16 Vt[2][128][64];
  __shared__ __align__(16) bf16 Ps[8][16][64];
  const int tid = threadIdx.x;
  const int w = tid >> 6, l = tid & 63;
  const int g = l >> 4, c = l & 15;
  const int x = blockIdx.x;
  const int h = blockIdx.y;
  const int b = blockIdx.z;
  const size_t hoff = (size_t)h * DHq;
  const float SCALE = 0.08838834764831845f;

  const int q0h = (15 - x) * 128, q0l = x * 128;
  const int qbh = q0h + w * 16, qbl = q0l + w * 16;
  const int qrh = qbh + c, qrl = qbl + c;

  short8 aqh[4], aql[4];
  {
    const bf16* qph = q + (size_t)(b * Sq + qrh) * ld + hoff + g * 8;
    const bf16* qpl = q + (size_t)(b * Sq + qrl) * ld + hoff + g * 8;
#pragma unroll
    for (int kk = 0; kk < 4; ++kk) {
      aqh[kk] = *(const short8*)(qph + kk * 32);
      aql[kk] = *(const short8*)(qpl + kk * 32);
    }
  }

  float mh = -3.0e38f, lh = 0.f, ml = -3.0e38f, ll_ = 0.f;
  f32x4 oh[8] = {}, ol[8] = {};

  const int stRow = tid >> 4;
  const int stBlk = tid & 15;
  const int ntiles = (q0h >> 6) + 2;

  {
#pragma unroll
    for (int i = 0; i < 2; ++i) {
      const int kr = i * 32 + w * 4 + (l >> 4);
      const int key = (kr ^ (kr >> 3)) & 7;
      gload16(k + (size_t)(b * Sq + kr) * ld + hoff + ((c ^ key) << 3),
              &Ks[0][i * 32 + w * 4][0]);
    }
    const int c0 = stBlk * 8;
#pragma unroll
    for (int i = 0; i < 2; ++i) {
      const int vr = i * 32 + stRow;
      union { short8 s; bf16 hh[8]; } uv;
      uv.s = *(const short8*)(v + (size_t)(b * Sq + vr) * ld + hoff + c0);
#pragma unroll
      for (int j = 0; j < 8; ++j) Vt[0][c0 + j][vr ^ swz8(c0 + j)] = uv.hh[j];
    }
  }
  __syncthreads();

  for (int t = 0; t < ntiles; ++t) {
    const int cur = t & 1, nxt = cur ^ 1;
    const int kv0 = t * 64;
    const bool pf = (t + 1 < ntiles);
    short8 vpa, vpb;
    if (pf) {
      const int kvn = kv0 + 64;
#pragma unroll
      for (int i = 0; i < 2; ++i) {
        const int kr = i * 32 + w * 4 + (l >> 4);
        const int key = (kr ^ (kr >> 3)) & 7;
        gload16(k + (size_t)(b * Sq + kvn + kr) * ld + hoff + ((c ^ key) << 3),
                &Ks[nxt][i * 32 + w * 4][0]);
      }
      vpa = *(const short8*)(v + (size_t)(b * Sq + kvn + stRow) * ld + hoff + stBlk * 8);
      vpb = *(const short8*)(v + (size_t)(b * Sq + kvn + 32 + stRow) * ld + hoff + stBlk * 8);
    }

    if (kv0 <= qbh + 15) ATTN_COMPUTE(aqh, qbh, qrh, mh, lh, oh, kv0, cur);

    if (pf) {
      const int c0 = stBlk * 8;
      union { short8 s; bf16 hh[8]; } uv;
      uv.s = vpa;
#pragma unroll
      for (int j = 0; j < 8; ++j) Vt[nxt][c0 + j][stRow ^ swz8(c0 + j)] = uv.hh[j];
      uv.s = vpb;
#pragma unroll
      for (int j = 0; j < 8; ++j) Vt[nxt][c0 + j][(32 + stRow) ^ swz8(c0 + j)] = uv.hh[j];
    }

    if (kv0 <= qbl + 15) ATTN_COMPUTE(aql, qbl, qrl, ml, ll_, ol, kv0, cur);

    __syncthreads();
  }

  {
    const float inv = 1.f / lh;
    bf16* op = o + (size_t)(b * Sq + qrh) * Dq + hoff + g * 4;
#pragma unroll
    for (int dt = 0; dt < 8; ++dt) {
      union { unsigned long long u; bf16 hh[4]; } pk;
#pragma unroll
      for (int r = 0; r < 4; ++r) pk.hh[r] = f2b(oh[dt][r] * inv);
      *(unsigned long long*)(op + dt * 16) = pk.u;
    }
  }
  {
    const float inv = 1.f / ll_;
    bf16* op = o + (size_t)(b * Sq + qrl) * Dq + hoff + g * 4;
#pragma unroll
    for (int dt = 0; dt < 8; ++dt) {
      union { unsigned long long u; bf16 hh[4]; } pk;
#pragma unroll
      for (int r = 0; r < 4; ++r) pk.hh[r] = f2b(ol[dt][r] * inv);
      *(unsigned long long*)(op + dt * 16) = pk.u;
    }
  }
}

// ---------------------------------------------------------------------------
// Workspace (PATH A, needs ~201.6 MB):
//   [0,16.8)    h / ob
//   [16.8,67.1) qkv ; h2 = first 16.8 of it after attn
//   [33.6,100.7) ub FULL M x 8192 (overlaps dead qkv-tail + wqkv_b + wo_b;
//                conv re-writes wqkv_b/wo_b every replay before their use)
//   [67.1,...)  weights: wqkv_b(25.2) wo_b(8.4) w1_b(33.6) w3_b(33.6) w2_b(33.6)
// ---------------------------------------------------------------------------
extern "C" void kernel_launch(void* const* d_in, const int* in_sizes, int n_in,
                              void* d_out, int out_size, void* d_ws, size_t ws_size,
                              hipStream_t stream) {
  (void)in_sizes; (void)n_in; (void)out_size;
  const float* x  = (const float*)d_in[0];
  const float* wq = (const float*)d_in[2];
  const float* wk = (const float*)d_in[3];
  const float* wv = (const float*)d_in[4];
  const float* wo = (const float*)d_in[5];
  const float* w1 = (const float*)d_in[6];
  const float* w2 = (const float*)d_in[7];
  const float* w3 = (const float*)d_in[8];
  const float* ga = (const float*)d_in[9];
  const float* gf = (const float*)d_in[10];
  float* out = (float*)d_out;

  char* ws = (char*)d_ws;
  dim3 blk(256);
  dim3 gA(8, Hq, Bq);
  dim3 blkA(512);
  dim3 blk8(512);

  const size_t SZ_H   = (size_t)Mq * Dq * 2;
  const size_t SZ_QKV = (size_t)Mq * 3 * Dq * 2;
  const size_t SZ_W4  = (size_t)Dq * Dq * 2;
  const size_t SZ_W13 = (size_t)FFq * Dq * 2;
  const size_t ACT    = SZ_H + SZ_QKV;
  const size_t WTS    = 3 * SZ_W4 + SZ_W4 + 3 * SZ_W13;
  const size_t NEED   = ACT + WTS;

  if (ws_size >= NEED) {
    bf16* h    = (bf16*)(ws);
    bf16* qkv  = (bf16*)(ws + SZ_H);
    bf16* ob   = h;
    bf16* h2   = qkv;
    bf16* ub   = (bf16*)(ws + 2 * SZ_H);   // FULL M x 8192 = 67.1MB
    char* wb   = ws + ACT;
    bf16* wqkv_b = (bf16*)(wb);
    bf16* wo_b   = (bf16*)(wb + 3 * SZ_W4);
    bf16* w1_b   = (bf16*)(wb + 4 * SZ_W4);
    bf16* w3_b   = (bf16*)(wb + 4 * SZ_W4 + SZ_W13);
    bf16* w2_b   = (bf16*)(wb + 4 * SZ_W4 + 2 * SZ_W13);

    const long nW4 = (long)Dq * Dq, nW13 = (long)FFq * Dq;
    conv_k<<<1024, blk, 0, stream>>>(wq, wqkv_b, nW4);
    conv_k<<<1024, blk, 0, stream>>>(wk, wqkv_b + nW4, nW4);
    conv_k<<<1024, blk, 0, stream>>>(wv, wqkv_b + 2 * nW4, nW4);
    conv_k<<<1024, blk, 0, stream>>>(wo, wo_b, nW4);
    conv_k<<<2048, blk, 0, stream>>>(w1, w1_b, nW13);
    conv_k<<<2048, blk, 0, stream>>>(w3, w3_b, nW13);
    conv_k<<<2048, blk, 0, stream>>>(w2, w2_b, nW13);

    rmsnorm_k<<<Mq, blk, 0, stream>>>(x, ga, h);
    gemm12<0><<<dim3(24, 32), blk8, 0, stream>>>(h, wqkv_b, nullptr, qkv, 6144, Dq, Dq, 0);
    rope_k<<<(Bq * Sq * Hq * 64) / 256, blk, 0, stream>>>(qkv, qkv + Dq, 3 * Dq);
    attn_k<<<gA, blkA, 0, stream>>>(qkv, qkv + Dq, qkv + 2 * Dq, ob, 3 * Dq);
    gemm12<1><<<dim3(8, 32), blk8, 0, stream>>>(ob, wo_b, x, out, Dq, Dq, Dq, 0);
    rmsnorm_k<<<Mq, blk, 0, stream>>>(out, gf, h2);
    // FFN full-width: w1 -> ub[.,0:8192]; silu-combine via w3 EPI2; w2 K=8192
    gemm8<0><<<dim3(32, 16), blk8, 0, stream>>>(h2, w1_b, nullptr, ub, FFq, Dq, Dq, 0);
    gemm8<2><<<dim3(32, 16), blk8, 0, stream>>>(h2, w3_b, ub, ub, FFq, Dq, Dq, 0);
    gemm12<1><<<dim3(8, 32), blk8, 0, stream>>>(ub, w2_b, out, out, Dq, FFq, FFq, 0);
  } else {
    // ---- PATH B: f32-weight fallback ----
    const size_t MS = (size_t)Mq * Dq * 2;
    bf16* h  = (bf16*)(ws);
    bf16* kb = (bf16*)(ws + MS);
    bf16* vb = (bf16*)(ws + 2 * MS);
    bf16* qb = (bf16*)(ws + 3 * MS);
    bf16* ub = (bf16*)(ws);
    bf16* ob = h;
    bf16* h2 = qb;

    dim3 gD(Dq / 128, Mq / 128);
    dim3 gU(32, Mq / 128);
    dim3 gAB(Sq / 128, Hq, Bq);
    (void)gAB;

    rmsnorm_k<<<Mq, blk, 0, stream>>>(x, ga, h);
    gemm2<0><<<gD, blk, 0, stream>>>(h, wq, nullptr, qb, Dq, Dq, Dq, 0);
    gemm2<0><<<gD, blk, 0, stream>>>(h, wk, nullptr, kb, Dq, Dq, Dq, 0);
    gemm2<0><<<gD, blk, 0, stream>>>(h, wv, nullptr, vb, Dq, Dq, Dq, 0);
    rope_k<<<(Bq * Sq * Hq * 64) / 256, blk, 0, stream>>>(qb, kb, Dq);
    attn_k<<<gA, blkA, 0, stream>>>(qb, kb, vb, ob, Dq);
    gemm2<1><<<gD, blk, 0, stream>>>(ob, wo, x, out, Dq, Dq, Dq, 0);
    rmsnorm_k<<<Mq, blk, 0, stream>>>(out, gf, h2);
    for (int hh = 0; hh < 2; ++hh) {
      const long long bo13 = (long long)hh * 4096 * 2048;
      gemm2<0><<<gU, blk, 0, stream>>>(h2, w1, nullptr, ub, 4096, Dq, Dq, bo13);
      gemm2<2><<<gU, blk, 0, stream>>>(h2, w3, ub, ub, 4096, Dq, Dq, bo13);
      gemm2<1><<<gD, blk, 0, stream>>>(ub, w2, out, out, Dq, 4096, FFq,
                                       (long long)hh * 4096);
    }
  }
}